// Round 2
// baseline (472.038 us; speedup 1.0000x reference)
//
#include <hip/hip_runtime.h>
#include <hip/hip_bf16.h>
#include <math.h>

typedef __hip_bfloat16 bf16;
typedef float f32x4 __attribute__((ext_vector_type(4)));
typedef __bf16 bf16x8 __attribute__((ext_vector_type(8)));

#define DEV __device__ __forceinline__

DEV float to_f(float v){ return v; }
DEV float to_f(bf16 v){ return __bfloat162float(v); }
DEV bf16 f2b(float v){ return __float2bfloat16(v); }
DEV unsigned short b2u(bf16 v){ return __builtin_bit_cast(unsigned short, v); }

DEV float gelu_f(float x){
  float z = 1.5957691216057308f*(x + 0.044715f*x*x*x);
  float e = __expf(-z);
  return x * __builtin_amdgcn_rcpf(1.0f + e);
}

DEV bf16x8 load_frag(const bf16* p, bool ok){
  uint4 u = make_uint4(0u,0u,0u,0u);
  if (ok) u = *(const uint4*)p;
  return __builtin_bit_cast(bf16x8, u);
}

DEV f32x4 mfma16(bf16x8 a, uint4 b, f32x4 c){
  return __builtin_amdgcn_mfma_f32_16x16x32_bf16(a, __builtin_bit_cast(bf16x8, b), c, 0, 0, 0);
}

DEV int swz8(int blk, int n){
  return (blk & 7) * (n >> 3) + (blk >> 3);
}

// async global->LDS DMA, 16 B per lane; lds dest wave-uniform base.
DEV void dma16(const void* g, void* l){
  __builtin_amdgcn_global_load_lds(
      (const __attribute__((address_space(1))) unsigned int*)g,
      (__attribute__((address_space(3))) unsigned int*)l,
      16, 0, 0);
}

#define NSLOT 64

// ---------------- encoder Conv_trio -------------------------------------------
template<typename TIN, int CIN, int COUT, int SUB, int STRIDE, int HI, int WI>
__global__ void trio_kernel(const TIN* __restrict__ in, const float* __restrict__ w,
                            const float* __restrict__ bias, bf16* __restrict__ out){
  constexpr int HO = HI/STRIDE, WO = WI/STRIDE;
  constexpr int CO_PER = COUT/SUB;
  int gtid = blockIdx.x*blockDim.x + threadIdx.x;
  int sub = gtid % SUB;
  int pix = gtid / SUB;
  int b = pix / (HO*WO); int rem = pix % (HO*WO);
  int y = rem / WO, x = rem % WO;

  float acc[CO_PER];
  #pragma unroll
  for (int j=0;j<CO_PER;j++) acc[j]=0.f;

  for (int ky=0;ky<3;ky++){
    int iy = (STRIDE==1) ? (y+ky-1) : (2*y+ky);
    if (iy<0 || iy>=HI) continue;
    for (int kx=0;kx<3;kx++){
      int ix = (STRIDE==1) ? (x+kx-1) : (2*x+kx);
      if (ix<0 || ix>=WI) continue;
      const TIN* ip = in + ((size_t)(b*HI+iy)*WI+ix)*CIN;
      const float* wp = w + ((ky*3+kx)*CIN)*COUT + sub*CO_PER;
      if constexpr (sizeof(TIN)==2 && (CIN%8)==0){
        #pragma unroll
        for (int v=0; v<CIN/8; v++){
          uint4 u = *(const uint4*)((const bf16*)ip + v*8);
          bf16x8 ch = __builtin_bit_cast(bf16x8, u);
          #pragma unroll
          for (int j=0;j<8;j++){
            float a = (float)ch[j];
            const float4* w4 = (const float4*)(wp + (size_t)(v*8+j)*COUT);
            #pragma unroll
            for (int q2=0;q2<CO_PER/4;q2++){
              float4 ww = w4[q2];
              acc[4*q2+0] += a*ww.x; acc[4*q2+1] += a*ww.y;
              acc[4*q2+2] += a*ww.z; acc[4*q2+3] += a*ww.w;
            }
          }
        }
      } else {
        #pragma unroll 4
        for (int ci=0; ci<CIN; ci++){
          float a = to_f(ip[ci]);
          const float4* w4 = (const float4*)(wp + (size_t)ci*COUT);
          #pragma unroll
          for (int j=0;j<CO_PER/4;j++){
            float4 ww = w4[j];
            acc[4*j+0] += a*ww.x; acc[4*j+1] += a*ww.y;
            acc[4*j+2] += a*ww.z; acc[4*j+3] += a*ww.w;
          }
        }
      }
    }
  }

  float s1=0.f, s2=0.f;
  #pragma unroll
  for (int j=0;j<CO_PER;j++){
    acc[j] += bias[sub*CO_PER+j];
    s1 += acc[j]; s2 += acc[j]*acc[j];
  }
  #pragma unroll
  for (int off=1; off<SUB; off<<=1){
    s1 += __shfl_xor(s1,off,64);
    s2 += __shfl_xor(s2,off,64);
  }
  float mu  = s1*(1.0f/COUT);
  float var = s2*(1.0f/COUT) - mu*mu;
  float sc  = rsqrtf(var + 1e-6f);

  bf16* op = out + (size_t)pix*COUT + sub*CO_PER;
  #pragma unroll
  for (int j=0;j<CO_PER;j++) op[j] = f2b(gelu_f((acc[j]-mu)*sc));
}

// ---------------- weight repack -----------------------------------------------
__global__ void repack_up(const float* __restrict__ w, bf16* __restrict__ bp){
  int v = blockIdx.x*256 + threadIdx.x;
  if (v >= 9*2*4*64*8) return;
  int j = v & 7; int lane = (v>>3)&63; int nt = (v>>9)&3; int c = (v>>11)&1; int tap = v>>12;
  int ci = c*32 + (lane>>4)*8 + j;
  int co = (lane&15)*4 + nt;
  bp[v] = f2b(w[(tap*64+ci)*64 + co]);
}

__global__ void repack_mask(const float* __restrict__ w, bf16* __restrict__ bp){
  int v = blockIdx.x*256 + threadIdx.x;
  if (v >= 9*2*64*8) return;
  int j = v & 7; int lane = (v>>3)&63; int c = (v>>9)&1; int tap = v>>10;
  int ci = c*32 + (lane>>4)*8 + j;
  int n = lane & 15;
  bp[v] = (n < 4) ? f2b(w[(tap*64+ci)*4 + n]) : f2b(0.0f);
}

// ------------- conv_transpose, stride-2 along y (DIM=0) -----------------------
template<int HI, int WI>
__global__ void upconv_dim0(const bf16* __restrict__ in, const bf16* __restrict__ bpack,
                            const float* __restrict__ upb, bf16* __restrict__ out){
  constexpr int HO = 2*HI, WO = WI, XT = WI/32;
  int lane = threadIdx.x & 63, wv = threadIdx.x >> 6;
  int wtile = swz8(blockIdx.x, gridDim.x)*4 + wv;
  int m = lane & 15, quad = lane >> 4;

  int x0 = (wtile % XT)*32;
  int o  = (wtile / XT) % HO;
  int b  = wtile / (XT*HO);

  int q = o >> 1;
  int stk[2], stq[2]; int nst;
  if (o & 1){ stk[0]=1; stq[0]=q; nst=1; }
  else {
    nst = 0;
    if (q >= 1){ stk[0]=0; stq[0]=q-1; nst=1; }
    stk[nst]=2; stq[nst]=q; nst++;
  }

  f32x4 acc[2][4];
  #pragma unroll
  for (int t=0;t<2;t++)
    #pragma unroll
    for (int nt=0;nt<4;nt++) acc[t][nt] = (f32x4){0.f,0.f,0.f,0.f};

  const uint4* bp4 = (const uint4*)bpack;

  #pragma unroll 1
  for (int s=0; s<nst; s++){
    int kyt = stk[s];
    const bf16* rowp = in + ((size_t)(b*HI+stq[s])*WI)*64 + quad*8;
    #pragma unroll
    for (int ut=0; ut<3; ut++){
      #pragma unroll
      for (int c=0;c<2;c++){
        int ix0 = x0 + m - 1 + ut;
        int ix1 = ix0 + 16;
        bf16x8 a0 = load_frag(rowp + (size_t)ix0*64 + c*32, ix0>=0 && ix0<WI);
        bf16x8 a1 = load_frag(rowp + (size_t)ix1*64 + c*32, ix1>=0 && ix1<WI);
        #pragma unroll
        for (int nt=0;nt<4;nt++){
          uint4 Bq = bp4[(((kyt*3+ut)*2+c)*4+nt)*64 + lane];
          acc[0][nt] = mfma16(a0, Bq, acc[0][nt]);
          acc[1][nt] = mfma16(a1, Bq, acc[1][nt]);
        }
      }
    }
  }

  float4 bv = *(const float4*)(upb + m*4);
  size_t rowbase = ((size_t)b*HO + o)*WO;
  #pragma unroll
  for (int t=0;t<2;t++){
    #pragma unroll
    for (int r=0;r<4;r++){
      int p = x0 + t*16 + quad*4 + r;
      float g0 = gelu_f(acc[t][0][r] + bv.x);
      float g1 = gelu_f(acc[t][1][r] + bv.y);
      float g2 = gelu_f(acc[t][2][r] + bv.z);
      float g3 = gelu_f(acc[t][3][r] + bv.w);
      unsigned int lo = (unsigned int)b2u(f2b(g0)) | ((unsigned int)b2u(f2b(g1))<<16);
      unsigned int hi = (unsigned int)b2u(f2b(g2)) | ((unsigned int)b2u(f2b(g3))<<16);
      *(uint2*)(out + (rowbase + p)*64 + m*4) = make_uint2(lo,hi);
    }
  }
}

// ------------- conv_transpose dim1, register form (all dim1 steps) ------------
// Pure-register: Au/As fragments loaded directly from global. The As
// (1-px-misaligned) re-reads duplicate bytes, but the input L3-fits (<=33.5 MB)
// so re-reads are L2/L3 hits — no extra HBM. No LDS -> no barriers, no
// vmcnt(0) drain, and occupancy is VGPR-bound (up to 8 blocks/CU vs 4-5 with
// the LDS variant), which is the lever for this latency-bound kernel.
template<int HI, int WI>
__global__ void upconv_dim1(const bf16* __restrict__ in, const bf16* __restrict__ bpack,
                            const float* __restrict__ upb, bf16* __restrict__ out){
  constexpr int HO = HI, WO = 2*WI, QT = WI/16;
  int lane = threadIdx.x & 63, wv = threadIdx.x >> 6;
  int wtile = swz8(blockIdx.x, gridDim.x)*4 + wv;
  int m = lane & 15, quad = lane >> 4;

  int q0 = (wtile % QT)*16;
  int y  = (wtile / QT) % HI;
  int b  = wtile / (QT*HI);

  f32x4 ae[4], ao[4];
  #pragma unroll
  for (int nt=0;nt<4;nt++){ ae[nt]=(f32x4){0.f,0.f,0.f,0.f}; ao[nt]=(f32x4){0.f,0.f,0.f,0.f}; }

  const uint4* bp4 = (const uint4*)bpack;

  #pragma unroll 1
  for (int ky=0; ky<3; ky++){
    int iy = y + ky - 1;
    if (iy < 0 || iy >= HI) continue;
    const bf16* rowp = in + ((size_t)(b*HI+iy)*WI)*64 + quad*8;
    #pragma unroll
    for (int c=0;c<2;c++){
      int qa = q0 + m;
      bf16x8 Au = load_frag(rowp + (size_t)qa*64 + c*32, true);
      bf16x8 As = load_frag(rowp + (size_t)(qa-1)*64 + c*32, qa >= 1);
      #pragma unroll
      for (int nt=0;nt<4;nt++){
        uint4 B0 = bp4[(((ky*3+0)*2+c)*4+nt)*64 + lane];
        uint4 B1 = bp4[(((ky*3+1)*2+c)*4+nt)*64 + lane];
        uint4 B2 = bp4[(((ky*3+2)*2+c)*4+nt)*64 + lane];
        ae[nt] = mfma16(As, B0, ae[nt]);
        ae[nt] = mfma16(Au, B2, ae[nt]);
        ao[nt] = mfma16(Au, B1, ao[nt]);
      }
    }
  }

  float4 bv = *(const float4*)(upb + m*4);
  size_t rowbase = ((size_t)b*HO + y)*WO;
  #pragma unroll
  for (int r=0;r<4;r++){
    int qq = q0 + quad*4 + r;
    {
      float g0 = gelu_f(ae[0][r] + bv.x);
      float g1 = gelu_f(ae[1][r] + bv.y);
      float g2 = gelu_f(ae[2][r] + bv.z);
      float g3 = gelu_f(ae[3][r] + bv.w);
      unsigned int lo = (unsigned int)b2u(f2b(g0)) | ((unsigned int)b2u(f2b(g1))<<16);
      unsigned int hi = (unsigned int)b2u(f2b(g2)) | ((unsigned int)b2u(f2b(g3))<<16);
      *(uint2*)(out + (rowbase + 2*qq)*64 + m*4) = make_uint2(lo,hi);
    }
    {
      float g0 = gelu_f(ao[0][r] + bv.x);
      float g1 = gelu_f(ao[1][r] + bv.y);
      float g2 = gelu_f(ao[2][r] + bv.z);
      float g3 = gelu_f(ao[3][r] + bv.w);
      unsigned int lo = (unsigned int)b2u(f2b(g0)) | ((unsigned int)b2u(f2b(g1))<<16);
      unsigned int hi = (unsigned int)b2u(f2b(g2)) | ((unsigned int)b2u(f2b(g3))<<16);
      *(uint2*)(out + (rowbase + 2*qq+1)*64 + m*4) = make_uint2(lo,hi);
    }
  }
}

// ---------------- maskloss, register form — step 0 only ------------------------
template<int STEP, int DIM, int HH, int WW, int TILES>
__global__ void maskloss_mfma(const bf16* __restrict__ feat, const bf16* __restrict__ mpack,
                              const float* __restrict__ mb, const float* __restrict__ img,
                              const float* __restrict__ masks_in, float* __restrict__ masks_out,
                              float* __restrict__ accbuf){
  __shared__ float llog[4][64][4];
  __shared__ float red[4][2];
  int lane = threadIdx.x & 63;
  int wv   = threadIdx.x >> 6;
  int wtile = swz8(blockIdx.x, gridDim.x)*4 + wv;
  int m = lane & 15, quad = lane >> 4;

  constexpr int TPR = WW/(16*TILES);
  int x0 = (wtile % TPR)*(16*TILES);
  int y  = (wtile / TPR) % HH;
  int b  = wtile / (TPR*HH);

  const uint4* bp4 = (const uint4*)mpack;

  #pragma unroll 1
  for (int t=0; t<TILES; t++){
    f32x4 acc4 = (f32x4){0.f,0.f,0.f,0.f};
    #pragma unroll
    for (int c=0;c<2;c++){
      bf16x8 afr[9];
      #pragma unroll
      for (int ky=0; ky<3; ky++){
        int iy = y + ky - 1;
        bool rowok = (iy >= 0) && (iy < HH);
        const bf16* rowp = feat + ((size_t)(b*HH+iy)*WW)*64 + quad*8 + c*32;
        #pragma unroll
        for (int kx=0; kx<3; kx++){
          int ix = x0 + t*16 + m + kx - 1;
          bool ok = rowok && (ix >= 0) && (ix < WW);
          afr[ky*3+kx] = load_frag(rowp + (size_t)ix*64, ok);
        }
      }
      #pragma unroll
      for (int tap=0; tap<9; tap++){
        uint4 bb = bp4[(tap*2+c)*64 + lane];
        acc4 = mfma16(afr[tap], bb, acc4);
      }
    }
    if (m < 4){
      #pragma unroll
      for (int r=0;r<4;r++) llog[wv][t*16 + quad*4 + r][m] = acc4[r] + mb[m];
    }
  }
  __syncthreads();

  float ent = 0.f, mse = 0.f;
  if (lane < 16*TILES){
    int p = lane; int xx = x0 + p;
    float l0 = llog[wv][p][0], l1 = llog[wv][p][1];
    float l2 = llog[wv][p][2], l3 = llog[wv][p][3];
    float mx = fmaxf(fmaxf(l0,l1), fmaxf(l2,l3));
    float e0=__expf(l0-mx), e1=__expf(l1-mx), e2=__expf(l2-mx), e3=__expf(l3-mx);
    float inv = __builtin_amdgcn_rcpf(e0+e1+e2+e3);
    float p0=e0*inv, p1=e1*inv, p2=e2*inv, p3=e3*inv;
    float sval = p1 + 2.f*p2 + 3.f*p3;

    constexpr int HM = (DIM==0)? HH/2 : HH;
    constexpr int WM = (DIM==0)? WW : WW/2;
    int my = (DIM==0)? (y>>1) : y;
    int mxi = (DIM==1)? (xx>>1) : xx;
    float mv = masks_in[((size_t)b*HM + my)*WM + mxi];
    masks_out[((size_t)b*HH + y)*WW + xx] = mv + 0.25f*sval;

    ent = -(p0*__logf(p0+1e-8f) + p1*__logf(p1+1e-8f) +
            p2*__logf(p2+1e-8f) + p3*__logf(p3+1e-8f));

    constexpr int FH = 256/HH, FW = 256/WW;
    float isum = 0.f;
    const float* ib = img + ((size_t)b*256 + y*FH)*256 + xx*FW;
    #pragma unroll
    for (int dy=0; dy<FH; dy++)
      #pragma unroll
      for (int dx=0; dx<FW; dx++) isum += ib[dy*256+dx];
    float img_ds = isum * (1.0f/(FH*FW));
    float d = sval*(1.0f/3.0f) - img_ds;
    mse = d*d;
  }

  #pragma unroll
  for (int off=1; off<64; off<<=1){
    ent += __shfl_xor(ent, off, 64);
    mse += __shfl_xor(mse, off, 64);
  }
  if (lane == 0){ red[wv][0] = ent; red[wv][1] = mse; }
  __syncthreads();
  if (threadIdx.x == 0){
    float e  = red[0][0] + red[1][0] + red[2][0] + red[3][0];
    float ms = red[0][1] + red[1][1] + red[2][1] + red[3][1];
    int slot = blockIdx.x & (NSLOT-1);
    atomicAdd(accbuf + (2*STEP  )*NSLOT + slot, e);
    atomicAdd(accbuf + (2*STEP+1)*NSLOT + slot, ms);
  }
}

// ---------------- maskloss via async LDS staging (WW >= 64) --------------------
// Both-sides swizzle: linear LDS dest, pre-swizzled global source, XOR'd read
// offsets -> 16-way ds_read_b128 conflict removed (verified: conflicts -> 0).
template<int STEP, int DIM, int HH, int WW>
__global__ void maskloss_lds(const bf16* __restrict__ feat, const bf16* __restrict__ mpack,
                             const float* __restrict__ mb, const float* __restrict__ img,
                             const float* __restrict__ masks_in, float* __restrict__ masks_out,
                             float* __restrict__ accbuf){
  constexpr int NBrow = WW/64;
  constexpr int PITCH = 9216;                // 72 px * 128 B
  __shared__ __align__(16) char smem[3*PITCH];
  __shared__ float llog[4][16][4];
  __shared__ float red[4][2];
  int tid = threadIdx.x;
  int lane = tid & 63, wv = tid >> 6;
  int bi = swz8(blockIdx.x, gridDim.x);
  int x0 = (bi % NBrow)*64;
  int y  = (bi / NBrow) % HH;
  int b  = bi / (NBrow*HH);
  int m = lane & 15, quad = lane >> 4;
  int lanesw = ((lane ^ (lane>>3)) << 4);    // pre-swizzled lane*16

  bool rok[3];
  #pragma unroll
  for (int r=0;r<3;r++){ int iy=y+r-1; rok[r] = (iy>=0)&&(iy<HH); }

  for (int k = wv; k < 27; k += 4){
    int r = k/9, coff = (k%9)*1024;
    if (!rok[r]) continue;
    int iy = y + r - 1;
    const char* g = (const char*)(feat + ((size_t)(b*HH+iy)*WW + x0 - 1)*64)
                    + coff + lanesw;
    dma16(g, smem + r*PITCH + coff);
  }
  asm volatile("s_waitcnt vmcnt(0)" ::: "memory");
  __syncthreads();
  if (x0 == 0 && tid < 96)
    ((float*)(smem + (tid>>5)*PITCH))[tid & 31] = 0.f;
  if (x0 + 64 == WW && tid >= 128 && tid < 224){
    int t = tid - 128;
    ((float*)(smem + (t>>5)*PITCH + 65*128))[t & 31] = 0.f;
  }
  __syncthreads();

  const uint4* bp4 = (const uint4*)mpack;
  f32x4 accA = (f32x4){0.f,0.f,0.f,0.f};
  f32x4 accB = (f32x4){0.f,0.f,0.f,0.f};
  #pragma unroll 1
  for (int ky=0; ky<3; ky++){
    if (!rok[ky]) continue;
    const char* rowl = smem + ky*PITCH;
    #pragma unroll
    for (int kx=0; kx<3; kx++){
      int lp = wv*16 + m + kx;
      const char* pl = rowl + (size_t)lp*128;
      int xw = (lp & 7) << 4;
      bf16x8 a0 = __builtin_bit_cast(bf16x8, *(const uint4*)(pl + ((quad*16     ) ^ xw)));
      bf16x8 a1 = __builtin_bit_cast(bf16x8, *(const uint4*)(pl + ((quad*16 + 64) ^ xw)));
      uint4 b0 = bp4[((ky*3+kx)*2+0)*64 + lane];
      uint4 b1 = bp4[((ky*3+kx)*2+1)*64 + lane];
      accA = mfma16(a0, b0, accA);
      accB = mfma16(a1, b1, accB);
    }
  }

  if (m < 4){
    #pragma unroll
    for (int r=0;r<4;r++) llog[wv][quad*4+r][m] = accA[r] + accB[r] + mb[m];
  }
  __syncthreads();

  float ent = 0.f, mse = 0.f;
  if (lane < 16){
    int p = lane; int xx = x0 + wv*16 + p;
    float l0 = llog[wv][p][0], l1 = llog[wv][p][1];
    float l2 = llog[wv][p][2], l3 = llog[wv][p][3];
    float mx = fmaxf(fmaxf(l0,l1), fmaxf(l2,l3));
    float e0=__expf(l0-mx), e1=__expf(l1-mx), e2=__expf(l2-mx), e3=__expf(l3-mx);
    float inv = __builtin_amdgcn_rcpf(e0+e1+e2+e3);
    float p0=e0*inv, p1=e1*inv, p2=e2*inv, p3=e3*inv;
    float sval = p1 + 2.f*p2 + 3.f*p3;

    constexpr int HM = (DIM==0)? HH/2 : HH;
    constexpr int WM = (DIM==0)? WW : WW/2;
    int my = (DIM==0)? (y>>1) : y;
    int mxi = (DIM==1)? (xx>>1) : xx;
    float mv = masks_in[((size_t)b*HM + my)*WM + mxi];
    masks_out[((size_t)b*HH + y)*WW + xx] = mv + 0.25f*sval;

    ent = -(p0*__logf(p0+1e-8f) + p1*__logf(p1+1e-8f) +
            p2*__logf(p2+1e-8f) + p3*__logf(p3+1e-8f));

    constexpr int FH = 256/HH, FW = 256/WW;
    float isum = 0.f;
    const float* ib = img + ((size_t)b*256 + y*FH)*256 + xx*FW;
    #pragma unroll
    for (int dy=0; dy<FH; dy++)
      #pragma unroll
      for (int dx=0; dx<FW; dx++) isum += ib[dy*256+dx];
    float img_ds = isum * (1.0f/(FH*FW));
    float d = sval*(1.0f/3.0f) - img_ds;
    mse = d*d;
  }

  #pragma unroll
  for (int off=1; off<64; off<<=1){
    ent += __shfl_xor(ent, off, 64);
    mse += __shfl_xor(mse, off, 64);
  }
  if (lane == 0){ red[wv][0] = ent; red[wv][1] = mse; }
  __syncthreads();
  if (threadIdx.x == 0){
    float e  = red[0][0] + red[1][0] + red[2][0] + red[3][0];
    float ms = red[0][1] + red[1][1] + red[2][1] + red[3][1];
    int slot = blockIdx.x & (NSLOT-1);
    atomicAdd(accbuf + (2*STEP  )*NSLOT + slot, e);
    atomicAdd(accbuf + (2*STEP+1)*NSLOT + slot, ms);
  }
}

__global__ void finalize_kernel(const float* __restrict__ acc, float* __restrict__ out){
  int lane = threadIdx.x & 63;
  float v[12];
  #pragma unroll
  for (int i=0;i<12;i++){
    float x = acc[i*NSLOT + lane];
    #pragma unroll
    for (int off=1; off<64; off<<=1) x += __shfl_xor(x, off, 64);
    v[i] = x;
  }
  if (lane == 0){
    const float lw[6] = {0.1f,0.1f,0.5f,0.5f,1.0f,1.0f};
    const float nn[6] = {16384.f,32768.f,65536.f,131072.f,262144.f,524288.f};
    float L=0.f;
    for (int i=0;i<6;i++) L += lw[i]*((v[2*i] + v[2*i+1])/nn[i]);
    out[0]=L;
  }
}

extern "C" void kernel_launch(void* const* d_in, const int* in_sizes, int n_in,
                              void* d_out, int out_size, void* d_ws, size_t ws_size,
                              hipStream_t stream){
  const float* image  = (const float*)d_in[0];
  const float* w1=(const float*)d_in[2];  const float* b1=(const float*)d_in[3];
  const float* w2=(const float*)d_in[4];  const float* b2=(const float*)d_in[5];
  const float* w3=(const float*)d_in[6];  const float* b3=(const float*)d_in[7];
  const float* w4=(const float*)d_in[8];  const float* b4=(const float*)d_in[9];
  const float* upw=(const float*)d_in[10];const float* upb=(const float*)d_in[11];
  const float* mw=(const float*)d_in[12]; const float* mb=(const float*)d_in[13];
  const float* masks0=(const float*)d_in[14];
  float* out = (float*)d_out;

  char* ws = (char*)d_ws;
  size_t off = 0;
  auto alloc = [&](size_t bytes)->char*{
    char* p = ws + off; off += (bytes + 255) & ~(size_t)255; return p;
  };
  bf16* enc1  = (bf16*)alloc((size_t)8*256*256*16*2);
  bf16* enc2  = (bf16*)alloc((size_t)8*128*128*16*2);
  bf16* enc3  = (bf16*)alloc((size_t)8*64*64*32*2);
  bf16* featA = (bf16*)alloc((size_t)8*256*256*64*2);
  bf16* featB = (bf16*)alloc((size_t)8*256*128*64*2);
  float* mbA  = (float*)alloc((size_t)8*256*128*4);
  float* mbB  = (float*)alloc((size_t)8*128*128*4);
  bf16* packU = (bf16*)alloc((size_t)9*2*4*64*8*2);
  bf16* packM = (bf16*)alloc((size_t)9*2*64*8*2);
  float* acc  = (float*)alloc(12*NSLOT*sizeof(float));

  hipMemsetAsync(acc, 0, 12*NSLOT*sizeof(float), stream);

  repack_up  <<<144,256,0,stream>>>(upw, packU);
  repack_mask<<< 36,256,0,stream>>>(mw,  packM);

  // encoder
  trio_kernel<float,1,16,1,1,256,256><<<8*256*256/256,256,0,stream>>>(image,w1,b1,enc1);
  trio_kernel<bf16,16,16,2,2,256,256><<<8*128*128*2/256,256,0,stream>>>(enc1,w2,b2,enc2);
  trio_kernel<bf16,16,32,8,2,128,128><<<8*64*64*8/256,256,0,stream>>>(enc2,w3,b3,enc3);
  trio_kernel<bf16,32,64,16,2,64,64><<<8*32*32*16/256,256,0,stream>>>(enc3,w4,b4,featA);

  // step 0: (32,32) -> (64,32)
  upconv_dim0<32,32><<<128,256,0,stream>>>(featA,packU,upb,featB);
  maskloss_mfma<0,0,64,32,2><<<128,256,0,stream>>>(featB,packM,mb,image,masks0,mbA,acc);
  // step 1: (64,32) -> (64,64)
  upconv_dim1<64,32><<<256,256,0,stream>>>(featB,packU,upb,featA);
  maskloss_lds<1,1,64,64><<<512,256,0,stream>>>(featA,packM,mb,image,mbA,mbB,acc);
  // step 2: (64,64) -> (128,64)
  upconv_dim0<64,64><<<512,256,0,stream>>>(featA,packU,upb,featB);
  maskloss_lds<2,0,128,64><<<1024,256,0,stream>>>(featB,packM,mb,image,mbB,mbA,acc);
  // step 3: (128,64) -> (128,128)
  upconv_dim1<128,64><<<1024,256,0,stream>>>(featB,packU,upb,featA);
  maskloss_lds<3,1,128,128><<<2048,256,0,stream>>>(featA,packM,mb,image,mbA,mbB,acc);
  // step 4: (128,128) -> (256,128)
  upconv_dim0<128,128><<<2048,256,0,stream>>>(featA,packU,upb,featB);
  maskloss_lds<4,0,256,128><<<4096,256,0,stream>>>(featB,packM,mb,image,mbB,mbA,acc);
  // step 5: (256,128) -> (256,256)
  upconv_dim1<256,128><<<4096,256,0,stream>>>(featB,packU,upb,featA);
  maskloss_lds<5,1,256,256><<<8192,256,0,stream>>>(featA,packM,mb,image,mbA,out+1,acc);

  finalize_kernel<<<1,64,0,stream>>>(acc,out);
}

// Round 3
// 471.819 us; speedup vs baseline: 1.0005x; 1.0005x over previous
//
#include <hip/hip_runtime.h>
#include <hip/hip_bf16.h>
#include <math.h>

typedef __hip_bfloat16 bf16;
typedef float f32x4 __attribute__((ext_vector_type(4)));
typedef __bf16 bf16x8 __attribute__((ext_vector_type(8)));

#define DEV __device__ __forceinline__

DEV float to_f(float v){ return v; }
DEV float to_f(bf16 v){ return __bfloat162float(v); }
DEV bf16 f2b(float v){ return __float2bfloat16(v); }
DEV unsigned short b2u(bf16 v){ return __builtin_bit_cast(unsigned short, v); }

DEV float gelu_f(float x){
  float z = 1.5957691216057308f*(x + 0.044715f*x*x*x);
  float e = __expf(-z);
  return x * __builtin_amdgcn_rcpf(1.0f + e);
}

DEV bf16x8 load_frag(const bf16* p, bool ok){
  uint4 u = make_uint4(0u,0u,0u,0u);
  if (ok) u = *(const uint4*)p;
  return __builtin_bit_cast(bf16x8, u);
}

DEV f32x4 mfma16(bf16x8 a, uint4 b, f32x4 c){
  return __builtin_amdgcn_mfma_f32_16x16x32_bf16(a, __builtin_bit_cast(bf16x8, b), c, 0, 0, 0);
}

DEV int swz8(int blk, int n){
  return (blk & 7) * (n >> 3) + (blk >> 3);
}

// async global->LDS DMA, 16 B per lane; lds dest wave-uniform base.
DEV void dma16(const void* g, void* l){
  __builtin_amdgcn_global_load_lds(
      (const __attribute__((address_space(1))) unsigned int*)g,
      (__attribute__((address_space(3))) unsigned int*)l,
      16, 0, 0);
}

#define NSLOT 64

// ---------------- encoder Conv_trio -------------------------------------------
template<typename TIN, int CIN, int COUT, int SUB, int STRIDE, int HI, int WI>
__global__ void trio_kernel(const TIN* __restrict__ in, const float* __restrict__ w,
                            const float* __restrict__ bias, bf16* __restrict__ out){
  constexpr int HO = HI/STRIDE, WO = WI/STRIDE;
  constexpr int CO_PER = COUT/SUB;
  int gtid = blockIdx.x*blockDim.x + threadIdx.x;
  int sub = gtid % SUB;
  int pix = gtid / SUB;
  int b = pix / (HO*WO); int rem = pix % (HO*WO);
  int y = rem / WO, x = rem % WO;

  float acc[CO_PER];
  #pragma unroll
  for (int j=0;j<CO_PER;j++) acc[j]=0.f;

  for (int ky=0;ky<3;ky++){
    int iy = (STRIDE==1) ? (y+ky-1) : (2*y+ky);
    if (iy<0 || iy>=HI) continue;
    for (int kx=0;kx<3;kx++){
      int ix = (STRIDE==1) ? (x+kx-1) : (2*x+kx);
      if (ix<0 || ix>=WI) continue;
      const TIN* ip = in + ((size_t)(b*HI+iy)*WI+ix)*CIN;
      const float* wp = w + ((ky*3+kx)*CIN)*COUT + sub*CO_PER;
      if constexpr (sizeof(TIN)==2 && (CIN%8)==0){
        #pragma unroll
        for (int v=0; v<CIN/8; v++){
          uint4 u = *(const uint4*)((const bf16*)ip + v*8);
          bf16x8 ch = __builtin_bit_cast(bf16x8, u);
          #pragma unroll
          for (int j=0;j<8;j++){
            float a = (float)ch[j];
            const float4* w4 = (const float4*)(wp + (size_t)(v*8+j)*COUT);
            #pragma unroll
            for (int q2=0;q2<CO_PER/4;q2++){
              float4 ww = w4[q2];
              acc[4*q2+0] += a*ww.x; acc[4*q2+1] += a*ww.y;
              acc[4*q2+2] += a*ww.z; acc[4*q2+3] += a*ww.w;
            }
          }
        }
      } else {
        #pragma unroll 4
        for (int ci=0; ci<CIN; ci++){
          float a = to_f(ip[ci]);
          const float4* w4 = (const float4*)(wp + (size_t)ci*COUT);
          #pragma unroll
          for (int j=0;j<CO_PER/4;j++){
            float4 ww = w4[j];
            acc[4*j+0] += a*ww.x; acc[4*j+1] += a*ww.y;
            acc[4*j+2] += a*ww.z; acc[4*j+3] += a*ww.w;
          }
        }
      }
    }
  }

  float s1=0.f, s2=0.f;
  #pragma unroll
  for (int j=0;j<CO_PER;j++){
    acc[j] += bias[sub*CO_PER+j];
    s1 += acc[j]; s2 += acc[j]*acc[j];
  }
  #pragma unroll
  for (int off=1; off<SUB; off<<=1){
    s1 += __shfl_xor(s1,off,64);
    s2 += __shfl_xor(s2,off,64);
  }
  float mu  = s1*(1.0f/COUT);
  float var = s2*(1.0f/COUT) - mu*mu;
  float sc  = rsqrtf(var + 1e-6f);

  bf16* op = out + (size_t)pix*COUT + sub*CO_PER;
  #pragma unroll
  for (int j=0;j<CO_PER;j++) op[j] = f2b(gelu_f((acc[j]-mu)*sc));
}

// ---------------- weight repack -----------------------------------------------
__global__ void repack_up(const float* __restrict__ w, bf16* __restrict__ bp){
  int v = blockIdx.x*256 + threadIdx.x;
  if (v >= 9*2*4*64*8) return;
  int j = v & 7; int lane = (v>>3)&63; int nt = (v>>9)&3; int c = (v>>11)&1; int tap = v>>12;
  int ci = c*32 + (lane>>4)*8 + j;
  int co = (lane&15)*4 + nt;
  bp[v] = f2b(w[(tap*64+ci)*64 + co]);
}

__global__ void repack_mask(const float* __restrict__ w, bf16* __restrict__ bp){
  int v = blockIdx.x*256 + threadIdx.x;
  if (v >= 9*2*64*8) return;
  int j = v & 7; int lane = (v>>3)&63; int c = (v>>9)&1; int tap = v>>10;
  int ci = c*32 + (lane>>4)*8 + j;
  int n = lane & 15;
  bp[v] = (n < 4) ? f2b(w[(tap*64+ci)*4 + n]) : f2b(0.0f);
}

// ------------- conv_transpose, stride-2 along y (DIM=0) -----------------------
template<int HI, int WI>
__global__ void upconv_dim0(const bf16* __restrict__ in, const bf16* __restrict__ bpack,
                            const float* __restrict__ upb, bf16* __restrict__ out){
  constexpr int HO = 2*HI, WO = WI, XT = WI/32;
  int lane = threadIdx.x & 63, wv = threadIdx.x >> 6;
  int wtile = swz8(blockIdx.x, gridDim.x)*4 + wv;
  int m = lane & 15, quad = lane >> 4;

  int x0 = (wtile % XT)*32;
  int o  = (wtile / XT) % HO;
  int b  = wtile / (XT*HO);

  int q = o >> 1;
  int stk[2], stq[2]; int nst;
  if (o & 1){ stk[0]=1; stq[0]=q; nst=1; }
  else {
    nst = 0;
    if (q >= 1){ stk[0]=0; stq[0]=q-1; nst=1; }
    stk[nst]=2; stq[nst]=q; nst++;
  }

  f32x4 acc[2][4];
  #pragma unroll
  for (int t=0;t<2;t++)
    #pragma unroll
    for (int nt=0;nt<4;nt++) acc[t][nt] = (f32x4){0.f,0.f,0.f,0.f};

  const uint4* bp4 = (const uint4*)bpack;

  #pragma unroll 1
  for (int s=0; s<nst; s++){
    int kyt = stk[s];
    const bf16* rowp = in + ((size_t)(b*HI+stq[s])*WI)*64 + quad*8;
    #pragma unroll
    for (int ut=0; ut<3; ut++){
      #pragma unroll
      for (int c=0;c<2;c++){
        int ix0 = x0 + m - 1 + ut;
        int ix1 = ix0 + 16;
        bf16x8 a0 = load_frag(rowp + (size_t)ix0*64 + c*32, ix0>=0 && ix0<WI);
        bf16x8 a1 = load_frag(rowp + (size_t)ix1*64 + c*32, ix1>=0 && ix1<WI);
        #pragma unroll
        for (int nt=0;nt<4;nt++){
          uint4 Bq = bp4[(((kyt*3+ut)*2+c)*4+nt)*64 + lane];
          acc[0][nt] = mfma16(a0, Bq, acc[0][nt]);
          acc[1][nt] = mfma16(a1, Bq, acc[1][nt]);
        }
      }
    }
  }

  float4 bv = *(const float4*)(upb + m*4);
  size_t rowbase = ((size_t)b*HO + o)*WO;
  #pragma unroll
  for (int t=0;t<2;t++){
    #pragma unroll
    for (int r=0;r<4;r++){
      int p = x0 + t*16 + quad*4 + r;
      float g0 = gelu_f(acc[t][0][r] + bv.x);
      float g1 = gelu_f(acc[t][1][r] + bv.y);
      float g2 = gelu_f(acc[t][2][r] + bv.z);
      float g3 = gelu_f(acc[t][3][r] + bv.w);
      unsigned int lo = (unsigned int)b2u(f2b(g0)) | ((unsigned int)b2u(f2b(g1))<<16);
      unsigned int hi = (unsigned int)b2u(f2b(g2)) | ((unsigned int)b2u(f2b(g3))<<16);
      *(uint2*)(out + (rowbase + p)*64 + m*4) = make_uint2(lo,hi);
    }
  }
}

// ------------- conv_transpose dim1, register form — small grids (step 1) ------
template<int HI, int WI>
__global__ void upconv_dim1(const bf16* __restrict__ in, const bf16* __restrict__ bpack,
                            const float* __restrict__ upb, bf16* __restrict__ out){
  constexpr int HO = HI, WO = 2*WI, QT = WI/16;
  int lane = threadIdx.x & 63, wv = threadIdx.x >> 6;
  int wtile = swz8(blockIdx.x, gridDim.x)*4 + wv;
  int m = lane & 15, quad = lane >> 4;

  int q0 = (wtile % QT)*16;
  int y  = (wtile / QT) % HI;
  int b  = wtile / (QT*HI);

  f32x4 ae[4], ao[4];
  #pragma unroll
  for (int nt=0;nt<4;nt++){ ae[nt]=(f32x4){0.f,0.f,0.f,0.f}; ao[nt]=(f32x4){0.f,0.f,0.f,0.f}; }

  const uint4* bp4 = (const uint4*)bpack;

  #pragma unroll 1
  for (int ky=0; ky<3; ky++){
    int iy = y + ky - 1;
    if (iy < 0 || iy >= HI) continue;
    const bf16* rowp = in + ((size_t)(b*HI+iy)*WI)*64 + quad*8;
    #pragma unroll
    for (int c=0;c<2;c++){
      int qa = q0 + m;
      bf16x8 Au = load_frag(rowp + (size_t)qa*64 + c*32, true);
      bf16x8 As = load_frag(rowp + (size_t)(qa-1)*64 + c*32, qa >= 1);
      #pragma unroll
      for (int nt=0;nt<4;nt++){
        uint4 B0 = bp4[(((ky*3+0)*2+c)*4+nt)*64 + lane];
        uint4 B1 = bp4[(((ky*3+1)*2+c)*4+nt)*64 + lane];
        uint4 B2 = bp4[(((ky*3+2)*2+c)*4+nt)*64 + lane];
        ae[nt] = mfma16(As, B0, ae[nt]);
        ae[nt] = mfma16(Au, B2, ae[nt]);
        ao[nt] = mfma16(Au, B1, ao[nt]);
      }
    }
  }

  float4 bv = *(const float4*)(upb + m*4);
  size_t rowbase = ((size_t)b*HO + y)*WO;
  #pragma unroll
  for (int r=0;r<4;r++){
    int qq = q0 + quad*4 + r;
    {
      float g0 = gelu_f(ae[0][r] + bv.x);
      float g1 = gelu_f(ae[1][r] + bv.y);
      float g2 = gelu_f(ae[2][r] + bv.z);
      float g3 = gelu_f(ae[3][r] + bv.w);
      unsigned int lo = (unsigned int)b2u(f2b(g0)) | ((unsigned int)b2u(f2b(g1))<<16);
      unsigned int hi = (unsigned int)b2u(f2b(g2)) | ((unsigned int)b2u(f2b(g3))<<16);
      *(uint2*)(out + (rowbase + 2*qq)*64 + m*4) = make_uint2(lo,hi);
    }
    {
      float g0 = gelu_f(ao[0][r] + bv.x);
      float g1 = gelu_f(ao[1][r] + bv.y);
      float g2 = gelu_f(ao[2][r] + bv.z);
      float g3 = gelu_f(ao[3][r] + bv.w);
      unsigned int lo = (unsigned int)b2u(f2b(g0)) | ((unsigned int)b2u(f2b(g1))<<16);
      unsigned int hi = (unsigned int)b2u(f2b(g2)) | ((unsigned int)b2u(f2b(g3))<<16);
      *(uint2*)(out + (rowbase + 2*qq+1)*64 + m*4) = make_uint2(lo,hi);
    }
  }
}

// ------------- conv_transpose dim1, 2-ROW per wave (B-traffic amortized) ------
// The kernel chain is L2-BW bound on the 72 KB weight-pack refetch per wave
// (exceeds 32 KB L1). Each wave computes 2 adjacent output rows: the 16
// A-fragments (4 input rows x 2c x {Au,As}) are hoisted into registers, then
// each B fragment is loaded ONCE and used for both rows -> B bytes per output
// row halve (72->36 KB), A per row 24->8 KB. No LDS, no barriers.
template<int HI, int WI>
__global__ void __launch_bounds__(256,2)
upconv_dim1_r2(const bf16* __restrict__ in, const bf16* __restrict__ bpack,
               const float* __restrict__ upb, bf16* __restrict__ out){
  constexpr int HO = HI, WO = 2*WI, QT = WI/16;
  int lane = threadIdx.x & 63, wv = threadIdx.x >> 6;
  int wtile = swz8(blockIdx.x, gridDim.x)*4 + wv;
  int m = lane & 15, quad = lane >> 4;

  int q0 = (wtile % QT)*16;
  int y  = ((wtile / QT) % (HI/2)) * 2;
  int b  = wtile / (QT*(HI/2));

  int qa = q0 + m;

  // A fragments: input rows y-1 .. y+2
  bf16x8 Afr[4][2][2];              // [row4][c][{Au,As}]
  #pragma unroll
  for (int i4=0;i4<4;i4++){
    int iy = y + i4 - 1;
    bool ok = (iy>=0) && (iy<HI);
    const bf16* rowp = in + ((size_t)(b*HI+iy)*WI)*64 + quad*8;
    #pragma unroll
    for (int c=0;c<2;c++){
      Afr[i4][c][0] = load_frag(rowp + (size_t)qa*64 + c*32, ok);
      Afr[i4][c][1] = load_frag(rowp + (size_t)(qa-1)*64 + c*32, ok && qa >= 1);
    }
  }

  f32x4 ae[2][4], ao[2][4];
  #pragma unroll
  for (int r=0;r<2;r++)
    #pragma unroll
    for (int nt=0;nt<4;nt++){ ae[r][nt]=(f32x4){0.f,0.f,0.f,0.f}; ao[r][nt]=(f32x4){0.f,0.f,0.f,0.f}; }

  const uint4* bp4 = (const uint4*)bpack;

  #pragma unroll
  for (int ky=0; ky<3; ky++){
    #pragma unroll
    for (int c=0;c<2;c++){
      #pragma unroll
      for (int nt=0;nt<4;nt++){
        uint4 B0 = bp4[(((ky*3+0)*2+c)*4+nt)*64 + lane];
        uint4 B1 = bp4[(((ky*3+1)*2+c)*4+nt)*64 + lane];
        uint4 B2 = bp4[(((ky*3+2)*2+c)*4+nt)*64 + lane];
        #pragma unroll
        for (int r=0;r<2;r++){
          ae[r][nt] = mfma16(Afr[ky+r][c][1], B0, ae[r][nt]);
          ae[r][nt] = mfma16(Afr[ky+r][c][0], B2, ae[r][nt]);
          ao[r][nt] = mfma16(Afr[ky+r][c][0], B1, ao[r][nt]);
        }
      }
    }
  }

  float4 bv = *(const float4*)(upb + m*4);
  #pragma unroll
  for (int r2=0;r2<2;r2++){
    size_t rowbase = ((size_t)b*HO + y + r2)*WO;
    #pragma unroll
    for (int r=0;r<4;r++){
      int qq = q0 + quad*4 + r;
      {
        float g0 = gelu_f(ae[r2][0][r] + bv.x);
        float g1 = gelu_f(ae[r2][1][r] + bv.y);
        float g2 = gelu_f(ae[r2][2][r] + bv.z);
        float g3 = gelu_f(ae[r2][3][r] + bv.w);
        unsigned int lo = (unsigned int)b2u(f2b(g0)) | ((unsigned int)b2u(f2b(g1))<<16);
        unsigned int hi = (unsigned int)b2u(f2b(g2)) | ((unsigned int)b2u(f2b(g3))<<16);
        *(uint2*)(out + (rowbase + 2*qq)*64 + m*4) = make_uint2(lo,hi);
      }
      {
        float g0 = gelu_f(ao[r2][0][r] + bv.x);
        float g1 = gelu_f(ao[r2][1][r] + bv.y);
        float g2 = gelu_f(ao[r2][2][r] + bv.z);
        float g3 = gelu_f(ao[r2][3][r] + bv.w);
        unsigned int lo = (unsigned int)b2u(f2b(g0)) | ((unsigned int)b2u(f2b(g1))<<16);
        unsigned int hi = (unsigned int)b2u(f2b(g2)) | ((unsigned int)b2u(f2b(g3))<<16);
        *(uint2*)(out + (rowbase + 2*qq+1)*64 + m*4) = make_uint2(lo,hi);
      }
    }
  }
}

// ---------------- maskloss, register form — step 0 only ------------------------
template<int STEP, int DIM, int HH, int WW, int TILES>
__global__ void maskloss_mfma(const bf16* __restrict__ feat, const bf16* __restrict__ mpack,
                              const float* __restrict__ mb, const float* __restrict__ img,
                              const float* __restrict__ masks_in, float* __restrict__ masks_out,
                              float* __restrict__ accbuf){
  __shared__ float llog[4][64][4];
  __shared__ float red[4][2];
  int lane = threadIdx.x & 63;
  int wv   = threadIdx.x >> 6;
  int wtile = swz8(blockIdx.x, gridDim.x)*4 + wv;
  int m = lane & 15, quad = lane >> 4;

  constexpr int TPR = WW/(16*TILES);
  int x0 = (wtile % TPR)*(16*TILES);
  int y  = (wtile / TPR) % HH;
  int b  = wtile / (TPR*HH);

  const uint4* bp4 = (const uint4*)mpack;

  #pragma unroll 1
  for (int t=0; t<TILES; t++){
    f32x4 acc4 = (f32x4){0.f,0.f,0.f,0.f};
    #pragma unroll
    for (int c=0;c<2;c++){
      bf16x8 afr[9];
      #pragma unroll
      for (int ky=0; ky<3; ky++){
        int iy = y + ky - 1;
        bool rowok = (iy >= 0) && (iy < HH);
        const bf16* rowp = feat + ((size_t)(b*HH+iy)*WW)*64 + quad*8 + c*32;
        #pragma unroll
        for (int kx=0; kx<3; kx++){
          int ix = x0 + t*16 + m + kx - 1;
          bool ok = rowok && (ix >= 0) && (ix < WW);
          afr[ky*3+kx] = load_frag(rowp + (size_t)ix*64, ok);
        }
      }
      #pragma unroll
      for (int tap=0; tap<9; tap++){
        uint4 bb = bp4[(tap*2+c)*64 + lane];
        acc4 = mfma16(afr[tap], bb, acc4);
      }
    }
    if (m < 4){
      #pragma unroll
      for (int r=0;r<4;r++) llog[wv][t*16 + quad*4 + r][m] = acc4[r] + mb[m];
    }
  }
  __syncthreads();

  float ent = 0.f, mse = 0.f;
  if (lane < 16*TILES){
    int p = lane; int xx = x0 + p;
    float l0 = llog[wv][p][0], l1 = llog[wv][p][1];
    float l2 = llog[wv][p][2], l3 = llog[wv][p][3];
    float mx = fmaxf(fmaxf(l0,l1), fmaxf(l2,l3));
    float e0=__expf(l0-mx), e1=__expf(l1-mx), e2=__expf(l2-mx), e3=__expf(l3-mx);
    float inv = __builtin_amdgcn_rcpf(e0+e1+e2+e3);
    float p0=e0*inv, p1=e1*inv, p2=e2*inv, p3=e3*inv;
    float sval = p1 + 2.f*p2 + 3.f*p3;

    constexpr int HM = (DIM==0)? HH/2 : HH;
    constexpr int WM = (DIM==0)? WW : WW/2;
    int my = (DIM==0)? (y>>1) : y;
    int mxi = (DIM==1)? (xx>>1) : xx;
    float mv = masks_in[((size_t)b*HM + my)*WM + mxi];
    masks_out[((size_t)b*HH + y)*WW + xx] = mv + 0.25f*sval;

    ent = -(p0*__logf(p0+1e-8f) + p1*__logf(p1+1e-8f) +
            p2*__logf(p2+1e-8f) + p3*__logf(p3+1e-8f));

    constexpr int FH = 256/HH, FW = 256/WW;
    float isum = 0.f;
    const float* ib = img + ((size_t)b*256 + y*FH)*256 + xx*FW;
    #pragma unroll
    for (int dy=0; dy<FH; dy++)
      #pragma unroll
      for (int dx=0; dx<FW; dx++) isum += ib[dy*256+dx];
    float img_ds = isum * (1.0f/(FH*FW));
    float d = sval*(1.0f/3.0f) - img_ds;
    mse = d*d;
  }

  #pragma unroll
  for (int off=1; off<64; off<<=1){
    ent += __shfl_xor(ent, off, 64);
    mse += __shfl_xor(mse, off, 64);
  }
  if (lane == 0){ red[wv][0] = ent; red[wv][1] = mse; }
  __syncthreads();
  if (threadIdx.x == 0){
    float e  = red[0][0] + red[1][0] + red[2][0] + red[3][0];
    float ms = red[0][1] + red[1][1] + red[2][1] + red[3][1];
    int slot = blockIdx.x & (NSLOT-1);
    atomicAdd(accbuf + (2*STEP  )*NSLOT + slot, e);
    atomicAdd(accbuf + (2*STEP+1)*NSLOT + slot, ms);
  }
}

// ---------------- maskloss via async LDS staging (WW >= 64) --------------------
// Both-sides swizzle: linear LDS dest, pre-swizzled global source, XOR'd read
// offsets -> 16-way ds_read_b128 conflict removed (verified: conflicts -> 0).
template<int STEP, int DIM, int HH, int WW>
__global__ void maskloss_lds(const bf16* __restrict__ feat, const bf16* __restrict__ mpack,
                             const float* __restrict__ mb, const float* __restrict__ img,
                             const float* __restrict__ masks_in, float* __restrict__ masks_out,
                             float* __restrict__ accbuf){
  constexpr int NBrow = WW/64;
  constexpr int PITCH = 9216;                // 72 px * 128 B
  __shared__ __align__(16) char smem[3*PITCH];
  __shared__ float llog[4][16][4];
  __shared__ float red[4][2];
  int tid = threadIdx.x;
  int lane = tid & 63, wv = tid >> 6;
  int bi = swz8(blockIdx.x, gridDim.x);
  int x0 = (bi % NBrow)*64;
  int y  = (bi / NBrow) % HH;
  int b  = bi / (NBrow*HH);
  int m = lane & 15, quad = lane >> 4;
  int lanesw = ((lane ^ (lane>>3)) << 4);    // pre-swizzled lane*16

  bool rok[3];
  #pragma unroll
  for (int r=0;r<3;r++){ int iy=y+r-1; rok[r] = (iy>=0)&&(iy<HH); }

  for (int k = wv; k < 27; k += 4){
    int r = k/9, coff = (k%9)*1024;
    if (!rok[r]) continue;
    int iy = y + r - 1;
    const char* g = (const char*)(feat + ((size_t)(b*HH+iy)*WW + x0 - 1)*64)
                    + coff + lanesw;
    dma16(g, smem + r*PITCH + coff);
  }
  asm volatile("s_waitcnt vmcnt(0)" ::: "memory");
  __syncthreads();
  if (x0 == 0 && tid < 96)
    ((float*)(smem + (tid>>5)*PITCH))[tid & 31] = 0.f;
  if (x0 + 64 == WW && tid >= 128 && tid < 224){
    int t = tid - 128;
    ((float*)(smem + (t>>5)*PITCH + 65*128))[t & 31] = 0.f;
  }
  __syncthreads();

  const uint4* bp4 = (const uint4*)mpack;
  f32x4 accA = (f32x4){0.f,0.f,0.f,0.f};
  f32x4 accB = (f32x4){0.f,0.f,0.f,0.f};
  #pragma unroll 1
  for (int ky=0; ky<3; ky++){
    if (!rok[ky]) continue;
    const char* rowl = smem + ky*PITCH;
    #pragma unroll
    for (int kx=0; kx<3; kx++){
      int lp = wv*16 + m + kx;
      const char* pl = rowl + (size_t)lp*128;
      int xw = (lp & 7) << 4;
      bf16x8 a0 = __builtin_bit_cast(bf16x8, *(const uint4*)(pl + ((quad*16     ) ^ xw)));
      bf16x8 a1 = __builtin_bit_cast(bf16x8, *(const uint4*)(pl + ((quad*16 + 64) ^ xw)));
      uint4 b0 = bp4[((ky*3+kx)*2+0)*64 + lane];
      uint4 b1 = bp4[((ky*3+kx)*2+1)*64 + lane];
      accA = mfma16(a0, b0, accA);
      accB = mfma16(a1, b1, accB);
    }
  }

  if (m < 4){
    #pragma unroll
    for (int r=0;r<4;r++) llog[wv][quad*4+r][m] = accA[r] + accB[r] + mb[m];
  }
  __syncthreads();

  float ent = 0.f, mse = 0.f;
  if (lane < 16){
    int p = lane; int xx = x0 + wv*16 + p;
    float l0 = llog[wv][p][0], l1 = llog[wv][p][1];
    float l2 = llog[wv][p][2], l3 = llog[wv][p][3];
    float mx = fmaxf(fmaxf(l0,l1), fmaxf(l2,l3));
    float e0=__expf(l0-mx), e1=__expf(l1-mx), e2=__expf(l2-mx), e3=__expf(l3-mx);
    float inv = __builtin_amdgcn_rcpf(e0+e1+e2+e3);
    float p0=e0*inv, p1=e1*inv, p2=e2*inv, p3=e3*inv;
    float sval = p1 + 2.f*p2 + 3.f*p3;

    constexpr int HM = (DIM==0)? HH/2 : HH;
    constexpr int WM = (DIM==0)? WW : WW/2;
    int my = (DIM==0)? (y>>1) : y;
    int mxi = (DIM==1)? (xx>>1) : xx;
    float mv = masks_in[((size_t)b*HM + my)*WM + mxi];
    masks_out[((size_t)b*HH + y)*WW + xx] = mv + 0.25f*sval;

    ent = -(p0*__logf(p0+1e-8f) + p1*__logf(p1+1e-8f) +
            p2*__logf(p2+1e-8f) + p3*__logf(p3+1e-8f));

    constexpr int FH = 256/HH, FW = 256/WW;
    float isum = 0.f;
    const float* ib = img + ((size_t)b*256 + y*FH)*256 + xx*FW;
    #pragma unroll
    for (int dy=0; dy<FH; dy++)
      #pragma unroll
      for (int dx=0; dx<FW; dx++) isum += ib[dy*256+dx];
    float img_ds = isum * (1.0f/(FH*FW));
    float d = sval*(1.0f/3.0f) - img_ds;
    mse = d*d;
  }

  #pragma unroll
  for (int off=1; off<64; off<<=1){
    ent += __shfl_xor(ent, off, 64);
    mse += __shfl_xor(mse, off, 64);
  }
  if (lane == 0){ red[wv][0] = ent; red[wv][1] = mse; }
  __syncthreads();
  if (threadIdx.x == 0){
    float e  = red[0][0] + red[1][0] + red[2][0] + red[3][0];
    float ms = red[0][1] + red[1][1] + red[2][1] + red[3][1];
    int slot = blockIdx.x & (NSLOT-1);
    atomicAdd(accbuf + (2*STEP  )*NSLOT + slot, e);
    atomicAdd(accbuf + (2*STEP+1)*NSLOT + slot, ms);
  }
}

__global__ void finalize_kernel(const float* __restrict__ acc, float* __restrict__ out){
  int lane = threadIdx.x & 63;
  float v[12];
  #pragma unroll
  for (int i=0;i<12;i++){
    float x = acc[i*NSLOT + lane];
    #pragma unroll
    for (int off=1; off<64; off<<=1) x += __shfl_xor(x, off, 64);
    v[i] = x;
  }
  if (lane == 0){
    const float lw[6] = {0.1f,0.1f,0.5f,0.5f,1.0f,1.0f};
    const float nn[6] = {16384.f,32768.f,65536.f,131072.f,262144.f,524288.f};
    float L=0.f;
    for (int i=0;i<6;i++) L += lw[i]*((v[2*i] + v[2*i+1])/nn[i]);
    out[0]=L;
  }
}

extern "C" void kernel_launch(void* const* d_in, const int* in_sizes, int n_in,
                              void* d_out, int out_size, void* d_ws, size_t ws_size,
                              hipStream_t stream){
  const float* image  = (const float*)d_in[0];
  const float* w1=(const float*)d_in[2];  const float* b1=(const float*)d_in[3];
  const float* w2=(const float*)d_in[4];  const float* b2=(const float*)d_in[5];
  const float* w3=(const float*)d_in[6];  const float* b3=(const float*)d_in[7];
  const float* w4=(const float*)d_in[8];  const float* b4=(const float*)d_in[9];
  const float* upw=(const float*)d_in[10];const float* upb=(const float*)d_in[11];
  const float* mw=(const float*)d_in[12]; const float* mb=(const float*)d_in[13];
  const float* masks0=(const float*)d_in[14];
  float* out = (float*)d_out;

  char* ws = (char*)d_ws;
  size_t off = 0;
  auto alloc = [&](size_t bytes)->char*{
    char* p = ws + off; off += (bytes + 255) & ~(size_t)255; return p;
  };
  bf16* enc1  = (bf16*)alloc((size_t)8*256*256*16*2);
  bf16* enc2  = (bf16*)alloc((size_t)8*128*128*16*2);
  bf16* enc3  = (bf16*)alloc((size_t)8*64*64*32*2);
  bf16* featA = (bf16*)alloc((size_t)8*256*256*64*2);
  bf16* featB = (bf16*)alloc((size_t)8*256*128*64*2);
  float* mbA  = (float*)alloc((size_t)8*256*128*4);
  float* mbB  = (float*)alloc((size_t)8*128*128*4);
  bf16* packU = (bf16*)alloc((size_t)9*2*4*64*8*2);
  bf16* packM = (bf16*)alloc((size_t)9*2*64*8*2);
  float* acc  = (float*)alloc(12*NSLOT*sizeof(float));

  hipMemsetAsync(acc, 0, 12*NSLOT*sizeof(float), stream);

  repack_up  <<<144,256,0,stream>>>(upw, packU);
  repack_mask<<< 36,256,0,stream>>>(mw,  packM);

  // encoder
  trio_kernel<float,1,16,1,1,256,256><<<8*256*256/256,256,0,stream>>>(image,w1,b1,enc1);
  trio_kernel<bf16,16,16,2,2,256,256><<<8*128*128*2/256,256,0,stream>>>(enc1,w2,b2,enc2);
  trio_kernel<bf16,16,32,8,2,128,128><<<8*64*64*8/256,256,0,stream>>>(enc2,w3,b3,enc3);
  trio_kernel<bf16,32,64,16,2,64,64><<<8*32*32*16/256,256,0,stream>>>(enc3,w4,b4,featA);

  // step 0: (32,32) -> (64,32)
  upconv_dim0<32,32><<<128,256,0,stream>>>(featA,packU,upb,featB);
  maskloss_mfma<0,0,64,32,2><<<128,256,0,stream>>>(featB,packM,mb,image,masks0,mbA,acc);
  // step 1: (64,32) -> (64,64)
  upconv_dim1<64,32><<<256,256,0,stream>>>(featB,packU,upb,featA);
  maskloss_lds<1,1,64,64><<<512,256,0,stream>>>(featA,packM,mb,image,mbA,mbB,acc);
  // step 2: (64,64) -> (128,64)
  upconv_dim0<64,64><<<512,256,0,stream>>>(featA,packU,upb,featB);
  maskloss_lds<2,0,128,64><<<1024,256,0,stream>>>(featB,packM,mb,image,mbB,mbA,acc);
  // step 3: (128,64) -> (128,128)  [2-row waves: 2048 wtiles -> 512 blocks]
  upconv_dim1_r2<128,64><<<512,256,0,stream>>>(featB,packU,upb,featA);
  maskloss_lds<3,1,128,128><<<2048,256,0,stream>>>(featA,packM,mb,image,mbA,mbB,acc);
  // step 4: (128,128) -> (256,128)
  upconv_dim0<128,128><<<2048,256,0,stream>>>(featA,packU,upb,featB);
  maskloss_lds<4,0,256,128><<<4096,256,0,stream>>>(featB,packM,mb,image,mbB,mbA,acc);
  // step 5: (256,128) -> (256,256) [2-row waves: 8192 wtiles -> 2048 blocks]
  upconv_dim1_r2<256,128><<<2048,256,0,stream>>>(featB,packU,upb,featA);
  maskloss_lds<5,1,256,256><<<8192,256,0,stream>>>(featA,packM,mb,image,mbA,out+1,acc);

  finalize_kernel<<<1,64,0,stream>>>(acc,out);
}

// Round 4
// 447.051 us; speedup vs baseline: 1.0559x; 1.0554x over previous
//
#include <hip/hip_runtime.h>
#include <hip/hip_bf16.h>
#include <math.h>

typedef __hip_bfloat16 bf16;
typedef float f32x4 __attribute__((ext_vector_type(4)));
typedef __bf16 bf16x8 __attribute__((ext_vector_type(8)));

#define DEV __device__ __forceinline__

DEV float to_f(float v){ return v; }
DEV float to_f(bf16 v){ return __bfloat162float(v); }
DEV bf16 f2b(float v){ return __float2bfloat16(v); }
DEV unsigned short b2u(bf16 v){ return __builtin_bit_cast(unsigned short, v); }

DEV float gelu_f(float x){
  float z = 1.5957691216057308f*(x + 0.044715f*x*x*x);
  float e = __expf(-z);
  return x * __builtin_amdgcn_rcpf(1.0f + e);
}

DEV bf16x8 load_frag(const bf16* p, bool ok){
  uint4 u = make_uint4(0u,0u,0u,0u);
  if (ok) u = *(const uint4*)p;
  return __builtin_bit_cast(bf16x8, u);
}

DEV f32x4 mfma16(bf16x8 a, uint4 b, f32x4 c){
  return __builtin_amdgcn_mfma_f32_16x16x32_bf16(a, __builtin_bit_cast(bf16x8, b), c, 0, 0, 0);
}

DEV int swz8(int blk, int n){
  return (blk & 7) * (n >> 3) + (blk >> 3);
}

// async global->LDS DMA, 16 B per lane; lds dest wave-uniform base.
DEV void dma16(const void* g, void* l){
  __builtin_amdgcn_global_load_lds(
      (const __attribute__((address_space(1))) unsigned int*)g,
      (__attribute__((address_space(3))) unsigned int*)l,
      16, 0, 0);
}

#define NSLOT 64

// ---------------- encoder Conv_trio -------------------------------------------
template<typename TIN, int CIN, int COUT, int SUB, int STRIDE, int HI, int WI>
__global__ void trio_kernel(const TIN* __restrict__ in, const float* __restrict__ w,
                            const float* __restrict__ bias, bf16* __restrict__ out){
  constexpr int HO = HI/STRIDE, WO = WI/STRIDE;
  constexpr int CO_PER = COUT/SUB;
  int gtid = blockIdx.x*blockDim.x + threadIdx.x;
  int sub = gtid % SUB;
  int pix = gtid / SUB;
  int b = pix / (HO*WO); int rem = pix % (HO*WO);
  int y = rem / WO, x = rem % WO;

  float acc[CO_PER];
  #pragma unroll
  for (int j=0;j<CO_PER;j++) acc[j]=0.f;

  for (int ky=0;ky<3;ky++){
    int iy = (STRIDE==1) ? (y+ky-1) : (2*y+ky);
    if (iy<0 || iy>=HI) continue;
    for (int kx=0;kx<3;kx++){
      int ix = (STRIDE==1) ? (x+kx-1) : (2*x+kx);
      if (ix<0 || ix>=WI) continue;
      const TIN* ip = in + ((size_t)(b*HI+iy)*WI+ix)*CIN;
      const float* wp = w + ((ky*3+kx)*CIN)*COUT + sub*CO_PER;
      if constexpr (sizeof(TIN)==2 && (CIN%8)==0){
        #pragma unroll
        for (int v=0; v<CIN/8; v++){
          uint4 u = *(const uint4*)((const bf16*)ip + v*8);
          bf16x8 ch = __builtin_bit_cast(bf16x8, u);
          #pragma unroll
          for (int j=0;j<8;j++){
            float a = (float)ch[j];
            const float4* w4 = (const float4*)(wp + (size_t)(v*8+j)*COUT);
            #pragma unroll
            for (int q2=0;q2<CO_PER/4;q2++){
              float4 ww = w4[q2];
              acc[4*q2+0] += a*ww.x; acc[4*q2+1] += a*ww.y;
              acc[4*q2+2] += a*ww.z; acc[4*q2+3] += a*ww.w;
            }
          }
        }
      } else {
        #pragma unroll 4
        for (int ci=0; ci<CIN; ci++){
          float a = to_f(ip[ci]);
          const float4* w4 = (const float4*)(wp + (size_t)ci*COUT);
          #pragma unroll
          for (int j=0;j<CO_PER/4;j++){
            float4 ww = w4[j];
            acc[4*j+0] += a*ww.x; acc[4*j+1] += a*ww.y;
            acc[4*j+2] += a*ww.z; acc[4*j+3] += a*ww.w;
          }
        }
      }
    }
  }

  float s1=0.f, s2=0.f;
  #pragma unroll
  for (int j=0;j<CO_PER;j++){
    acc[j] += bias[sub*CO_PER+j];
    s1 += acc[j]; s2 += acc[j]*acc[j];
  }
  #pragma unroll
  for (int off=1; off<SUB; off<<=1){
    s1 += __shfl_xor(s1,off,64);
    s2 += __shfl_xor(s2,off,64);
  }
  float mu  = s1*(1.0f/COUT);
  float var = s2*(1.0f/COUT) - mu*mu;
  float sc  = rsqrtf(var + 1e-6f);

  bf16* op = out + (size_t)pix*COUT + sub*CO_PER;
  #pragma unroll
  for (int j=0;j<CO_PER;j++) op[j] = f2b(gelu_f((acc[j]-mu)*sc));
}

// ---------------- weight repack -----------------------------------------------
__global__ void repack_up(const float* __restrict__ w, bf16* __restrict__ bp){
  int v = blockIdx.x*256 + threadIdx.x;
  if (v >= 9*2*4*64*8) return;
  int j = v & 7; int lane = (v>>3)&63; int nt = (v>>9)&3; int c = (v>>11)&1; int tap = v>>12;
  int ci = c*32 + (lane>>4)*8 + j;
  int co = (lane&15)*4 + nt;
  bp[v] = f2b(w[(tap*64+ci)*64 + co]);
}

__global__ void repack_mask(const float* __restrict__ w, bf16* __restrict__ bp){
  int v = blockIdx.x*256 + threadIdx.x;
  if (v >= 9*2*64*8) return;
  int j = v & 7; int lane = (v>>3)&63; int c = (v>>9)&1; int tap = v>>10;
  int ci = c*32 + (lane>>4)*8 + j;
  int n = lane & 15;
  bp[v] = (n < 4) ? f2b(w[(tap*64+ci)*4 + n]) : f2b(0.0f);
}

// ------------- conv_transpose, stride-2 along y (DIM=0) -----------------------
template<int HI, int WI>
__global__ void upconv_dim0(const bf16* __restrict__ in, const bf16* __restrict__ bpack,
                            const float* __restrict__ upb, bf16* __restrict__ out){
  constexpr int HO = 2*HI, WO = WI, XT = WI/32;
  int lane = threadIdx.x & 63, wv = threadIdx.x >> 6;
  int wtile = swz8(blockIdx.x, gridDim.x)*4 + wv;
  int m = lane & 15, quad = lane >> 4;

  int x0 = (wtile % XT)*32;
  int o  = (wtile / XT) % HO;
  int b  = wtile / (XT*HO);

  int q = o >> 1;
  int stk[2], stq[2]; int nst;
  if (o & 1){ stk[0]=1; stq[0]=q; nst=1; }
  else {
    nst = 0;
    if (q >= 1){ stk[0]=0; stq[0]=q-1; nst=1; }
    stk[nst]=2; stq[nst]=q; nst++;
  }

  f32x4 acc[2][4];
  #pragma unroll
  for (int t=0;t<2;t++)
    #pragma unroll
    for (int nt=0;nt<4;nt++) acc[t][nt] = (f32x4){0.f,0.f,0.f,0.f};

  const uint4* bp4 = (const uint4*)bpack;

  #pragma unroll 1
  for (int s=0; s<nst; s++){
    int kyt = stk[s];
    const bf16* rowp = in + ((size_t)(b*HI+stq[s])*WI)*64 + quad*8;
    #pragma unroll
    for (int ut=0; ut<3; ut++){
      #pragma unroll
      for (int c=0;c<2;c++){
        int ix0 = x0 + m - 1 + ut;
        int ix1 = ix0 + 16;
        bf16x8 a0 = load_frag(rowp + (size_t)ix0*64 + c*32, ix0>=0 && ix0<WI);
        bf16x8 a1 = load_frag(rowp + (size_t)ix1*64 + c*32, ix1>=0 && ix1<WI);
        #pragma unroll
        for (int nt=0;nt<4;nt++){
          uint4 Bq = bp4[(((kyt*3+ut)*2+c)*4+nt)*64 + lane];
          acc[0][nt] = mfma16(a0, Bq, acc[0][nt]);
          acc[1][nt] = mfma16(a1, Bq, acc[1][nt]);
        }
      }
    }
  }

  float4 bv = *(const float4*)(upb + m*4);
  size_t rowbase = ((size_t)b*HO + o)*WO;
  #pragma unroll
  for (int t=0;t<2;t++){
    #pragma unroll
    for (int r=0;r<4;r++){
      int p = x0 + t*16 + quad*4 + r;
      float g0 = gelu_f(acc[t][0][r] + bv.x);
      float g1 = gelu_f(acc[t][1][r] + bv.y);
      float g2 = gelu_f(acc[t][2][r] + bv.z);
      float g3 = gelu_f(acc[t][3][r] + bv.w);
      unsigned int lo = (unsigned int)b2u(f2b(g0)) | ((unsigned int)b2u(f2b(g1))<<16);
      unsigned int hi = (unsigned int)b2u(f2b(g2)) | ((unsigned int)b2u(f2b(g3))<<16);
      *(uint2*)(out + (rowbase + p)*64 + m*4) = make_uint2(lo,hi);
    }
  }
}

// ------------- conv_transpose dim1, register form — small grids (step 1) ------
template<int HI, int WI>
__global__ void upconv_dim1(const bf16* __restrict__ in, const bf16* __restrict__ bpack,
                            const float* __restrict__ upb, bf16* __restrict__ out){
  constexpr int HO = HI, WO = 2*WI, QT = WI/16;
  int lane = threadIdx.x & 63, wv = threadIdx.x >> 6;
  int wtile = swz8(blockIdx.x, gridDim.x)*4 + wv;
  int m = lane & 15, quad = lane >> 4;

  int q0 = (wtile % QT)*16;
  int y  = (wtile / QT) % HI;
  int b  = wtile / (QT*HI);

  f32x4 ae[4], ao[4];
  #pragma unroll
  for (int nt=0;nt<4;nt++){ ae[nt]=(f32x4){0.f,0.f,0.f,0.f}; ao[nt]=(f32x4){0.f,0.f,0.f,0.f}; }

  const uint4* bp4 = (const uint4*)bpack;

  #pragma unroll 1
  for (int ky=0; ky<3; ky++){
    int iy = y + ky - 1;
    if (iy < 0 || iy >= HI) continue;
    const bf16* rowp = in + ((size_t)(b*HI+iy)*WI)*64 + quad*8;
    #pragma unroll
    for (int c=0;c<2;c++){
      int qa = q0 + m;
      bf16x8 Au = load_frag(rowp + (size_t)qa*64 + c*32, true);
      bf16x8 As = load_frag(rowp + (size_t)(qa-1)*64 + c*32, qa >= 1);
      #pragma unroll
      for (int nt=0;nt<4;nt++){
        uint4 B0 = bp4[(((ky*3+0)*2+c)*4+nt)*64 + lane];
        uint4 B1 = bp4[(((ky*3+1)*2+c)*4+nt)*64 + lane];
        uint4 B2 = bp4[(((ky*3+2)*2+c)*4+nt)*64 + lane];
        ae[nt] = mfma16(As, B0, ae[nt]);
        ae[nt] = mfma16(Au, B2, ae[nt]);
        ao[nt] = mfma16(Au, B1, ao[nt]);
      }
    }
  }

  float4 bv = *(const float4*)(upb + m*4);
  size_t rowbase = ((size_t)b*HO + y)*WO;
  #pragma unroll
  for (int r=0;r<4;r++){
    int qq = q0 + quad*4 + r;
    {
      float g0 = gelu_f(ae[0][r] + bv.x);
      float g1 = gelu_f(ae[1][r] + bv.y);
      float g2 = gelu_f(ae[2][r] + bv.z);
      float g3 = gelu_f(ae[3][r] + bv.w);
      unsigned int lo = (unsigned int)b2u(f2b(g0)) | ((unsigned int)b2u(f2b(g1))<<16);
      unsigned int hi = (unsigned int)b2u(f2b(g2)) | ((unsigned int)b2u(f2b(g3))<<16);
      *(uint2*)(out + (rowbase + 2*qq)*64 + m*4) = make_uint2(lo,hi);
    }
    {
      float g0 = gelu_f(ao[0][r] + bv.x);
      float g1 = gelu_f(ao[1][r] + bv.y);
      float g2 = gelu_f(ao[2][r] + bv.z);
      float g3 = gelu_f(ao[3][r] + bv.w);
      unsigned int lo = (unsigned int)b2u(f2b(g0)) | ((unsigned int)b2u(f2b(g1))<<16);
      unsigned int hi = (unsigned int)b2u(f2b(g2)) | ((unsigned int)b2u(f2b(g3))<<16);
      *(uint2*)(out + (rowbase + 2*qq+1)*64 + m*4) = make_uint2(lo,hi);
    }
  }
}

// ------------- conv_transpose dim1, 2-row + B-pack in LDS ----------------------
// Four structural variants (r0-r3) all pinned at 59-67 us with MfmaUtil ~11%:
// the invariant is ~72 B-fragment GLOBAL loads per wave hitting L2 at ~200 cyc,
// with compiler vmcnt waits before each MFMA group — a latency chain no amount
// of occupancy hid. Fix: stage the full 72 KB B-pack into LDS once per block
// (one vmcnt(0) + one barrier at kernel START only), then the MFMA loop reads
// B via conflict-free ds_read_b128 (uniform index + lane*16 -> consecutive).
// A stays in registers (2-row form); dim0 is left untouched as control.
template<int HI, int WI>
__global__ void __launch_bounds__(256,2)
upconv_dim1_bs(const bf16* __restrict__ in, const bf16* __restrict__ bpack,
               const float* __restrict__ upb, bf16* __restrict__ out){
  constexpr int HO = HI, WO = 2*WI, QT = WI/16;
  __shared__ __align__(16) uint4 Bsh[4608];          // 72 KB: full dim1 B-pack
  int tid = threadIdx.x, lane = tid & 63, wv = tid >> 6;
  int wtile = swz8(blockIdx.x, gridDim.x)*4 + wv;
  int m = lane & 15, quad = lane >> 4;

  int q0 = (wtile % QT)*16;
  int y  = ((wtile / QT) % (HI/2)) * 2;
  int b  = wtile / (QT*(HI/2));

  // stage B-pack: 4608 uint4, 18 wave-chunks of 64 uint4 each per wave
  {
    const uint4* gp = (const uint4*)bpack;
    #pragma unroll
    for (int k=0;k<18;k++){
      int base = (wv*18 + k)*64;
      dma16(gp + base + lane, Bsh + base);
    }
  }

  int qa = q0 + m;

  // A fragments: input rows y-1 .. y+2 (issued before the staging wait so the
  // single vmcnt(0) covers both)
  bf16x8 Afr[4][2][2];              // [row4][c][{Au,As}]
  #pragma unroll
  for (int i4=0;i4<4;i4++){
    int iy = y + i4 - 1;
    bool ok = (iy>=0) && (iy<HI);
    const bf16* rowp = in + ((size_t)(b*HI+iy)*WI)*64 + quad*8;
    #pragma unroll
    for (int c=0;c<2;c++){
      Afr[i4][c][0] = load_frag(rowp + (size_t)qa*64 + c*32, ok);
      Afr[i4][c][1] = load_frag(rowp + (size_t)(qa-1)*64 + c*32, ok && qa >= 1);
    }
  }

  asm volatile("s_waitcnt vmcnt(0)" ::: "memory");
  __syncthreads();

  f32x4 ae[2][4], ao[2][4];
  #pragma unroll
  for (int r=0;r<2;r++)
    #pragma unroll
    for (int nt=0;nt<4;nt++){ ae[r][nt]=(f32x4){0.f,0.f,0.f,0.f}; ao[r][nt]=(f32x4){0.f,0.f,0.f,0.f}; }

  #pragma unroll
  for (int ky=0; ky<3; ky++){
    #pragma unroll
    for (int c=0;c<2;c++){
      #pragma unroll
      for (int nt=0;nt<4;nt++){
        uint4 B0 = Bsh[(((ky*3+0)*2+c)*4+nt)*64 + lane];
        uint4 B1 = Bsh[(((ky*3+1)*2+c)*4+nt)*64 + lane];
        uint4 B2 = Bsh[(((ky*3+2)*2+c)*4+nt)*64 + lane];
        #pragma unroll
        for (int r=0;r<2;r++){
          ae[r][nt] = mfma16(Afr[ky+r][c][1], B0, ae[r][nt]);
          ae[r][nt] = mfma16(Afr[ky+r][c][0], B2, ae[r][nt]);
          ao[r][nt] = mfma16(Afr[ky+r][c][0], B1, ao[r][nt]);
        }
      }
    }
  }

  float4 bv = *(const float4*)(upb + m*4);
  #pragma unroll
  for (int r2=0;r2<2;r2++){
    size_t rowbase = ((size_t)b*HO + y + r2)*WO;
    #pragma unroll
    for (int r=0;r<4;r++){
      int qq = q0 + quad*4 + r;
      {
        float g0 = gelu_f(ae[r2][0][r] + bv.x);
        float g1 = gelu_f(ae[r2][1][r] + bv.y);
        float g2 = gelu_f(ae[r2][2][r] + bv.z);
        float g3 = gelu_f(ae[r2][3][r] + bv.w);
        unsigned int lo = (unsigned int)b2u(f2b(g0)) | ((unsigned int)b2u(f2b(g1))<<16);
        unsigned int hi = (unsigned int)b2u(f2b(g2)) | ((unsigned int)b2u(f2b(g3))<<16);
        *(uint2*)(out + (rowbase + 2*qq)*64 + m*4) = make_uint2(lo,hi);
      }
      {
        float g0 = gelu_f(ao[r2][0][r] + bv.x);
        float g1 = gelu_f(ao[r2][1][r] + bv.y);
        float g2 = gelu_f(ao[r2][2][r] + bv.z);
        float g3 = gelu_f(ao[r2][3][r] + bv.w);
        unsigned int lo = (unsigned int)b2u(f2b(g0)) | ((unsigned int)b2u(f2b(g1))<<16);
        unsigned int hi = (unsigned int)b2u(f2b(g2)) | ((unsigned int)b2u(f2b(g3))<<16);
        *(uint2*)(out + (rowbase + 2*qq+1)*64 + m*4) = make_uint2(lo,hi);
      }
    }
  }
}

// ---------------- maskloss, register form — step 0 only ------------------------
template<int STEP, int DIM, int HH, int WW, int TILES>
__global__ void maskloss_mfma(const bf16* __restrict__ feat, const bf16* __restrict__ mpack,
                              const float* __restrict__ mb, const float* __restrict__ img,
                              const float* __restrict__ masks_in, float* __restrict__ masks_out,
                              float* __restrict__ accbuf){
  __shared__ float llog[4][64][4];
  __shared__ float red[4][2];
  int lane = threadIdx.x & 63;
  int wv   = threadIdx.x >> 6;
  int wtile = swz8(blockIdx.x, gridDim.x)*4 + wv;
  int m = lane & 15, quad = lane >> 4;

  constexpr int TPR = WW/(16*TILES);
  int x0 = (wtile % TPR)*(16*TILES);
  int y  = (wtile / TPR) % HH;
  int b  = wtile / (TPR*HH);

  const uint4* bp4 = (const uint4*)mpack;

  #pragma unroll 1
  for (int t=0; t<TILES; t++){
    f32x4 acc4 = (f32x4){0.f,0.f,0.f,0.f};
    #pragma unroll
    for (int c=0;c<2;c++){
      bf16x8 afr[9];
      #pragma unroll
      for (int ky=0; ky<3; ky++){
        int iy = y + ky - 1;
        bool rowok = (iy >= 0) && (iy < HH);
        const bf16* rowp = feat + ((size_t)(b*HH+iy)*WW)*64 + quad*8 + c*32;
        #pragma unroll
        for (int kx=0; kx<3; kx++){
          int ix = x0 + t*16 + m + kx - 1;
          bool ok = rowok && (ix >= 0) && (ix < WW);
          afr[ky*3+kx] = load_frag(rowp + (size_t)ix*64, ok);
        }
      }
      #pragma unroll
      for (int tap=0; tap<9; tap++){
        uint4 bb = bp4[(tap*2+c)*64 + lane];
        acc4 = mfma16(afr[tap], bb, acc4);
      }
    }
    if (m < 4){
      #pragma unroll
      for (int r=0;r<4;r++) llog[wv][t*16 + quad*4 + r][m] = acc4[r] + mb[m];
    }
  }
  __syncthreads();

  float ent = 0.f, mse = 0.f;
  if (lane < 16*TILES){
    int p = lane; int xx = x0 + p;
    float l0 = llog[wv][p][0], l1 = llog[wv][p][1];
    float l2 = llog[wv][p][2], l3 = llog[wv][p][3];
    float mx = fmaxf(fmaxf(l0,l1), fmaxf(l2,l3));
    float e0=__expf(l0-mx), e1=__expf(l1-mx), e2=__expf(l2-mx), e3=__expf(l3-mx);
    float inv = __builtin_amdgcn_rcpf(e0+e1+e2+e3);
    float p0=e0*inv, p1=e1*inv, p2=e2*inv, p3=e3*inv;
    float sval = p1 + 2.f*p2 + 3.f*p3;

    constexpr int HM = (DIM==0)? HH/2 : HH;
    constexpr int WM = (DIM==0)? WW : WW/2;
    int my = (DIM==0)? (y>>1) : y;
    int mxi = (DIM==1)? (xx>>1) : xx;
    float mv = masks_in[((size_t)b*HM + my)*WM + mxi];
    masks_out[((size_t)b*HH + y)*WW + xx] = mv + 0.25f*sval;

    ent = -(p0*__logf(p0+1e-8f) + p1*__logf(p1+1e-8f) +
            p2*__logf(p2+1e-8f) + p3*__logf(p3+1e-8f));

    constexpr int FH = 256/HH, FW = 256/WW;
    float isum = 0.f;
    const float* ib = img + ((size_t)b*256 + y*FH)*256 + xx*FW;
    #pragma unroll
    for (int dy=0; dy<FH; dy++)
      #pragma unroll
      for (int dx=0; dx<FW; dx++) isum += ib[dy*256+dx];
    float img_ds = isum * (1.0f/(FH*FW));
    float d = sval*(1.0f/3.0f) - img_ds;
    mse = d*d;
  }

  #pragma unroll
  for (int off=1; off<64; off<<=1){
    ent += __shfl_xor(ent, off, 64);
    mse += __shfl_xor(mse, off, 64);
  }
  if (lane == 0){ red[wv][0] = ent; red[wv][1] = mse; }
  __syncthreads();
  if (threadIdx.x == 0){
    float e  = red[0][0] + red[1][0] + red[2][0] + red[3][0];
    float ms = red[0][1] + red[1][1] + red[2][1] + red[3][1];
    int slot = blockIdx.x & (NSLOT-1);
    atomicAdd(accbuf + (2*STEP  )*NSLOT + slot, e);
    atomicAdd(accbuf + (2*STEP+1)*NSLOT + slot, ms);
  }
}

// ---------------- maskloss via async LDS staging (WW >= 64) --------------------
// Both-sides swizzle: linear LDS dest, pre-swizzled global source, XOR'd read
// offsets -> 16-way ds_read_b128 conflict removed (verified: conflicts -> 0).
template<int STEP, int DIM, int HH, int WW>
__global__ void maskloss_lds(const bf16* __restrict__ feat, const bf16* __restrict__ mpack,
                             const float* __restrict__ mb, const float* __restrict__ img,
                             const float* __restrict__ masks_in, float* __restrict__ masks_out,
                             float* __restrict__ accbuf){
  constexpr int NBrow = WW/64;
  constexpr int PITCH = 9216;                // 72 px * 128 B
  __shared__ __align__(16) char smem[3*PITCH];
  __shared__ float llog[4][16][4];
  __shared__ float red[4][2];
  int tid = threadIdx.x;
  int lane = tid & 63, wv = tid >> 6;
  int bi = swz8(blockIdx.x, gridDim.x);
  int x0 = (bi % NBrow)*64;
  int y  = (bi / NBrow) % HH;
  int b  = bi / (NBrow*HH);
  int m = lane & 15, quad = lane >> 4;
  int lanesw = ((lane ^ (lane>>3)) << 4);    // pre-swizzled lane*16

  bool rok[3];
  #pragma unroll
  for (int r=0;r<3;r++){ int iy=y+r-1; rok[r] = (iy>=0)&&(iy<HH); }

  for (int k = wv; k < 27; k += 4){
    int r = k/9, coff = (k%9)*1024;
    if (!rok[r]) continue;
    int iy = y + r - 1;
    const char* g = (const char*)(feat + ((size_t)(b*HH+iy)*WW + x0 - 1)*64)
                    + coff + lanesw;
    dma16(g, smem + r*PITCH + coff);
  }
  asm volatile("s_waitcnt vmcnt(0)" ::: "memory");
  __syncthreads();
  if (x0 == 0 && tid < 96)
    ((float*)(smem + (tid>>5)*PITCH))[tid & 31] = 0.f;
  if (x0 + 64 == WW && tid >= 128 && tid < 224){
    int t = tid - 128;
    ((float*)(smem + (t>>5)*PITCH + 65*128))[t & 31] = 0.f;
  }
  __syncthreads();

  const uint4* bp4 = (const uint4*)mpack;
  f32x4 accA = (f32x4){0.f,0.f,0.f,0.f};
  f32x4 accB = (f32x4){0.f,0.f,0.f,0.f};
  #pragma unroll 1
  for (int ky=0; ky<3; ky++){
    if (!rok[ky]) continue;
    const char* rowl = smem + ky*PITCH;
    #pragma unroll
    for (int kx=0; kx<3; kx++){
      int lp = wv*16 + m + kx;
      const char* pl = rowl + (size_t)lp*128;
      int xw = (lp & 7) << 4;
      bf16x8 a0 = __builtin_bit_cast(bf16x8, *(const uint4*)(pl + ((quad*16     ) ^ xw)));
      bf16x8 a1 = __builtin_bit_cast(bf16x8, *(const uint4*)(pl + ((quad*16 + 64) ^ xw)));
      uint4 b0 = bp4[((ky*3+kx)*2+0)*64 + lane];
      uint4 b1 = bp4[((ky*3+kx)*2+1)*64 + lane];
      accA = mfma16(a0, b0, accA);
      accB = mfma16(a1, b1, accB);
    }
  }

  if (m < 4){
    #pragma unroll
    for (int r=0;r<4;r++) llog[wv][quad*4+r][m] = accA[r] + accB[r] + mb[m];
  }
  __syncthreads();

  float ent = 0.f, mse = 0.f;
  if (lane < 16){
    int p = lane; int xx = x0 + wv*16 + p;
    float l0 = llog[wv][p][0], l1 = llog[wv][p][1];
    float l2 = llog[wv][p][2], l3 = llog[wv][p][3];
    float mx = fmaxf(fmaxf(l0,l1), fmaxf(l2,l3));
    float e0=__expf(l0-mx), e1=__expf(l1-mx), e2=__expf(l2-mx), e3=__expf(l3-mx);
    float inv = __builtin_amdgcn_rcpf(e0+e1+e2+e3);
    float p0=e0*inv, p1=e1*inv, p2=e2*inv, p3=e3*inv;
    float sval = p1 + 2.f*p2 + 3.f*p3;

    constexpr int HM = (DIM==0)? HH/2 : HH;
    constexpr int WM = (DIM==0)? WW : WW/2;
    int my = (DIM==0)? (y>>1) : y;
    int mxi = (DIM==1)? (xx>>1) : xx;
    float mv = masks_in[((size_t)b*HM + my)*WM + mxi];
    masks_out[((size_t)b*HH + y)*WW + xx] = mv + 0.25f*sval;

    ent = -(p0*__logf(p0+1e-8f) + p1*__logf(p1+1e-8f) +
            p2*__logf(p2+1e-8f) + p3*__logf(p3+1e-8f));

    constexpr int FH = 256/HH, FW = 256/WW;
    float isum = 0.f;
    const float* ib = img + ((size_t)b*256 + y*FH)*256 + xx*FW;
    #pragma unroll
    for (int dy=0; dy<FH; dy++)
      #pragma unroll
      for (int dx=0; dx<FW; dx++) isum += ib[dy*256+dx];
    float img_ds = isum * (1.0f/(FH*FW));
    float d = sval*(1.0f/3.0f) - img_ds;
    mse = d*d;
  }

  #pragma unroll
  for (int off=1; off<64; off<<=1){
    ent += __shfl_xor(ent, off, 64);
    mse += __shfl_xor(mse, off, 64);
  }
  if (lane == 0){ red[wv][0] = ent; red[wv][1] = mse; }
  __syncthreads();
  if (threadIdx.x == 0){
    float e  = red[0][0] + red[1][0] + red[2][0] + red[3][0];
    float ms = red[0][1] + red[1][1] + red[2][1] + red[3][1];
    int slot = blockIdx.x & (NSLOT-1);
    atomicAdd(accbuf + (2*STEP  )*NSLOT + slot, e);
    atomicAdd(accbuf + (2*STEP+1)*NSLOT + slot, ms);
  }
}

__global__ void finalize_kernel(const float* __restrict__ acc, float* __restrict__ out){
  int lane = threadIdx.x & 63;
  float v[12];
  #pragma unroll
  for (int i=0;i<12;i++){
    float x = acc[i*NSLOT + lane];
    #pragma unroll
    for (int off=1; off<64; off<<=1) x += __shfl_xor(x, off, 64);
    v[i] = x;
  }
  if (lane == 0){
    const float lw[6] = {0.1f,0.1f,0.5f,0.5f,1.0f,1.0f};
    const float nn[6] = {16384.f,32768.f,65536.f,131072.f,262144.f,524288.f};
    float L=0.f;
    for (int i=0;i<6;i++) L += lw[i]*((v[2*i] + v[2*i+1])/nn[i]);
    out[0]=L;
  }
}

extern "C" void kernel_launch(void* const* d_in, const int* in_sizes, int n_in,
                              void* d_out, int out_size, void* d_ws, size_t ws_size,
                              hipStream_t stream){
  const float* image  = (const float*)d_in[0];
  const float* w1=(const float*)d_in[2];  const float* b1=(const float*)d_in[3];
  const float* w2=(const float*)d_in[4];  const float* b2=(const float*)d_in[5];
  const float* w3=(const float*)d_in[6];  const float* b3=(const float*)d_in[7];
  const float* w4=(const float*)d_in[8];  const float* b4=(const float*)d_in[9];
  const float* upw=(const float*)d_in[10];const float* upb=(const float*)d_in[11];
  const float* mw=(const float*)d_in[12]; const float* mb=(const float*)d_in[13];
  const float* masks0=(const float*)d_in[14];
  float* out = (float*)d_out;

  char* ws = (char*)d_ws;
  size_t off = 0;
  auto alloc = [&](size_t bytes)->char*{
    char* p = ws + off; off += (bytes + 255) & ~(size_t)255; return p;
  };
  bf16* enc1  = (bf16*)alloc((size_t)8*256*256*16*2);
  bf16* enc2  = (bf16*)alloc((size_t)8*128*128*16*2);
  bf16* enc3  = (bf16*)alloc((size_t)8*64*64*32*2);
  bf16* featA = (bf16*)alloc((size_t)8*256*256*64*2);
  bf16* featB = (bf16*)alloc((size_t)8*256*128*64*2);
  float* mbA  = (float*)alloc((size_t)8*256*128*4);
  float* mbB  = (float*)alloc((size_t)8*128*128*4);
  bf16* packU = (bf16*)alloc((size_t)9*2*4*64*8*2);
  bf16* packM = (bf16*)alloc((size_t)9*2*64*8*2);
  float* acc  = (float*)alloc(12*NSLOT*sizeof(float));

  hipMemsetAsync(acc, 0, 12*NSLOT*sizeof(float), stream);

  repack_up  <<<144,256,0,stream>>>(upw, packU);
  repack_mask<<< 36,256,0,stream>>>(mw,  packM);

  // encoder
  trio_kernel<float,1,16,1,1,256,256><<<8*256*256/256,256,0,stream>>>(image,w1,b1,enc1);
  trio_kernel<bf16,16,16,2,2,256,256><<<8*128*128*2/256,256,0,stream>>>(enc1,w2,b2,enc2);
  trio_kernel<bf16,16,32,8,2,128,128><<<8*64*64*8/256,256,0,stream>>>(enc2,w3,b3,enc3);
  trio_kernel<bf16,32,64,16,2,64,64><<<8*32*32*16/256,256,0,stream>>>(enc3,w4,b4,featA);

  // step 0: (32,32) -> (64,32)
  upconv_dim0<32,32><<<128,256,0,stream>>>(featA,packU,upb,featB);
  maskloss_mfma<0,0,64,32,2><<<128,256,0,stream>>>(featB,packM,mb,image,masks0,mbA,acc);
  // step 1: (64,32) -> (64,64)
  upconv_dim1<64,32><<<256,256,0,stream>>>(featB,packU,upb,featA);
  maskloss_lds<1,1,64,64><<<512,256,0,stream>>>(featA,packM,mb,image,mbA,mbB,acc);
  // step 2: (64,64) -> (128,64)
  upconv_dim0<64,64><<<512,256,0,stream>>>(featA,packU,upb,featB);
  maskloss_lds<2,0,128,64><<<1024,256,0,stream>>>(featB,packM,mb,image,mbB,mbA,acc);
  // step 3: (128,64) -> (128,128)  [2-row waves + LDS B-pack: 512 blocks]
  upconv_dim1_bs<128,64><<<512,256,0,stream>>>(featB,packU,upb,featA);
  maskloss_lds<3,1,128,128><<<2048,256,0,stream>>>(featA,packM,mb,image,mbA,mbB,acc);
  // step 4: (128,128) -> (256,128)
  upconv_dim0<128,128><<<2048,256,0,stream>>>(featA,packU,upb,featB);
  maskloss_lds<4,0,256,128><<<4096,256,0,stream>>>(featB,packM,mb,image,mbB,mbA,acc);
  // step 5: (256,128) -> (256,256) [2-row waves + LDS B-pack: 2048 blocks]
  upconv_dim1_bs<256,128><<<2048,256,0,stream>>>(featB,packU,upb,featA);
  maskloss_lds<5,1,256,256><<<8192,256,0,stream>>>(featA,packM,mb,image,mbA,out+1,acc);

  finalize_kernel<<<1,64,0,stream>>>(acc,out);
}

// Round 5
// 403.578 us; speedup vs baseline: 1.1696x; 1.1077x over previous
//
#include <hip/hip_runtime.h>
#include <hip/hip_bf16.h>
#include <math.h>

typedef __hip_bfloat16 bf16;
typedef float f32x4 __attribute__((ext_vector_type(4)));
typedef __bf16 bf16x8 __attribute__((ext_vector_type(8)));

#define DEV __device__ __forceinline__

DEV float to_f(float v){ return v; }
DEV float to_f(bf16 v){ return __bfloat162float(v); }
DEV bf16 f2b(float v){ return __float2bfloat16(v); }
DEV unsigned short b2u(bf16 v){ return __builtin_bit_cast(unsigned short, v); }

DEV float gelu_f(float x){
  float z = 1.5957691216057308f*(x + 0.044715f*x*x*x);
  float e = __expf(-z);
  return x * __builtin_amdgcn_rcpf(1.0f + e);
}

DEV bf16x8 load_frag(const bf16* p, bool ok){
  uint4 u = make_uint4(0u,0u,0u,0u);
  if (ok) u = *(const uint4*)p;
  return __builtin_bit_cast(bf16x8, u);
}

DEV f32x4 mfma16(bf16x8 a, uint4 b, f32x4 c){
  return __builtin_amdgcn_mfma_f32_16x16x32_bf16(a, __builtin_bit_cast(bf16x8, b), c, 0, 0, 0);
}

DEV int swz8(int blk, int n){
  return (blk & 7) * (n >> 3) + (blk >> 3);
}

// async global->LDS DMA, 16 B per lane; lds dest wave-uniform base.
DEV void dma16(const void* g, void* l){
  __builtin_amdgcn_global_load_lds(
      (const __attribute__((address_space(1))) unsigned int*)g,
      (__attribute__((address_space(3))) unsigned int*)l,
      16, 0, 0);
}

#define NSLOT 64

// ---------------- encoder Conv_trio -------------------------------------------
template<typename TIN, int CIN, int COUT, int SUB, int STRIDE, int HI, int WI>
__global__ void trio_kernel(const TIN* __restrict__ in, const float* __restrict__ w,
                            const float* __restrict__ bias, bf16* __restrict__ out){
  constexpr int HO = HI/STRIDE, WO = WI/STRIDE;
  constexpr int CO_PER = COUT/SUB;
  int gtid = blockIdx.x*blockDim.x + threadIdx.x;
  int sub = gtid % SUB;
  int pix = gtid / SUB;
  int b = pix / (HO*WO); int rem = pix % (HO*WO);
  int y = rem / WO, x = rem % WO;

  float acc[CO_PER];
  #pragma unroll
  for (int j=0;j<CO_PER;j++) acc[j]=0.f;

  for (int ky=0;ky<3;ky++){
    int iy = (STRIDE==1) ? (y+ky-1) : (2*y+ky);
    if (iy<0 || iy>=HI) continue;
    for (int kx=0;kx<3;kx++){
      int ix = (STRIDE==1) ? (x+kx-1) : (2*x+kx);
      if (ix<0 || ix>=WI) continue;
      const TIN* ip = in + ((size_t)(b*HI+iy)*WI+ix)*CIN;
      const float* wp = w + ((ky*3+kx)*CIN)*COUT + sub*CO_PER;
      if constexpr (sizeof(TIN)==2 && (CIN%8)==0){
        #pragma unroll
        for (int v=0; v<CIN/8; v++){
          uint4 u = *(const uint4*)((const bf16*)ip + v*8);
          bf16x8 ch = __builtin_bit_cast(bf16x8, u);
          #pragma unroll
          for (int j=0;j<8;j++){
            float a = (float)ch[j];
            const float4* w4 = (const float4*)(wp + (size_t)(v*8+j)*COUT);
            #pragma unroll
            for (int q2=0;q2<CO_PER/4;q2++){
              float4 ww = w4[q2];
              acc[4*q2+0] += a*ww.x; acc[4*q2+1] += a*ww.y;
              acc[4*q2+2] += a*ww.z; acc[4*q2+3] += a*ww.w;
            }
          }
        }
      } else {
        #pragma unroll 4
        for (int ci=0; ci<CIN; ci++){
          float a = to_f(ip[ci]);
          const float4* w4 = (const float4*)(wp + (size_t)ci*COUT);
          #pragma unroll
          for (int j=0;j<CO_PER/4;j++){
            float4 ww = w4[j];
            acc[4*j+0] += a*ww.x; acc[4*j+1] += a*ww.y;
            acc[4*j+2] += a*ww.z; acc[4*j+3] += a*ww.w;
          }
        }
      }
    }
  }

  float s1=0.f, s2=0.f;
  #pragma unroll
  for (int j=0;j<CO_PER;j++){
    acc[j] += bias[sub*CO_PER+j];
    s1 += acc[j]; s2 += acc[j]*acc[j];
  }
  #pragma unroll
  for (int off=1; off<SUB; off<<=1){
    s1 += __shfl_xor(s1,off,64);
    s2 += __shfl_xor(s2,off,64);
  }
  float mu  = s1*(1.0f/COUT);
  float var = s2*(1.0f/COUT) - mu*mu;
  float sc  = rsqrtf(var + 1e-6f);

  bf16* op = out + (size_t)pix*COUT + sub*CO_PER;
  #pragma unroll
  for (int j=0;j<CO_PER;j++) op[j] = f2b(gelu_f((acc[j]-mu)*sc));
}

// ---------------- weight repack -----------------------------------------------
__global__ void repack_up(const float* __restrict__ w, bf16* __restrict__ bp){
  int v = blockIdx.x*256 + threadIdx.x;
  if (v >= 9*2*4*64*8) return;
  int j = v & 7; int lane = (v>>3)&63; int nt = (v>>9)&3; int c = (v>>11)&1; int tap = v>>12;
  int ci = c*32 + (lane>>4)*8 + j;
  int co = (lane&15)*4 + nt;
  bp[v] = f2b(w[(tap*64+ci)*64 + co]);
}

__global__ void repack_mask(const float* __restrict__ w, bf16* __restrict__ bp){
  int v = blockIdx.x*256 + threadIdx.x;
  if (v >= 9*2*64*8) return;
  int j = v & 7; int lane = (v>>3)&63; int c = (v>>9)&1; int tap = v>>10;
  int ci = c*32 + (lane>>4)*8 + j;
  int n = lane & 15;
  bp[v] = (n < 4) ? f2b(w[(tap*64+ci)*4 + n]) : f2b(0.0f);
}

// ------------- conv_transpose, stride-2 along y (DIM=0) — register form -------
template<int HI, int WI>
__global__ void upconv_dim0(const bf16* __restrict__ in, const bf16* __restrict__ bpack,
                            const float* __restrict__ upb, bf16* __restrict__ out){
  constexpr int HO = 2*HI, WO = WI, XT = WI/32;
  int lane = threadIdx.x & 63, wv = threadIdx.x >> 6;
  int wtile = swz8(blockIdx.x, gridDim.x)*4 + wv;
  int m = lane & 15, quad = lane >> 4;

  int x0 = (wtile % XT)*32;
  int o  = (wtile / XT) % HO;
  int b  = wtile / (XT*HO);

  int q = o >> 1;
  int stk[2], stq[2]; int nst;
  if (o & 1){ stk[0]=1; stq[0]=q; nst=1; }
  else {
    nst = 0;
    if (q >= 1){ stk[0]=0; stq[0]=q-1; nst=1; }
    stk[nst]=2; stq[nst]=q; nst++;
  }

  f32x4 acc[2][4];
  #pragma unroll
  for (int t=0;t<2;t++)
    #pragma unroll
    for (int nt=0;nt<4;nt++) acc[t][nt] = (f32x4){0.f,0.f,0.f,0.f};

  const uint4* bp4 = (const uint4*)bpack;

  #pragma unroll 1
  for (int s=0; s<nst; s++){
    int kyt = stk[s];
    const bf16* rowp = in + ((size_t)(b*HI+stq[s])*WI)*64 + quad*8;
    #pragma unroll
    for (int ut=0; ut<3; ut++){
      #pragma unroll
      for (int c=0;c<2;c++){
        int ix0 = x0 + m - 1 + ut;
        int ix1 = ix0 + 16;
        bf16x8 a0 = load_frag(rowp + (size_t)ix0*64 + c*32, ix0>=0 && ix0<WI);
        bf16x8 a1 = load_frag(rowp + (size_t)ix1*64 + c*32, ix1>=0 && ix1<WI);
        #pragma unroll
        for (int nt=0;nt<4;nt++){
          uint4 Bq = bp4[(((kyt*3+ut)*2+c)*4+nt)*64 + lane];
          acc[0][nt] = mfma16(a0, Bq, acc[0][nt]);
          acc[1][nt] = mfma16(a1, Bq, acc[1][nt]);
        }
      }
    }
  }

  float4 bv = *(const float4*)(upb + m*4);
  size_t rowbase = ((size_t)b*HO + o)*WO;
  #pragma unroll
  for (int t=0;t<2;t++){
    #pragma unroll
    for (int r=0;r<4;r++){
      int p = x0 + t*16 + quad*4 + r;
      float g0 = gelu_f(acc[t][0][r] + bv.x);
      float g1 = gelu_f(acc[t][1][r] + bv.y);
      float g2 = gelu_f(acc[t][2][r] + bv.z);
      float g3 = gelu_f(acc[t][3][r] + bv.w);
      unsigned int lo = (unsigned int)b2u(f2b(g0)) | ((unsigned int)b2u(f2b(g1))<<16);
      unsigned int hi = (unsigned int)b2u(f2b(g2)) | ((unsigned int)b2u(f2b(g3))<<16);
      *(uint2*)(out + (rowbase + p)*64 + m*4) = make_uint2(lo,hi);
    }
  }
}

// ------------- conv_transpose dim0 + B-pack in LDS (r4-validated mechanism) ----
// dim0 waves issue up to 48 global B-fragment loads per wave (same ~200-cyc L2
// latency chain as dim1 had). Stage the 72 KB pack once per block; single
// vmcnt(0)+barrier at start only.
template<int HI, int WI>
__global__ void __launch_bounds__(256,2)
upconv_dim0_bs(const bf16* __restrict__ in, const bf16* __restrict__ bpack,
               const float* __restrict__ upb, bf16* __restrict__ out){
  constexpr int HO = 2*HI, WO = WI, XT = WI/32;
  __shared__ __align__(16) uint4 Bsh[4608];          // 72 KB
  int tid = threadIdx.x, lane = tid & 63, wv = tid >> 6;
  int wtile = swz8(blockIdx.x, gridDim.x)*4 + wv;
  int m = lane & 15, quad = lane >> 4;

  int x0 = (wtile % XT)*32;
  int o  = (wtile / XT) % HO;
  int b  = wtile / (XT*HO);

  {
    const uint4* gp = (const uint4*)bpack;
    #pragma unroll
    for (int k=0;k<18;k++){
      int base = (wv*18 + k)*64;
      dma16(gp + base + lane, Bsh + base);
    }
  }

  int q = o >> 1;
  int stk[2], stq[2]; int nst;
  if (o & 1){ stk[0]=1; stq[0]=q; nst=1; }
  else {
    nst = 0;
    if (q >= 1){ stk[0]=0; stq[0]=q-1; nst=1; }
    stk[nst]=2; stq[nst]=q; nst++;
  }

  f32x4 acc[2][4];
  #pragma unroll
  for (int t=0;t<2;t++)
    #pragma unroll
    for (int nt=0;nt<4;nt++) acc[t][nt] = (f32x4){0.f,0.f,0.f,0.f};

  asm volatile("s_waitcnt vmcnt(0)" ::: "memory");
  __syncthreads();

  #pragma unroll 1
  for (int s=0; s<nst; s++){
    int kyt = stk[s];
    const bf16* rowp = in + ((size_t)(b*HI+stq[s])*WI)*64 + quad*8;
    #pragma unroll
    for (int ut=0; ut<3; ut++){
      #pragma unroll
      for (int c=0;c<2;c++){
        int ix0 = x0 + m - 1 + ut;
        int ix1 = ix0 + 16;
        bf16x8 a0 = load_frag(rowp + (size_t)ix0*64 + c*32, ix0>=0 && ix0<WI);
        bf16x8 a1 = load_frag(rowp + (size_t)ix1*64 + c*32, ix1>=0 && ix1<WI);
        #pragma unroll
        for (int nt=0;nt<4;nt++){
          uint4 Bq = Bsh[(((kyt*3+ut)*2+c)*4+nt)*64 + lane];
          acc[0][nt] = mfma16(a0, Bq, acc[0][nt]);
          acc[1][nt] = mfma16(a1, Bq, acc[1][nt]);
        }
      }
    }
  }

  float4 bv = *(const float4*)(upb + m*4);
  size_t rowbase = ((size_t)b*HO + o)*WO;
  #pragma unroll
  for (int t=0;t<2;t++){
    #pragma unroll
    for (int r=0;r<4;r++){
      int p = x0 + t*16 + quad*4 + r;
      float g0 = gelu_f(acc[t][0][r] + bv.x);
      float g1 = gelu_f(acc[t][1][r] + bv.y);
      float g2 = gelu_f(acc[t][2][r] + bv.z);
      float g3 = gelu_f(acc[t][3][r] + bv.w);
      unsigned int lo = (unsigned int)b2u(f2b(g0)) | ((unsigned int)b2u(f2b(g1))<<16);
      unsigned int hi = (unsigned int)b2u(f2b(g2)) | ((unsigned int)b2u(f2b(g3))<<16);
      *(uint2*)(out + (rowbase + p)*64 + m*4) = make_uint2(lo,hi);
    }
  }
}

// ------------- conv_transpose dim1, register form — small grids (step 1) ------
template<int HI, int WI>
__global__ void upconv_dim1(const bf16* __restrict__ in, const bf16* __restrict__ bpack,
                            const float* __restrict__ upb, bf16* __restrict__ out){
  constexpr int HO = HI, WO = 2*WI, QT = WI/16;
  int lane = threadIdx.x & 63, wv = threadIdx.x >> 6;
  int wtile = swz8(blockIdx.x, gridDim.x)*4 + wv;
  int m = lane & 15, quad = lane >> 4;

  int q0 = (wtile % QT)*16;
  int y  = (wtile / QT) % HI;
  int b  = wtile / (QT*HI);

  f32x4 ae[4], ao[4];
  #pragma unroll
  for (int nt=0;nt<4;nt++){ ae[nt]=(f32x4){0.f,0.f,0.f,0.f}; ao[nt]=(f32x4){0.f,0.f,0.f,0.f}; }

  const uint4* bp4 = (const uint4*)bpack;

  #pragma unroll 1
  for (int ky=0; ky<3; ky++){
    int iy = y + ky - 1;
    if (iy < 0 || iy >= HI) continue;
    const bf16* rowp = in + ((size_t)(b*HI+iy)*WI)*64 + quad*8;
    #pragma unroll
    for (int c=0;c<2;c++){
      int qa = q0 + m;
      bf16x8 Au = load_frag(rowp + (size_t)qa*64 + c*32, true);
      bf16x8 As = load_frag(rowp + (size_t)(qa-1)*64 + c*32, qa >= 1);
      #pragma unroll
      for (int nt=0;nt<4;nt++){
        uint4 B0 = bp4[(((ky*3+0)*2+c)*4+nt)*64 + lane];
        uint4 B1 = bp4[(((ky*3+1)*2+c)*4+nt)*64 + lane];
        uint4 B2 = bp4[(((ky*3+2)*2+c)*4+nt)*64 + lane];
        ae[nt] = mfma16(As, B0, ae[nt]);
        ae[nt] = mfma16(Au, B2, ae[nt]);
        ao[nt] = mfma16(Au, B1, ao[nt]);
      }
    }
  }

  float4 bv = *(const float4*)(upb + m*4);
  size_t rowbase = ((size_t)b*HO + y)*WO;
  #pragma unroll
  for (int r=0;r<4;r++){
    int qq = q0 + quad*4 + r;
    {
      float g0 = gelu_f(ae[0][r] + bv.x);
      float g1 = gelu_f(ae[1][r] + bv.y);
      float g2 = gelu_f(ae[2][r] + bv.z);
      float g3 = gelu_f(ae[3][r] + bv.w);
      unsigned int lo = (unsigned int)b2u(f2b(g0)) | ((unsigned int)b2u(f2b(g1))<<16);
      unsigned int hi = (unsigned int)b2u(f2b(g2)) | ((unsigned int)b2u(f2b(g3))<<16);
      *(uint2*)(out + (rowbase + 2*qq)*64 + m*4) = make_uint2(lo,hi);
    }
    {
      float g0 = gelu_f(ao[0][r] + bv.x);
      float g1 = gelu_f(ao[1][r] + bv.y);
      float g2 = gelu_f(ao[2][r] + bv.z);
      float g3 = gelu_f(ao[3][r] + bv.w);
      unsigned int lo = (unsigned int)b2u(f2b(g0)) | ((unsigned int)b2u(f2b(g1))<<16);
      unsigned int hi = (unsigned int)b2u(f2b(g2)) | ((unsigned int)b2u(f2b(g3))<<16);
      *(uint2*)(out + (rowbase + 2*qq+1)*64 + m*4) = make_uint2(lo,hi);
    }
  }
}

// ------------- conv_transpose dim1, 2-row + B-pack in LDS (r4-validated) ------
template<int HI, int WI>
__global__ void __launch_bounds__(256,2)
upconv_dim1_bs(const bf16* __restrict__ in, const bf16* __restrict__ bpack,
               const float* __restrict__ upb, bf16* __restrict__ out){
  constexpr int HO = HI, WO = 2*WI, QT = WI/16;
  __shared__ __align__(16) uint4 Bsh[4608];          // 72 KB: full dim1 B-pack
  int tid = threadIdx.x, lane = tid & 63, wv = tid >> 6;
  int wtile = swz8(blockIdx.x, gridDim.x)*4 + wv;
  int m = lane & 15, quad = lane >> 4;

  int q0 = (wtile % QT)*16;
  int y  = ((wtile / QT) % (HI/2)) * 2;
  int b  = wtile / (QT*(HI/2));

  // stage B-pack: 4608 uint4, 18 wave-chunks of 64 uint4 each per wave
  {
    const uint4* gp = (const uint4*)bpack;
    #pragma unroll
    for (int k=0;k<18;k++){
      int base = (wv*18 + k)*64;
      dma16(gp + base + lane, Bsh + base);
    }
  }

  int qa = q0 + m;

  // A fragments: input rows y-1 .. y+2 (issued before the staging wait so the
  // single vmcnt(0) covers both)
  bf16x8 Afr[4][2][2];              // [row4][c][{Au,As}]
  #pragma unroll
  for (int i4=0;i4<4;i4++){
    int iy = y + i4 - 1;
    bool ok = (iy>=0) && (iy<HI);
    const bf16* rowp = in + ((size_t)(b*HI+iy)*WI)*64 + quad*8;
    #pragma unroll
    for (int c=0;c<2;c++){
      Afr[i4][c][0] = load_frag(rowp + (size_t)qa*64 + c*32, ok);
      Afr[i4][c][1] = load_frag(rowp + (size_t)(qa-1)*64 + c*32, ok && qa >= 1);
    }
  }

  asm volatile("s_waitcnt vmcnt(0)" ::: "memory");
  __syncthreads();

  f32x4 ae[2][4], ao[2][4];
  #pragma unroll
  for (int r=0;r<2;r++)
    #pragma unroll
    for (int nt=0;nt<4;nt++){ ae[r][nt]=(f32x4){0.f,0.f,0.f,0.f}; ao[r][nt]=(f32x4){0.f,0.f,0.f,0.f}; }

  #pragma unroll
  for (int ky=0; ky<3; ky++){
    #pragma unroll
    for (int c=0;c<2;c++){
      #pragma unroll
      for (int nt=0;nt<4;nt++){
        uint4 B0 = Bsh[(((ky*3+0)*2+c)*4+nt)*64 + lane];
        uint4 B1 = Bsh[(((ky*3+1)*2+c)*4+nt)*64 + lane];
        uint4 B2 = Bsh[(((ky*3+2)*2+c)*4+nt)*64 + lane];
        #pragma unroll
        for (int r=0;r<2;r++){
          ae[r][nt] = mfma16(Afr[ky+r][c][1], B0, ae[r][nt]);
          ae[r][nt] = mfma16(Afr[ky+r][c][0], B2, ae[r][nt]);
          ao[r][nt] = mfma16(Afr[ky+r][c][0], B1, ao[r][nt]);
        }
      }
    }
  }

  float4 bv = *(const float4*)(upb + m*4);
  #pragma unroll
  for (int r2=0;r2<2;r2++){
    size_t rowbase = ((size_t)b*HO + y + r2)*WO;
    #pragma unroll
    for (int r=0;r<4;r++){
      int qq = q0 + quad*4 + r;
      {
        float g0 = gelu_f(ae[r2][0][r] + bv.x);
        float g1 = gelu_f(ae[r2][1][r] + bv.y);
        float g2 = gelu_f(ae[r2][2][r] + bv.z);
        float g3 = gelu_f(ae[r2][3][r] + bv.w);
        unsigned int lo = (unsigned int)b2u(f2b(g0)) | ((unsigned int)b2u(f2b(g1))<<16);
        unsigned int hi = (unsigned int)b2u(f2b(g2)) | ((unsigned int)b2u(f2b(g3))<<16);
        *(uint2*)(out + (rowbase + 2*qq)*64 + m*4) = make_uint2(lo,hi);
      }
      {
        float g0 = gelu_f(ao[r2][0][r] + bv.x);
        float g1 = gelu_f(ao[r2][1][r] + bv.y);
        float g2 = gelu_f(ao[r2][2][r] + bv.z);
        float g3 = gelu_f(ao[r2][3][r] + bv.w);
        unsigned int lo = (unsigned int)b2u(f2b(g0)) | ((unsigned int)b2u(f2b(g1))<<16);
        unsigned int hi = (unsigned int)b2u(f2b(g2)) | ((unsigned int)b2u(f2b(g3))<<16);
        *(uint2*)(out + (rowbase + 2*qq+1)*64 + m*4) = make_uint2(lo,hi);
      }
    }
  }
}

// ---------------- maskloss, register form — step 0 only ------------------------
template<int STEP, int DIM, int HH, int WW, int TILES>
__global__ void maskloss_mfma(const bf16* __restrict__ feat, const bf16* __restrict__ mpack,
                              const float* __restrict__ mb, const float* __restrict__ img,
                              const float* __restrict__ masks_in, float* __restrict__ masks_out,
                              float* __restrict__ accbuf){
  __shared__ float llog[4][64][4];
  __shared__ float red[4][2];
  int lane = threadIdx.x & 63;
  int wv   = threadIdx.x >> 6;
  int wtile = swz8(blockIdx.x, gridDim.x)*4 + wv;
  int m = lane & 15, quad = lane >> 4;

  constexpr int TPR = WW/(16*TILES);
  int x0 = (wtile % TPR)*(16*TILES);
  int y  = (wtile / TPR) % HH;
  int b  = wtile / (TPR*HH);

  const uint4* bp4 = (const uint4*)mpack;

  #pragma unroll 1
  for (int t=0; t<TILES; t++){
    f32x4 acc4 = (f32x4){0.f,0.f,0.f,0.f};
    #pragma unroll
    for (int c=0;c<2;c++){
      bf16x8 afr[9];
      #pragma unroll
      for (int ky=0; ky<3; ky++){
        int iy = y + ky - 1;
        bool rowok = (iy >= 0) && (iy < HH);
        const bf16* rowp = feat + ((size_t)(b*HH+iy)*WW)*64 + quad*8 + c*32;
        #pragma unroll
        for (int kx=0; kx<3; kx++){
          int ix = x0 + t*16 + m + kx - 1;
          bool ok = rowok && (ix >= 0) && (ix < WW);
          afr[ky*3+kx] = load_frag(rowp + (size_t)ix*64, ok);
        }
      }
      #pragma unroll
      for (int tap=0; tap<9; tap++){
        uint4 bb = bp4[(tap*2+c)*64 + lane];
        acc4 = mfma16(afr[tap], bb, acc4);
      }
    }
    if (m < 4){
      #pragma unroll
      for (int r=0;r<4;r++) llog[wv][t*16 + quad*4 + r][m] = acc4[r] + mb[m];
    }
  }
  __syncthreads();

  float ent = 0.f, mse = 0.f;
  if (lane < 16*TILES){
    int p = lane; int xx = x0 + p;
    float l0 = llog[wv][p][0], l1 = llog[wv][p][1];
    float l2 = llog[wv][p][2], l3 = llog[wv][p][3];
    float mx = fmaxf(fmaxf(l0,l1), fmaxf(l2,l3));
    float d0=l0-mx, d1=l1-mx, d2=l2-mx, d3=l3-mx;
    float e0=__expf(d0), e1=__expf(d1), e2=__expf(d2), e3=__expf(d3);
    float S = e0+e1+e2+e3;
    float inv = __builtin_amdgcn_rcpf(S);
    float sval = (e1 + 2.f*e2 + 3.f*e3)*inv;

    constexpr int HM = (DIM==0)? HH/2 : HH;
    constexpr int WM = (DIM==0)? WW : WW/2;
    int my = (DIM==0)? (y>>1) : y;
    int mxi = (DIM==1)? (xx>>1) : xx;
    float mv = masks_in[((size_t)b*HM + my)*WM + mxi];
    masks_out[((size_t)b*HH + y)*WW + xx] = mv + 0.25f*sval;

    // ent = -sum p log p = log S - sum(e_i d_i)/S
    ent = __logf(S) - (e0*d0 + e1*d1 + e2*d2 + e3*d3)*inv;

    constexpr int FH = 256/HH, FW = 256/WW;
    float isum = 0.f;
    const float* ib = img + ((size_t)b*256 + y*FH)*256 + xx*FW;
    #pragma unroll
    for (int dy=0; dy<FH; dy++)
      #pragma unroll
      for (int dx=0; dx<FW; dx++) isum += ib[dy*256+dx];
    float img_ds = isum * (1.0f/(FH*FW));
    float d = sval*(1.0f/3.0f) - img_ds;
    mse = d*d;
  }

  #pragma unroll
  for (int off=1; off<64; off<<=1){
    ent += __shfl_xor(ent, off, 64);
    mse += __shfl_xor(mse, off, 64);
  }
  if (lane == 0){ red[wv][0] = ent; red[wv][1] = mse; }
  __syncthreads();
  if (threadIdx.x == 0){
    float e  = red[0][0] + red[1][0] + red[2][0] + red[3][0];
    float ms = red[0][1] + red[1][1] + red[2][1] + red[3][1];
    int slot = blockIdx.x & (NSLOT-1);
    atomicAdd(accbuf + (2*STEP  )*NSLOT + slot, e);
    atomicAdd(accbuf + (2*STEP+1)*NSLOT + slot, ms);
  }
}

// ---------------- maskloss via async LDS staging (WW >= 64) --------------------
// ROWS y-rows per block (ROWS=2 for big steps): stages ROWS+2 input rows for
// ROWS output rows -> staged bytes/px drop 3x->2x, DMA issues/barriers/atomics
// per px halve, 2 MFMA tiles per wave between barriers. Swizzle as before
// (conflicts verified 0).
template<int STEP, int DIM, int HH, int WW, int ROWS>
__global__ void maskloss_lds(const bf16* __restrict__ feat, const bf16* __restrict__ mpack,
                             const float* __restrict__ mb, const float* __restrict__ img,
                             const float* __restrict__ masks_in, float* __restrict__ masks_out,
                             float* __restrict__ accbuf){
  constexpr int NBrow = WW/64;
  constexpr int PITCH = 9216;                // 72 px * 128 B
  constexpr int NR = ROWS + 2;
  constexpr int WPR = 4/ROWS;                // waves per row
  __shared__ __align__(16) char smem[NR*PITCH];
  __shared__ float llog[4][ROWS][16][4];
  __shared__ float red[4][2];
  int tid = threadIdx.x;
  int lane = tid & 63, wv = tid >> 6;
  int bi = swz8(blockIdx.x, gridDim.x);
  int x0 = (bi % NBrow)*64;
  int y0 = ((bi / NBrow) % (HH/ROWS)) * ROWS;
  int b  = bi / (NBrow*(HH/ROWS));
  int m = lane & 15, quad = lane >> 4;
  int lanesw = ((lane ^ (lane>>3)) << 4);    // pre-swizzled lane*16

  int r_w   = wv / WPR;                      // wave's row within block
  int xbase = (wv % WPR) * (16*ROWS);        // wave's x window (ROWS tiles)
  int yw    = y0 + r_w;                      // wave's absolute output row

  for (int k = wv; k < NR*9; k += 4){
    int r = k/9, coff = (k%9)*1024;
    int iy = y0 + r - 1;
    if (iy < 0 || iy >= HH) continue;
    const char* g = (const char*)(feat + ((size_t)(b*HH+iy)*WW + x0 - 1)*64)
                    + coff + lanesw;
    dma16(g, smem + r*PITCH + coff);
  }
  asm volatile("s_waitcnt vmcnt(0)" ::: "memory");
  __syncthreads();
  if (x0 == 0 && tid < 32*NR)
    ((float*)(smem + (tid>>5)*PITCH))[tid & 31] = 0.f;
  if (x0 + 64 == WW && tid >= 128 && tid < 128 + 32*NR){
    int t = tid - 128;
    ((float*)(smem + (t>>5)*PITCH + 65*128))[t & 31] = 0.f;
  }
  __syncthreads();

  const uint4* bp4 = (const uint4*)mpack;
  #pragma unroll
  for (int t=0; t<ROWS; t++){
    f32x4 accA = (f32x4){0.f,0.f,0.f,0.f};
    f32x4 accB = (f32x4){0.f,0.f,0.f,0.f};
    #pragma unroll
    for (int ky=0; ky<3; ky++){
      int iyw = yw + ky - 1;
      if (iyw < 0 || iyw >= HH) continue;
      const char* rowl = smem + (size_t)(r_w + ky)*PITCH;
      #pragma unroll
      for (int kx=0; kx<3; kx++){
        int lp = xbase + t*16 + m + kx;
        const char* pl = rowl + (size_t)lp*128;
        int xw = (lp & 7) << 4;
        bf16x8 a0 = __builtin_bit_cast(bf16x8, *(const uint4*)(pl + ((quad*16     ) ^ xw)));
        bf16x8 a1 = __builtin_bit_cast(bf16x8, *(const uint4*)(pl + ((quad*16 + 64) ^ xw)));
        uint4 b0 = bp4[((ky*3+kx)*2+0)*64 + lane];
        uint4 b1 = bp4[((ky*3+kx)*2+1)*64 + lane];
        accA = mfma16(a0, b0, accA);
        accB = mfma16(a1, b1, accB);
      }
    }
    if (m < 4){
      #pragma unroll
      for (int r=0;r<4;r++) llog[wv][t][quad*4+r][m] = accA[r] + accB[r] + mb[m];
    }
  }
  __syncthreads();

  float ent = 0.f, mse = 0.f;
  if (lane < 16*ROWS){
    int t = lane >> 4;
    int p = lane & 15;
    int xx = x0 + xbase + t*16 + p;
    float l0 = llog[wv][t][p][0], l1 = llog[wv][t][p][1];
    float l2 = llog[wv][t][p][2], l3 = llog[wv][t][p][3];
    float mx = fmaxf(fmaxf(l0,l1), fmaxf(l2,l3));
    float d0=l0-mx, d1=l1-mx, d2=l2-mx, d3=l3-mx;
    float e0=__expf(d0), e1=__expf(d1), e2=__expf(d2), e3=__expf(d3);
    float S = e0+e1+e2+e3;
    float inv = __builtin_amdgcn_rcpf(S);
    float sval = (e1 + 2.f*e2 + 3.f*e3)*inv;

    constexpr int HM = (DIM==0)? HH/2 : HH;
    constexpr int WM = (DIM==0)? WW : WW/2;
    int my = (DIM==0)? (yw>>1) : yw;
    int mxi = (DIM==1)? (xx>>1) : xx;
    float mv = masks_in[((size_t)b*HM + my)*WM + mxi];
    masks_out[((size_t)b*HH + yw)*WW + xx] = mv + 0.25f*sval;

    // ent = -sum p log p = log S - sum(e_i d_i)/S
    ent = __logf(S) - (e0*d0 + e1*d1 + e2*d2 + e3*d3)*inv;

    constexpr int FH = 256/HH, FW = 256/WW;
    float isum = 0.f;
    const float* ib = img + ((size_t)b*256 + yw*FH)*256 + xx*FW;
    #pragma unroll
    for (int dy=0; dy<FH; dy++)
      #pragma unroll
      for (int dx=0; dx<FW; dx++) isum += ib[dy*256+dx];
    float img_ds = isum * (1.0f/(FH*FW));
    float d = sval*(1.0f/3.0f) - img_ds;
    mse = d*d;
  }

  #pragma unroll
  for (int off=1; off<64; off<<=1){
    ent += __shfl_xor(ent, off, 64);
    mse += __shfl_xor(mse, off, 64);
  }
  if (lane == 0){ red[wv][0] = ent; red[wv][1] = mse; }
  __syncthreads();
  if (threadIdx.x == 0){
    float e  = red[0][0] + red[1][0] + red[2][0] + red[3][0];
    float ms = red[0][1] + red[1][1] + red[2][1] + red[3][1];
    int slot = blockIdx.x & (NSLOT-1);
    atomicAdd(accbuf + (2*STEP  )*NSLOT + slot, e);
    atomicAdd(accbuf + (2*STEP+1)*NSLOT + slot, ms);
  }
}

__global__ void finalize_kernel(const float* __restrict__ acc, float* __restrict__ out){
  int lane = threadIdx.x & 63;
  float v[12];
  #pragma unroll
  for (int i=0;i<12;i++){
    float x = acc[i*NSLOT + lane];
    #pragma unroll
    for (int off=1; off<64; off<<=1) x += __shfl_xor(x, off, 64);
    v[i] = x;
  }
  if (lane == 0){
    const float lw[6] = {0.1f,0.1f,0.5f,0.5f,1.0f,1.0f};
    const float nn[6] = {16384.f,32768.f,65536.f,131072.f,262144.f,524288.f};
    float L=0.f;
    for (int i=0;i<6;i++) L += lw[i]*((v[2*i] + v[2*i+1])/nn[i]);
    out[0]=L;
  }
}

extern "C" void kernel_launch(void* const* d_in, const int* in_sizes, int n_in,
                              void* d_out, int out_size, void* d_ws, size_t ws_size,
                              hipStream_t stream){
  const float* image  = (const float*)d_in[0];
  const float* w1=(const float*)d_in[2];  const float* b1=(const float*)d_in[3];
  const float* w2=(const float*)d_in[4];  const float* b2=(const float*)d_in[5];
  const float* w3=(const float*)d_in[6];  const float* b3=(const float*)d_in[7];
  const float* w4=(const float*)d_in[8];  const float* b4=(const float*)d_in[9];
  const float* upw=(const float*)d_in[10];const float* upb=(const float*)d_in[11];
  const float* mw=(const float*)d_in[12]; const float* mb=(const float*)d_in[13];
  const float* masks0=(const float*)d_in[14];
  float* out = (float*)d_out;

  char* ws = (char*)d_ws;
  size_t off = 0;
  auto alloc = [&](size_t bytes)->char*{
    char* p = ws + off; off += (bytes + 255) & ~(size_t)255; return p;
  };
  bf16* enc1  = (bf16*)alloc((size_t)8*256*256*16*2);
  bf16* enc2  = (bf16*)alloc((size_t)8*128*128*16*2);
  bf16* enc3  = (bf16*)alloc((size_t)8*64*64*32*2);
  bf16* featA = (bf16*)alloc((size_t)8*256*256*64*2);
  bf16* featB = (bf16*)alloc((size_t)8*256*128*64*2);
  float* mbA  = (float*)alloc((size_t)8*256*128*4);
  float* mbB  = (float*)alloc((size_t)8*128*128*4);
  bf16* packU = (bf16*)alloc((size_t)9*2*4*64*8*2);
  bf16* packM = (bf16*)alloc((size_t)9*2*64*8*2);
  float* acc  = (float*)alloc(12*NSLOT*sizeof(float));

  hipMemsetAsync(acc, 0, 12*NSLOT*sizeof(float), stream);

  repack_up  <<<144,256,0,stream>>>(upw, packU);
  repack_mask<<< 36,256,0,stream>>>(mw,  packM);

  // encoder
  trio_kernel<float,1,16,1,1,256,256><<<8*256*256/256,256,0,stream>>>(image,w1,b1,enc1);
  trio_kernel<bf16,16,16,2,2,256,256><<<8*128*128*2/256,256,0,stream>>>(enc1,w2,b2,enc2);
  trio_kernel<bf16,16,32,8,2,128,128><<<8*64*64*8/256,256,0,stream>>>(enc2,w3,b3,enc3);
  trio_kernel<bf16,32,64,16,2,64,64><<<8*32*32*16/256,256,0,stream>>>(enc3,w4,b4,featA);

  // step 0: (32,32) -> (64,32)
  upconv_dim0<32,32><<<128,256,0,stream>>>(featA,packU,upb,featB);
  maskloss_mfma<0,0,64,32,2><<<128,256,0,stream>>>(featB,packM,mb,image,masks0,mbA,acc);
  // step 1: (64,32) -> (64,64)
  upconv_dim1<64,32><<<256,256,0,stream>>>(featB,packU,upb,featA);
  maskloss_lds<1,1,64,64,1><<<512,256,0,stream>>>(featA,packM,mb,image,mbA,mbB,acc);
  // step 2: (64,64) -> (128,64)
  upconv_dim0_bs<64,64><<<512,256,0,stream>>>(featA,packU,upb,featB);
  maskloss_lds<2,0,128,64,1><<<1024,256,0,stream>>>(featB,packM,mb,image,mbB,mbA,acc);
  // step 3: (128,64) -> (128,128)
  upconv_dim1_bs<128,64><<<512,256,0,stream>>>(featB,packU,upb,featA);
  maskloss_lds<3,1,128,128,2><<<1024,256,0,stream>>>(featA,packM,mb,image,mbA,mbB,acc);
  // step 4: (128,128) -> (256,128)
  upconv_dim0_bs<128,128><<<2048,256,0,stream>>>(featA,packU,upb,featB);
  maskloss_lds<4,0,256,128,2><<<2048,256,0,stream>>>(featB,packM,mb,image,mbB,mbA,acc);
  // step 5: (256,128) -> (256,256)
  upconv_dim1_bs<256,128><<<2048,256,0,stream>>>(featB,packU,upb,featA);
  maskloss_lds<5,1,256,256,2><<<4096,256,0,stream>>>(featA,packM,mb,image,mbA,out+1,acc);

  finalize_kernel<<<1,64,0,stream>>>(acc,out);
}

// Round 7
// 351.357 us; speedup vs baseline: 1.3435x; 1.1486x over previous
//
#include <hip/hip_runtime.h>
#include <hip/hip_bf16.h>
#include <math.h>

typedef __hip_bfloat16 bf16;
typedef float f32x4 __attribute__((ext_vector_type(4)));
typedef __bf16 bf16x8 __attribute__((ext_vector_type(8)));

#define DEV __device__ __forceinline__

DEV float to_f(float v){ return v; }
DEV float to_f(bf16 v){ return __bfloat162float(v); }
DEV bf16 f2b(float v){ return __float2bfloat16(v); }
DEV unsigned short b2u(bf16 v){ return __builtin_bit_cast(unsigned short, v); }

DEV float gelu_f(float x){
  float z = 1.5957691216057308f*(x + 0.044715f*x*x*x);
  float e = __expf(-z);
  return x * __builtin_amdgcn_rcpf(1.0f + e);
}

DEV bf16x8 load_frag(const bf16* p, bool ok){
  uint4 u = make_uint4(0u,0u,0u,0u);
  if (ok) u = *(const uint4*)p;
  return __builtin_bit_cast(bf16x8, u);
}

DEV f32x4 mfma16(bf16x8 a, uint4 b, f32x4 c){
  return __builtin_amdgcn_mfma_f32_16x16x32_bf16(a, __builtin_bit_cast(bf16x8, b), c, 0, 0, 0);
}

DEV int swz8(int blk, int n){
  return (blk & 7) * (n >> 3) + (blk >> 3);
}

// async global->LDS DMA, 16 B per lane; lds dest wave-uniform base.
DEV void dma16(const void* g, void* l){
  __builtin_amdgcn_global_load_lds(
      (const __attribute__((address_space(1))) unsigned int*)g,
      (__attribute__((address_space(3))) unsigned int*)l,
      16, 0, 0);
}

#define NSLOT 64

// ---------------- encoder Conv_trio (VALU form — trio1/CIN=1 only) -------------
template<typename TIN, int CIN, int COUT, int SUB, int STRIDE, int HI, int WI>
__global__ void trio_kernel(const TIN* __restrict__ in, const float* __restrict__ w,
                            const float* __restrict__ bias, bf16* __restrict__ out){
  constexpr int HO = HI/STRIDE, WO = WI/STRIDE;
  constexpr int CO_PER = COUT/SUB;
  int gtid = blockIdx.x*blockDim.x + threadIdx.x;
  int sub = gtid % SUB;
  int pix = gtid / SUB;
  int b = pix / (HO*WO); int rem = pix % (HO*WO);
  int y = rem / WO, x = rem % WO;

  float acc[CO_PER];
  #pragma unroll
  for (int j=0;j<CO_PER;j++) acc[j]=0.f;

  for (int ky=0;ky<3;ky++){
    int iy = (STRIDE==1) ? (y+ky-1) : (2*y+ky);
    if (iy<0 || iy>=HI) continue;
    for (int kx=0;kx<3;kx++){
      int ix = (STRIDE==1) ? (x+kx-1) : (2*x+kx);
      if (ix<0 || ix>=WI) continue;
      const TIN* ip = in + ((size_t)(b*HI+iy)*WI+ix)*CIN;
      const float* wp = w + ((ky*3+kx)*CIN)*COUT + sub*CO_PER;
      #pragma unroll 4
      for (int ci=0; ci<CIN; ci++){
        float a = to_f(ip[ci]);
        const float4* w4 = (const float4*)(wp + (size_t)ci*COUT);
        #pragma unroll
        for (int j=0;j<CO_PER/4;j++){
          float4 ww = w4[j];
          acc[4*j+0] += a*ww.x; acc[4*j+1] += a*ww.y;
          acc[4*j+2] += a*ww.z; acc[4*j+3] += a*ww.w;
        }
      }
    }
  }

  float s1=0.f, s2=0.f;
  #pragma unroll
  for (int j=0;j<CO_PER;j++){
    acc[j] += bias[sub*CO_PER+j];
    s1 += acc[j]; s2 += acc[j]*acc[j];
  }
  #pragma unroll
  for (int off=1; off<SUB; off<<=1){
    s1 += __shfl_xor(s1,off,64);
    s2 += __shfl_xor(s2,off,64);
  }
  float mu  = s1*(1.0f/COUT);
  float var = s2*(1.0f/COUT) - mu*mu;
  float sc  = rsqrtf(var + 1e-6f);

  bf16* op = out + (size_t)pix*COUT + sub*CO_PER;
  #pragma unroll
  for (int j=0;j<CO_PER;j++) op[j] = f2b(gelu_f((acc[j]-mu)*sc));
}

// ---------------- MFMA encoder trios (CIN>=16, stride 2) ----------------------
// A: row=px=lane&15, k=quad*8+j; B: k -> cout=col=m; D: px=quad*4+r, cout=m.
// CIN=32: one K=32 MFMA per tap (k = cin).
// CIN=16: two taps per MFMA: tap = 2P+(quad>>1), ci=(quad&1)*8+j; pair 4 is
//         tap8 + zero-padded weights.
// Channel-norm: per-px sum over couts = shfl_xor over m (1,2,4,8), local nt.

template<int COUT>
__global__ void repack_c16(const float* __restrict__ w, bf16* __restrict__ bp){
  constexpr int NT = COUT/16;
  int v = blockIdx.x*256 + threadIdx.x;
  if (v >= 5*NT*64*8) return;
  int j = v & 7; int lane = (v>>3)&63; int idx = v>>9;
  int nt = idx % NT; int P = idx / NT;
  int m = lane & 15, quad = lane >> 4;
  int tp = quad >> 1;
  int ci = (quad & 1)*8 + j;
  int tap = 2*P + tp;
  int co = nt*16 + m;
  bp[v] = (tap < 9) ? f2b(w[((size_t)tap*16 + ci)*COUT + co]) : f2b(0.0f);
}

__global__ void repack_c32(const float* __restrict__ w, bf16* __restrict__ bp){
  int v = blockIdx.x*256 + threadIdx.x;
  if (v >= 9*4*64*8) return;
  int j = v & 7; int lane = (v>>3)&63; int idx = v>>9;
  int nt = idx & 3; int tap = idx >> 2;
  int m = lane & 15, quad = lane >> 4;
  int ci = quad*8 + j;
  int co = nt*16 + m;
  bp[v] = f2b(w[((size_t)tap*32 + ci)*64 + co]);
}

template<int CIN, int COUT, int HI, int WI>
__global__ void trio_mfma(const bf16* __restrict__ in, const bf16* __restrict__ bpack,
                          const float* __restrict__ bias, bf16* __restrict__ out){
  constexpr int HO = HI/2, WO = WI/2, NT = COUT/16;
  constexpr int TPR = WO/16;
  int lane = threadIdx.x & 63, wv = threadIdx.x >> 6;
  int wtile = blockIdx.x*4 + wv;
  int m = lane & 15, quad = lane >> 4;

  int x0 = (wtile % TPR)*16;
  int oy = (wtile / TPR) % HO;
  int b  = wtile / (TPR*HO);

  const uint4* bp4 = (const uint4*)bpack;

  f32x4 acc[NT];
  #pragma unroll
  for (int nt=0;nt<NT;nt++) acc[nt] = (f32x4){0.f,0.f,0.f,0.f};

  if constexpr (CIN == 32){
    #pragma unroll
    for (int tap=0; tap<9; tap++){
      int ky = tap/3, kx = tap%3;
      int iy = 2*oy + ky;
      int ix = 2*(x0 + m) + kx;
      bool ok = (iy < HI) && (ix < WI);
      bf16x8 a = load_frag(in + ((size_t)(b*HI+iy)*WI + ix)*32 + quad*8, ok);
      #pragma unroll
      for (int nt=0;nt<NT;nt++)
        acc[nt] = mfma16(a, bp4[(tap*NT+nt)*64 + lane], acc[nt]);
    }
  } else {  // CIN == 16, taps packed in pairs
    #pragma unroll
    for (int P=0; P<5; P++){
      int tap = 2*P + (quad >> 1);
      int ky = tap/3, kx = tap - ky*3;
      int iy = 2*oy + ky;
      int ix = 2*(x0 + m) + kx;
      bool ok = (tap < 9) && (iy < HI) && (ix < WI);
      bf16x8 a = load_frag(in + ((size_t)(b*HI+iy)*WI + ix)*16 + (quad&1)*8, ok);
      #pragma unroll
      for (int nt=0;nt<NT;nt++)
        acc[nt] = mfma16(a, bp4[(P*NT+nt)*64 + lane], acc[nt]);
    }
  }

  // bias + channel norm (per px = quad*4+r, over COUT couts) + gelu + store
  float av[NT][4];
  float s1[4] = {0.f,0.f,0.f,0.f}, s2[4] = {0.f,0.f,0.f,0.f};
  #pragma unroll
  for (int nt=0;nt<NT;nt++){
    float bv = bias[nt*16 + m];
    #pragma unroll
    for (int r=0;r<4;r++){
      float v = acc[nt][r] + bv;
      av[nt][r] = v;
      s1[r] += v; s2[r] += v*v;
    }
  }
  #pragma unroll
  for (int r=0;r<4;r++){
    #pragma unroll
    for (int off=1; off<16; off<<=1){
      s1[r] += __shfl_xor(s1[r], off, 64);
      s2[r] += __shfl_xor(s2[r], off, 64);
    }
  }
  #pragma unroll
  for (int r=0;r<4;r++){
    float mu  = s1[r]*(1.0f/COUT);
    float var = s2[r]*(1.0f/COUT) - mu*mu;
    float sc  = rsqrtf(var + 1e-6f);
    size_t px = ((size_t)(b*HO + oy))*WO + x0 + quad*4 + r;
    #pragma unroll
    for (int nt=0;nt<NT;nt++)
      out[px*COUT + nt*16 + m] = f2b(gelu_f((av[nt][r]-mu)*sc));
  }
}

// ---------------- weight repack (upconv / mask) --------------------------------
__global__ void repack_up(const float* __restrict__ w, bf16* __restrict__ bp){
  int v = blockIdx.x*256 + threadIdx.x;
  if (v >= 9*2*4*64*8) return;
  int j = v & 7; int lane = (v>>3)&63; int nt = (v>>9)&3; int c = (v>>11)&1; int tap = v>>12;
  int ci = c*32 + (lane>>4)*8 + j;
  int co = (lane&15)*4 + nt;
  bp[v] = f2b(w[(tap*64+ci)*64 + co]);
}

__global__ void repack_mask(const float* __restrict__ w, bf16* __restrict__ bp){
  int v = blockIdx.x*256 + threadIdx.x;
  if (v >= 9*2*64*8) return;
  int j = v & 7; int lane = (v>>3)&63; int c = (v>>9)&1; int tap = v>>10;
  int ci = c*32 + (lane>>4)*8 + j;
  int n = lane & 15;
  bp[v] = (n < 4) ? f2b(w[(tap*64+ci)*4 + n]) : f2b(0.0f);
}

// ------------- conv_transpose, stride-2 along y (DIM=0) — register form -------
template<int HI, int WI>
__global__ void upconv_dim0(const bf16* __restrict__ in, const bf16* __restrict__ bpack,
                            const float* __restrict__ upb, bf16* __restrict__ out){
  constexpr int HO = 2*HI, WO = WI, XT = WI/32;
  int lane = threadIdx.x & 63, wv = threadIdx.x >> 6;
  int wtile = swz8(blockIdx.x, gridDim.x)*4 + wv;
  int m = lane & 15, quad = lane >> 4;

  int x0 = (wtile % XT)*32;
  int o  = (wtile / XT) % HO;
  int b  = wtile / (XT*HO);

  int q = o >> 1;
  int stk[2], stq[2]; int nst;
  if (o & 1){ stk[0]=1; stq[0]=q; nst=1; }
  else {
    nst = 0;
    if (q >= 1){ stk[0]=0; stq[0]=q-1; nst=1; }
    stk[nst]=2; stq[nst]=q; nst++;
  }

  f32x4 acc[2][4];
  #pragma unroll
  for (int t=0;t<2;t++)
    #pragma unroll
    for (int nt=0;nt<4;nt++) acc[t][nt] = (f32x4){0.f,0.f,0.f,0.f};

  const uint4* bp4 = (const uint4*)bpack;

  #pragma unroll 1
  for (int s=0; s<nst; s++){
    int kyt = stk[s];
    const bf16* rowp = in + ((size_t)(b*HI+stq[s])*WI)*64 + quad*8;
    #pragma unroll
    for (int ut=0; ut<3; ut++){
      #pragma unroll
      for (int c=0;c<2;c++){
        int ix0 = x0 + m - 1 + ut;
        int ix1 = ix0 + 16;
        bf16x8 a0 = load_frag(rowp + (size_t)ix0*64 + c*32, ix0>=0 && ix0<WI);
        bf16x8 a1 = load_frag(rowp + (size_t)ix1*64 + c*32, ix1>=0 && ix1<WI);
        #pragma unroll
        for (int nt=0;nt<4;nt++){
          uint4 Bq = bp4[(((kyt*3+ut)*2+c)*4+nt)*64 + lane];
          acc[0][nt] = mfma16(a0, Bq, acc[0][nt]);
          acc[1][nt] = mfma16(a1, Bq, acc[1][nt]);
        }
      }
    }
  }

  float4 bv = *(const float4*)(upb + m*4);
  size_t rowbase = ((size_t)b*HO + o)*WO;
  #pragma unroll
  for (int t=0;t<2;t++){
    #pragma unroll
    for (int r=0;r<4;r++){
      int p = x0 + t*16 + quad*4 + r;
      float g0 = gelu_f(acc[t][0][r] + bv.x);
      float g1 = gelu_f(acc[t][1][r] + bv.y);
      float g2 = gelu_f(acc[t][2][r] + bv.z);
      float g3 = gelu_f(acc[t][3][r] + bv.w);
      unsigned int lo = (unsigned int)b2u(f2b(g0)) | ((unsigned int)b2u(f2b(g1))<<16);
      unsigned int hi = (unsigned int)b2u(f2b(g2)) | ((unsigned int)b2u(f2b(g3))<<16);
      *(uint2*)(out + (rowbase + p)*64 + m*4) = make_uint2(lo,hi);
    }
  }
}

// ------------- conv_transpose dim0 + B-pack in LDS (r4-validated mechanism) ----
template<int HI, int WI>
__global__ void __launch_bounds__(256,2)
upconv_dim0_bs(const bf16* __restrict__ in, const bf16* __restrict__ bpack,
               const float* __restrict__ upb, bf16* __restrict__ out){
  constexpr int HO = 2*HI, WO = WI, XT = WI/32;
  __shared__ __align__(16) uint4 Bsh[4608];          // 72 KB
  int tid = threadIdx.x, lane = tid & 63, wv = tid >> 6;
  int wtile = swz8(blockIdx.x, gridDim.x)*4 + wv;
  int m = lane & 15, quad = lane >> 4;

  int x0 = (wtile % XT)*32;
  int o  = (wtile / XT) % HO;
  int b  = wtile / (XT*HO);

  {
    const uint4* gp = (const uint4*)bpack;
    #pragma unroll
    for (int k=0;k<18;k++){
      int base = (wv*18 + k)*64;
      dma16(gp + base + lane, Bsh + base);
    }
  }

  int q = o >> 1;
  int stk[2], stq[2]; int nst;
  if (o & 1){ stk[0]=1; stq[0]=q; nst=1; }
  else {
    nst = 0;
    if (q >= 1){ stk[0]=0; stq[0]=q-1; nst=1; }
    stk[nst]=2; stq[nst]=q; nst++;
  }

  f32x4 acc[2][4];
  #pragma unroll
  for (int t=0;t<2;t++)
    #pragma unroll
    for (int nt=0;nt<4;nt++) acc[t][nt] = (f32x4){0.f,0.f,0.f,0.f};

  asm volatile("s_waitcnt vmcnt(0)" ::: "memory");
  __syncthreads();

  #pragma unroll 1
  for (int s=0; s<nst; s++){
    int kyt = stk[s];
    const bf16* rowp = in + ((size_t)(b*HI+stq[s])*WI)*64 + quad*8;
    #pragma unroll
    for (int ut=0; ut<3; ut++){
      #pragma unroll
      for (int c=0;c<2;c++){
        int ix0 = x0 + m - 1 + ut;
        int ix1 = ix0 + 16;
        bf16x8 a0 = load_frag(rowp + (size_t)ix0*64 + c*32, ix0>=0 && ix0<WI);
        bf16x8 a1 = load_frag(rowp + (size_t)ix1*64 + c*32, ix1>=0 && ix1<WI);
        #pragma unroll
        for (int nt=0;nt<4;nt++){
          uint4 Bq = Bsh[(((kyt*3+ut)*2+c)*4+nt)*64 + lane];
          acc[0][nt] = mfma16(a0, Bq, acc[0][nt]);
          acc[1][nt] = mfma16(a1, Bq, acc[1][nt]);
        }
      }
    }
  }

  float4 bv = *(const float4*)(upb + m*4);
  size_t rowbase = ((size_t)b*HO + o)*WO;
  #pragma unroll
  for (int t=0;t<2;t++){
    #pragma unroll
    for (int r=0;r<4;r++){
      int p = x0 + t*16 + quad*4 + r;
      float g0 = gelu_f(acc[t][0][r] + bv.x);
      float g1 = gelu_f(acc[t][1][r] + bv.y);
      float g2 = gelu_f(acc[t][2][r] + bv.z);
      float g3 = gelu_f(acc[t][3][r] + bv.w);
      unsigned int lo = (unsigned int)b2u(f2b(g0)) | ((unsigned int)b2u(f2b(g1))<<16);
      unsigned int hi = (unsigned int)b2u(f2b(g2)) | ((unsigned int)b2u(f2b(g3))<<16);
      *(uint2*)(out + (rowbase + p)*64 + m*4) = make_uint2(lo,hi);
    }
  }
}

// ------------- conv_transpose dim1, register form — small grids (step 1) ------
template<int HI, int WI>
__global__ void upconv_dim1(const bf16* __restrict__ in, const bf16* __restrict__ bpack,
                            const float* __restrict__ upb, bf16* __restrict__ out){
  constexpr int HO = HI, WO = 2*WI, QT = WI/16;
  int lane = threadIdx.x & 63, wv = threadIdx.x >> 6;
  int wtile = swz8(blockIdx.x, gridDim.x)*4 + wv;
  int m = lane & 15, quad = lane >> 4;

  int q0 = (wtile % QT)*16;
  int y  = (wtile / QT) % HI;
  int b  = wtile / (QT*HI);

  f32x4 ae[4], ao[4];
  #pragma unroll
  for (int nt=0;nt<4;nt++){ ae[nt]=(f32x4){0.f,0.f,0.f,0.f}; ao[nt]=(f32x4){0.f,0.f,0.f,0.f}; }

  const uint4* bp4 = (const uint4*)bpack;

  #pragma unroll 1
  for (int ky=0; ky<3; ky++){
    int iy = y + ky - 1;
    if (iy < 0 || iy >= HI) continue;
    const bf16* rowp = in + ((size_t)(b*HI+iy)*WI)*64 + quad*8;
    #pragma unroll
    for (int c=0;c<2;c++){
      int qa = q0 + m;
      bf16x8 Au = load_frag(rowp + (size_t)qa*64 + c*32, true);
      bf16x8 As = load_frag(rowp + (size_t)(qa-1)*64 + c*32, qa >= 1);
      #pragma unroll
      for (int nt=0;nt<4;nt++){
        uint4 B0 = bp4[(((ky*3+0)*2+c)*4+nt)*64 + lane];
        uint4 B1 = bp4[(((ky*3+1)*2+c)*4+nt)*64 + lane];
        uint4 B2 = bp4[(((ky*3+2)*2+c)*4+nt)*64 + lane];
        ae[nt] = mfma16(As, B0, ae[nt]);
        ae[nt] = mfma16(Au, B2, ae[nt]);
        ao[nt] = mfma16(Au, B1, ao[nt]);
      }
    }
  }

  float4 bv = *(const float4*)(upb + m*4);
  size_t rowbase = ((size_t)b*HO + y)*WO;
  #pragma unroll
  for (int r=0;r<4;r++){
    int qq = q0 + quad*4 + r;
    {
      float g0 = gelu_f(ae[0][r] + bv.x);
      float g1 = gelu_f(ae[1][r] + bv.y);
      float g2 = gelu_f(ae[2][r] + bv.z);
      float g3 = gelu_f(ae[3][r] + bv.w);
      unsigned int lo = (unsigned int)b2u(f2b(g0)) | ((unsigned int)b2u(f2b(g1))<<16);
      unsigned int hi = (unsigned int)b2u(f2b(g2)) | ((unsigned int)b2u(f2b(g3))<<16);
      *(uint2*)(out + (rowbase + 2*qq)*64 + m*4) = make_uint2(lo,hi);
    }
    {
      float g0 = gelu_f(ao[0][r] + bv.x);
      float g1 = gelu_f(ao[1][r] + bv.y);
      float g2 = gelu_f(ao[2][r] + bv.z);
      float g3 = gelu_f(ao[3][r] + bv.w);
      unsigned int lo = (unsigned int)b2u(f2b(g0)) | ((unsigned int)b2u(f2b(g1))<<16);
      unsigned int hi = (unsigned int)b2u(f2b(g2)) | ((unsigned int)b2u(f2b(g3))<<16);
      *(uint2*)(out + (rowbase + 2*qq+1)*64 + m*4) = make_uint2(lo,hi);
    }
  }
}

// ------------- conv_transpose dim1, 2-row + B-pack in LDS (r4-validated) ------
template<int HI, int WI>
__global__ void __launch_bounds__(256,2)
upconv_dim1_bs(const bf16* __restrict__ in, const bf16* __restrict__ bpack,
               const float* __restrict__ upb, bf16* __restrict__ out){
  constexpr int HO = HI, WO = 2*WI, QT = WI/16;
  __shared__ __align__(16) uint4 Bsh[4608];          // 72 KB: full dim1 B-pack
  int tid = threadIdx.x, lane = tid & 63, wv = tid >> 6;
  int wtile = swz8(blockIdx.x, gridDim.x)*4 + wv;
  int m = lane & 15, quad = lane >> 4;

  int q0 = (wtile % QT)*16;
  int y  = ((wtile / QT) % (HI/2)) * 2;
  int b  = wtile / (QT*(HI/2));

  {
    const uint4* gp = (const uint4*)bpack;
    #pragma unroll
    for (int k=0;k<18;k++){
      int base = (wv*18 + k)*64;
      dma16(gp + base + lane, Bsh + base);
    }
  }

  int qa = q0 + m;

  bf16x8 Afr[4][2][2];              // [row4][c][{Au,As}]
  #pragma unroll
  for (int i4=0;i4<4;i4++){
    int iy = y + i4 - 1;
    bool ok = (iy>=0) && (iy<HI);
    const bf16* rowp = in + ((size_t)(b*HI+iy)*WI)*64 + quad*8;
    #pragma unroll
    for (int c=0;c<2;c++){
      Afr[i4][c][0] = load_frag(rowp + (size_t)qa*64 + c*32, ok);
      Afr[i4][c][1] = load_frag(rowp + (size_t)(qa-1)*64 + c*32, ok && qa >= 1);
    }
  }

  asm volatile("s_waitcnt vmcnt(0)" ::: "memory");
  __syncthreads();

  f32x4 ae[2][4], ao[2][4];
  #pragma unroll
  for (int r=0;r<2;r++)
    #pragma unroll
    for (int nt=0;nt<4;nt++){ ae[r][nt]=(f32x4){0.f,0.f,0.f,0.f}; ao[r][nt]=(f32x4){0.f,0.f,0.f,0.f}; }

  #pragma unroll
  for (int ky=0; ky<3; ky++){
    #pragma unroll
    for (int c=0;c<2;c++){
      #pragma unroll
      for (int nt=0;nt<4;nt++){
        uint4 B0 = Bsh[(((ky*3+0)*2+c)*4+nt)*64 + lane];
        uint4 B1 = Bsh[(((ky*3+1)*2+c)*4+nt)*64 + lane];
        uint4 B2 = Bsh[(((ky*3+2)*2+c)*4+nt)*64 + lane];
        #pragma unroll
        for (int r=0;r<2;r++){
          ae[r][nt] = mfma16(Afr[ky+r][c][1], B0, ae[r][nt]);
          ae[r][nt] = mfma16(Afr[ky+r][c][0], B2, ae[r][nt]);
          ao[r][nt] = mfma16(Afr[ky+r][c][0], B1, ao[r][nt]);
        }
      }
    }
  }

  float4 bv = *(const float4*)(upb + m*4);
  #pragma unroll
  for (int r2=0;r2<2;r2++){
    size_t rowbase = ((size_t)b*HO + y + r2)*WO;
    #pragma unroll
    for (int r=0;r<4;r++){
      int qq = q0 + quad*4 + r;
      {
        float g0 = gelu_f(ae[r2][0][r] + bv.x);
        float g1 = gelu_f(ae[r2][1][r] + bv.y);
        float g2 = gelu_f(ae[r2][2][r] + bv.z);
        float g3 = gelu_f(ae[r2][3][r] + bv.w);
        unsigned int lo = (unsigned int)b2u(f2b(g0)) | ((unsigned int)b2u(f2b(g1))<<16);
        unsigned int hi = (unsigned int)b2u(f2b(g2)) | ((unsigned int)b2u(f2b(g3))<<16);
        *(uint2*)(out + (rowbase + 2*qq)*64 + m*4) = make_uint2(lo,hi);
      }
      {
        float g0 = gelu_f(ao[r2][0][r] + bv.x);
        float g1 = gelu_f(ao[r2][1][r] + bv.y);
        float g2 = gelu_f(ao[r2][2][r] + bv.z);
        float g3 = gelu_f(ao[r2][3][r] + bv.w);
        unsigned int lo = (unsigned int)b2u(f2b(g0)) | ((unsigned int)b2u(f2b(g1))<<16);
        unsigned int hi = (unsigned int)b2u(f2b(g2)) | ((unsigned int)b2u(f2b(g3))<<16);
        *(uint2*)(out + (rowbase + 2*qq+1)*64 + m*4) = make_uint2(lo,hi);
      }
    }
  }
}

// ---------------- maskloss, register form — step 0 only ------------------------
template<int STEP, int DIM, int HH, int WW, int TILES>
__global__ void maskloss_mfma(const bf16* __restrict__ feat, const bf16* __restrict__ mpack,
                              const float* __restrict__ mb, const float* __restrict__ img,
                              const float* __restrict__ masks_in, float* __restrict__ masks_out,
                              float* __restrict__ accbuf){
  __shared__ float llog[4][64][4];
  __shared__ float red[4][2];
  int lane = threadIdx.x & 63;
  int wv   = threadIdx.x >> 6;
  int wtile = swz8(blockIdx.x, gridDim.x)*4 + wv;
  int m = lane & 15, quad = lane >> 4;

  constexpr int TPR = WW/(16*TILES);
  int x0 = (wtile % TPR)*(16*TILES);
  int y  = (wtile / TPR) % HH;
  int b  = wtile / (TPR*HH);

  const uint4* bp4 = (const uint4*)mpack;

  #pragma unroll 1
  for (int t=0; t<TILES; t++){
    f32x4 acc4 = (f32x4){0.f,0.f,0.f,0.f};
    #pragma unroll
    for (int c=0;c<2;c++){
      bf16x8 afr[9];
      #pragma unroll
      for (int ky=0; ky<3; ky++){
        int iy = y + ky - 1;
        bool rowok = (iy >= 0) && (iy < HH);
        const bf16* rowp = feat + ((size_t)(b*HH+iy)*WW)*64 + quad*8 + c*32;
        #pragma unroll
        for (int kx=0; kx<3; kx++){
          int ix = x0 + t*16 + m + kx - 1;
          bool ok = rowok && (ix >= 0) && (ix < WW);
          afr[ky*3+kx] = load_frag(rowp + (size_t)ix*64, ok);
        }
      }
      #pragma unroll
      for (int tap=0; tap<9; tap++){
        uint4 bb = bp4[(tap*2+c)*64 + lane];
        acc4 = mfma16(afr[tap], bb, acc4);
      }
    }
    if (m < 4){
      #pragma unroll
      for (int r=0;r<4;r++) llog[wv][t*16 + quad*4 + r][m] = acc4[r] + mb[m];
    }
  }
  __syncthreads();

  float ent = 0.f, mse = 0.f;
  if (lane < 16*TILES){
    int p = lane; int xx = x0 + p;
    float l0 = llog[wv][p][0], l1 = llog[wv][p][1];
    float l2 = llog[wv][p][2], l3 = llog[wv][p][3];
    float mx = fmaxf(fmaxf(l0,l1), fmaxf(l2,l3));
    float d0=l0-mx, d1=l1-mx, d2=l2-mx, d3=l3-mx;
    float e0=__expf(d0), e1=__expf(d1), e2=__expf(d2), e3=__expf(d3);
    float S = e0+e1+e2+e3;
    float inv = __builtin_amdgcn_rcpf(S);
    float sval = (e1 + 2.f*e2 + 3.f*e3)*inv;

    constexpr int HM = (DIM==0)? HH/2 : HH;
    constexpr int WM = (DIM==0)? WW : WW/2;
    int my = (DIM==0)? (y>>1) : y;
    int mxi = (DIM==1)? (xx>>1) : xx;
    float mv = masks_in[((size_t)b*HM + my)*WM + mxi];
    masks_out[((size_t)b*HH + y)*WW + xx] = mv + 0.25f*sval;

    ent = __logf(S) - (e0*d0 + e1*d1 + e2*d2 + e3*d3)*inv;

    constexpr int FH = 256/HH, FW = 256/WW;
    float isum = 0.f;
    const float* ib = img + ((size_t)b*256 + y*FH)*256 + xx*FW;
    #pragma unroll
    for (int dy=0; dy<FH; dy++)
      #pragma unroll
      for (int dx=0; dx<FW; dx++) isum += ib[dy*256+dx];
    float img_ds = isum * (1.0f/(FH*FW));
    float d = sval*(1.0f/3.0f) - img_ds;
    mse = d*d;
  }

  #pragma unroll
  for (int off=1; off<64; off<<=1){
    ent += __shfl_xor(ent, off, 64);
    mse += __shfl_xor(mse, off, 64);
  }
  if (lane == 0){ red[wv][0] = ent; red[wv][1] = mse; }
  __syncthreads();
  if (threadIdx.x == 0){
    float e  = red[0][0] + red[1][0] + red[2][0] + red[3][0];
    float ms = red[0][1] + red[1][1] + red[2][1] + red[3][1];
    int slot = blockIdx.x & (NSLOT-1);
    atomicAdd(accbuf + (2*STEP  )*NSLOT + slot, e);
    atomicAdd(accbuf + (2*STEP+1)*NSLOT + slot, ms);
  }
}

// ---------------- maskloss via async LDS staging (WW >= 64) --------------------
template<int STEP, int DIM, int HH, int WW, int ROWS>
__global__ void maskloss_lds(const bf16* __restrict__ feat, const bf16* __restrict__ mpack,
                             const float* __restrict__ mb, const float* __restrict__ img,
                             const float* __restrict__ masks_in, float* __restrict__ masks_out,
                             float* __restrict__ accbuf){
  constexpr int NBrow = WW/64;
  constexpr int PITCH = 9216;                // 72 px * 128 B
  constexpr int NR = ROWS + 2;
  constexpr int WPR = 4/ROWS;                // waves per row
  __shared__ __align__(16) char smem[NR*PITCH];
  __shared__ float llog[4][ROWS][16][4];
  __shared__ float red[4][2];
  int tid = threadIdx.x;
  int lane = tid & 63, wv = tid >> 6;
  int bi = swz8(blockIdx.x, gridDim.x);
  int x0 = (bi % NBrow)*64;
  int y0 = ((bi / NBrow) % (HH/ROWS)) * ROWS;
  int b  = bi / (NBrow*(HH/ROWS));
  int m = lane & 15, quad = lane >> 4;
  int lanesw = ((lane ^ (lane>>3)) << 4);    // pre-swizzled lane*16

  int r_w   = wv / WPR;                      // wave's row within block
  int xbase = (wv % WPR) * (16*ROWS);        // wave's x window (ROWS tiles)
  int yw    = y0 + r_w;                      // wave's absolute output row

  for (int k = wv; k < NR*9; k += 4){
    int r = k/9, coff = (k%9)*1024;
    int iy = y0 + r - 1;
    if (iy < 0 || iy >= HH) continue;
    const char* g = (const char*)(feat + ((size_t)(b*HH+iy)*WW + x0 - 1)*64)
                    + coff + lanesw;
    dma16(g, smem + r*PITCH + coff);
  }
  asm volatile("s_waitcnt vmcnt(0)" ::: "memory");
  __syncthreads();
  if (x0 == 0 && tid < 32*NR)
    ((float*)(smem + (tid>>5)*PITCH))[tid & 31] = 0.f;
  if (x0 + 64 == WW && tid >= 128 && tid < 128 + 32*NR){
    int t = tid - 128;
    ((float*)(smem + (t>>5)*PITCH + 65*128))[t & 31] = 0.f;
  }
  __syncthreads();

  const uint4* bp4 = (const uint4*)mpack;
  #pragma unroll
  for (int t=0; t<ROWS; t++){
    f32x4 accA = (f32x4){0.f,0.f,0.f,0.f};
    f32x4 accB = (f32x4){0.f,0.f,0.f,0.f};
    #pragma unroll
    for (int ky=0; ky<3; ky++){
      int iyw = yw + ky - 1;
      if (iyw < 0 || iyw >= HH) continue;
      const char* rowl = smem + (size_t)(r_w + ky)*PITCH;
      #pragma unroll
      for (int kx=0; kx<3; kx++){
        int lp = xbase + t*16 + m + kx;
        const char* pl = rowl + (size_t)lp*128;
        int xw = (lp & 7) << 4;
        bf16x8 a0 = __builtin_bit_cast(bf16x8, *(const uint4*)(pl + ((quad*16     ) ^ xw)));
        bf16x8 a1 = __builtin_bit_cast(bf16x8, *(const uint4*)(pl + ((quad*16 + 64) ^ xw)));
        uint4 b0 = bp4[((ky*3+kx)*2+0)*64 + lane];
        uint4 b1 = bp4[((ky*3+kx)*2+1)*64 + lane];
        accA = mfma16(a0, b0, accA);
        accB = mfma16(a1, b1, accB);
      }
    }
    if (m < 4){
      #pragma unroll
      for (int r=0;r<4;r++) llog[wv][t][quad*4+r][m] = accA[r] + accB[r] + mb[m];
    }
  }
  __syncthreads();

  float ent = 0.f, mse = 0.f;
  if (lane < 16*ROWS){
    int t = lane >> 4;
    int p = lane & 15;
    int xx = x0 + xbase + t*16 + p;
    float l0 = llog[wv][t][p][0], l1 = llog[wv][t][p][1];
    float l2 = llog[wv][t][p][2], l3 = llog[wv][t][p][3];
    float mx = fmaxf(fmaxf(l0,l1), fmaxf(l2,l3));
    float d0=l0-mx, d1=l1-mx, d2=l2-mx, d3=l3-mx;
    float e0=__expf(d0), e1=__expf(d1), e2=__expf(d2), e3=__expf(d3);
    float S = e0+e1+e2+e3;
    float inv = __builtin_amdgcn_rcpf(S);
    float sval = (e1 + 2.f*e2 + 3.f*e3)*inv;

    constexpr int HM = (DIM==0)? HH/2 : HH;
    constexpr int WM = (DIM==0)? WW : WW/2;
    int my = (DIM==0)? (yw>>1) : yw;
    int mxi = (DIM==1)? (xx>>1) : xx;
    float mv = masks_in[((size_t)b*HM + my)*WM + mxi];
    masks_out[((size_t)b*HH + yw)*WW + xx] = mv + 0.25f*sval;

    ent = __logf(S) - (e0*d0 + e1*d1 + e2*d2 + e3*d3)*inv;

    constexpr int FH = 256/HH, FW = 256/WW;
    float isum = 0.f;
    const float* ib = img + ((size_t)b*256 + yw*FH)*256 + xx*FW;
    #pragma unroll
    for (int dy=0; dy<FH; dy++)
      #pragma unroll
      for (int dx=0; dx<FW; dx++) isum += ib[dy*256+dx];
    float img_ds = isum * (1.0f/(FH*FW));
    float d = sval*(1.0f/3.0f) - img_ds;
    mse = d*d;
  }

  #pragma unroll
  for (int off=1; off<64; off<<=1){
    ent += __shfl_xor(ent, off, 64);
    mse += __shfl_xor(mse, off, 64);
  }
  if (lane == 0){ red[wv][0] = ent; red[wv][1] = mse; }
  __syncthreads();
  if (threadIdx.x == 0){
    float e  = red[0][0] + red[1][0] + red[2][0] + red[3][0];
    float ms = red[0][1] + red[1][1] + red[2][1] + red[3][1];
    int slot = blockIdx.x & (NSLOT-1);
    atomicAdd(accbuf + (2*STEP  )*NSLOT + slot, e);
    atomicAdd(accbuf + (2*STEP+1)*NSLOT + slot, ms);
  }
}

__global__ void finalize_kernel(const float* __restrict__ acc, float* __restrict__ out){
  int lane = threadIdx.x & 63;
  float v[12];
  #pragma unroll
  for (int i=0;i<12;i++){
    float x = acc[i*NSLOT + lane];
    #pragma unroll
    for (int off=1; off<64; off<<=1) x += __shfl_xor(x, off, 64);
    v[i] = x;
  }
  if (lane == 0){
    const float lw[6] = {0.1f,0.1f,0.5f,0.5f,1.0f,1.0f};
    const float nn[6] = {16384.f,32768.f,65536.f,131072.f,262144.f,524288.f};
    float L=0.f;
    for (int i=0;i<6;i++) L += lw[i]*((v[2*i] + v[2*i+1])/nn[i]);
    out[0]=L;
  }
}

extern "C" void kernel_launch(void* const* d_in, const int* in_sizes, int n_in,
                              void* d_out, int out_size, void* d_ws, size_t ws_size,
                              hipStream_t stream){
  const float* image  = (const float*)d_in[0];
  const float* w1=(const float*)d_in[2];  const float* b1=(const float*)d_in[3];
  const float* w2=(const float*)d_in[4];  const float* b2=(const float*)d_in[5];
  const float* w3=(const float*)d_in[6];  const float* b3=(const float*)d_in[7];
  const float* w4=(const float*)d_in[8];  const float* b4=(const float*)d_in[9];
  const float* upw=(const float*)d_in[10];const float* upb=(const float*)d_in[11];
  const float* mw=(const float*)d_in[12]; const float* mb=(const float*)d_in[13];
  const float* masks0=(const float*)d_in[14];
  float* out = (float*)d_out;

  char* ws = (char*)d_ws;
  size_t off = 0;
  auto alloc = [&](size_t bytes)->char*{
    char* p = ws + off; off += (bytes + 255) & ~(size_t)255; return p;
  };
  bf16* enc1  = (bf16*)alloc((size_t)8*256*256*16*2);
  bf16* enc2  = (bf16*)alloc((size_t)8*128*128*16*2);
  bf16* enc3  = (bf16*)alloc((size_t)8*64*64*32*2);
  bf16* featA = (bf16*)alloc((size_t)8*256*256*64*2);
  bf16* featB = (bf16*)alloc((size_t)8*256*128*64*2);
  float* mbA  = (float*)alloc((size_t)8*256*128*4);
  float* mbB  = (float*)alloc((size_t)8*128*128*4);
  bf16* packU = (bf16*)alloc((size_t)9*2*4*64*8*2);
  bf16* packM = (bf16*)alloc((size_t)9*2*64*8*2);
  bf16* packT2= (bf16*)alloc((size_t)5*1*64*8*2);
  bf16* packT3= (bf16*)alloc((size_t)5*2*64*8*2);
  bf16* packT4= (bf16*)alloc((size_t)9*4*64*8*2);
  float* acc  = (float*)alloc(12*NSLOT*sizeof(float));

  hipMemsetAsync(acc, 0, 12*NSLOT*sizeof(float), stream);

  repack_up  <<<144,256,0,stream>>>(upw, packU);
  repack_mask<<< 36,256,0,stream>>>(mw,  packM);
  repack_c16<16><<<10,256,0,stream>>>(w2, packT2);
  repack_c16<32><<<20,256,0,stream>>>(w3, packT3);
  repack_c32    <<<72,256,0,stream>>>(w4, packT4);

  // encoder
  trio_kernel<float,1,16,1,1,256,256><<<8*256*256/256,256,0,stream>>>(image,w1,b1,enc1);
  trio_mfma<16,16,256,256><<<8*128*128/16/4,256,0,stream>>>(enc1,packT2,b2,enc2);
  trio_mfma<16,32,128,128><<<8*64*64/16/4,256,0,stream>>>(enc2,packT3,b3,enc3);
  trio_mfma<32,64,64,64><<<8*32*32/16/4,256,0,stream>>>(enc3,packT4,b4,featA);

  // step 0: (32,32) -> (64,32)
  upconv_dim0<32,32><<<128,256,0,stream>>>(featA,packU,upb,featB);
  maskloss_mfma<0,0,64,32,2><<<128,256,0,stream>>>(featB,packM,mb,image,masks0,mbA,acc);
  // step 1: (64,32) -> (64,64)
  upconv_dim1<64,32><<<256,256,0,stream>>>(featB,packU,upb,featA);
  maskloss_lds<1,1,64,64,1><<<512,256,0,stream>>>(featA,packM,mb,image,mbA,mbB,acc);
  // step 2: (64,64) -> (128,64)
  upconv_dim0_bs<64,64><<<512,256,0,stream>>>(featA,packU,upb,featB);
  maskloss_lds<2,0,128,64,1><<<1024,256,0,stream>>>(featB,packM,mb,image,mbB,mbA,acc);
  // step 3: (128,64) -> (128,128)
  upconv_dim1_bs<128,64><<<512,256,0,stream>>>(featB,packU,upb,featA);
  maskloss_lds<3,1,128,128,2><<<1024,256,0,stream>>>(featA,packM,mb,image,mbA,mbB,acc);
  // step 4: (128,128) -> (256,128)
  upconv_dim0_bs<128,128><<<2048,256,0,stream>>>(featA,packU,upb,featB);
  maskloss_lds<4,0,256,128,2><<<2048,256,0,stream>>>(featB,packM,mb,image,mbB,mbA,acc);
  // step 5: (256,128) -> (256,256)
  upconv_dim1_bs<256,128><<<2048,256,0,stream>>>(featB,packU,upb,featA);
  maskloss_lds<5,1,256,256,2><<<4096,256,0,stream>>>(featA,packM,mb,image,mbA,out+1,acc);

  finalize_kernel<<<1,64,0,stream>>>(acc,out);
}

// Round 8
// 324.841 us; speedup vs baseline: 1.4531x; 1.0816x over previous
//
#include <hip/hip_runtime.h>
#include <hip/hip_bf16.h>
#include <math.h>

typedef __hip_bfloat16 bf16;
typedef float f32x4 __attribute__((ext_vector_type(4)));
typedef __bf16 bf16x8 __attribute__((ext_vector_type(8)));

#define DEV __device__ __forceinline__

DEV float to_f(float v){ return v; }
DEV float to_f(bf16 v){ return __bfloat162float(v); }
DEV bf16 f2b(float v){ return __float2bfloat16(v); }
DEV unsigned short b2u(bf16 v){ return __builtin_bit_cast(unsigned short, v); }

DEV float gelu_f(float x){
  float z = 1.5957691216057308f*(x + 0.044715f*x*x*x);
  float e = __expf(-z);
  return x * __builtin_amdgcn_rcpf(1.0f + e);
}

DEV bf16x8 load_frag(const bf16* p, bool ok){
  uint4 u = make_uint4(0u,0u,0u,0u);
  if (ok) u = *(const uint4*)p;
  return __builtin_bit_cast(bf16x8, u);
}

DEV f32x4 mfma16(bf16x8 a, uint4 b, f32x4 c){
  return __builtin_amdgcn_mfma_f32_16x16x32_bf16(a, __builtin_bit_cast(bf16x8, b), c, 0, 0, 0);
}

DEV int swz8(int blk, int n){
  return (blk & 7) * (n >> 3) + (blk >> 3);
}

// async global->LDS DMA, 16 B per lane; lds dest wave-uniform base.
DEV void dma16(const void* g, void* l){
  __builtin_amdgcn_global_load_lds(
      (const __attribute__((address_space(1))) unsigned int*)g,
      (__attribute__((address_space(3))) unsigned int*)l,
      16, 0, 0);
}

#define NSLOT 64

// ---------------- encoder Conv_trio (VALU form — trio1/CIN=1 only) -------------
template<typename TIN, int CIN, int COUT, int SUB, int STRIDE, int HI, int WI>
__global__ void trio_kernel(const TIN* __restrict__ in, const float* __restrict__ w,
                            const float* __restrict__ bias, bf16* __restrict__ out){
  constexpr int HO = HI/STRIDE, WO = WI/STRIDE;
  constexpr int CO_PER = COUT/SUB;
  int gtid = blockIdx.x*blockDim.x + threadIdx.x;
  int sub = gtid % SUB;
  int pix = gtid / SUB;
  int b = pix / (HO*WO); int rem = pix % (HO*WO);
  int y = rem / WO, x = rem % WO;

  float acc[CO_PER];
  #pragma unroll
  for (int j=0;j<CO_PER;j++) acc[j]=0.f;

  for (int ky=0;ky<3;ky++){
    int iy = (STRIDE==1) ? (y+ky-1) : (2*y+ky);
    if (iy<0 || iy>=HI) continue;
    for (int kx=0;kx<3;kx++){
      int ix = (STRIDE==1) ? (x+kx-1) : (2*x+kx);
      if (ix<0 || ix>=WI) continue;
      const TIN* ip = in + ((size_t)(b*HI+iy)*WI+ix)*CIN;
      const float* wp = w + ((ky*3+kx)*CIN)*COUT + sub*CO_PER;
      #pragma unroll 4
      for (int ci=0; ci<CIN; ci++){
        float a = to_f(ip[ci]);
        const float4* w4 = (const float4*)(wp + (size_t)ci*COUT);
        #pragma unroll
        for (int j=0;j<CO_PER/4;j++){
          float4 ww = w4[j];
          acc[4*j+0] += a*ww.x; acc[4*j+1] += a*ww.y;
          acc[4*j+2] += a*ww.z; acc[4*j+3] += a*ww.w;
        }
      }
    }
  }

  float s1=0.f, s2=0.f;
  #pragma unroll
  for (int j=0;j<CO_PER;j++){
    acc[j] += bias[sub*CO_PER+j];
    s1 += acc[j]; s2 += acc[j]*acc[j];
  }
  #pragma unroll
  for (int off=1; off<SUB; off<<=1){
    s1 += __shfl_xor(s1,off,64);
    s2 += __shfl_xor(s2,off,64);
  }
  float mu  = s1*(1.0f/COUT);
  float var = s2*(1.0f/COUT) - mu*mu;
  float sc  = rsqrtf(var + 1e-6f);

  bf16* op = out + (size_t)pix*COUT + sub*CO_PER;
  #pragma unroll
  for (int j=0;j<CO_PER;j++) op[j] = f2b(gelu_f((acc[j]-mu)*sc));
}

// ---------------- MFMA encoder trios (CIN>=16, stride 2) ----------------------
template<int CIN, int COUT, int HI, int WI>
__global__ void trio_mfma(const bf16* __restrict__ in, const bf16* __restrict__ bpack,
                          const float* __restrict__ bias, bf16* __restrict__ out){
  constexpr int HO = HI/2, WO = WI/2, NT = COUT/16;
  constexpr int TPR = WO/16;
  int lane = threadIdx.x & 63, wv = threadIdx.x >> 6;
  int wtile = blockIdx.x*4 + wv;
  int m = lane & 15, quad = lane >> 4;

  int x0 = (wtile % TPR)*16;
  int oy = (wtile / TPR) % HO;
  int b  = wtile / (TPR*HO);

  const uint4* bp4 = (const uint4*)bpack;

  f32x4 acc[NT];
  #pragma unroll
  for (int nt=0;nt<NT;nt++) acc[nt] = (f32x4){0.f,0.f,0.f,0.f};

  if constexpr (CIN == 32){
    #pragma unroll
    for (int tap=0; tap<9; tap++){
      int ky = tap/3, kx = tap%3;
      int iy = 2*oy + ky;
      int ix = 2*(x0 + m) + kx;
      bool ok = (iy < HI) && (ix < WI);
      bf16x8 a = load_frag(in + ((size_t)(b*HI+iy)*WI + ix)*32 + quad*8, ok);
      #pragma unroll
      for (int nt=0;nt<NT;nt++)
        acc[nt] = mfma16(a, bp4[(tap*NT+nt)*64 + lane], acc[nt]);
    }
  } else {  // CIN == 16, taps packed in pairs
    #pragma unroll
    for (int P=0; P<5; P++){
      int tap = 2*P + (quad >> 1);
      int ky = tap/3, kx = tap - ky*3;
      int iy = 2*oy + ky;
      int ix = 2*(x0 + m) + kx;
      bool ok = (tap < 9) && (iy < HI) && (ix < WI);
      bf16x8 a = load_frag(in + ((size_t)(b*HI+iy)*WI + ix)*16 + (quad&1)*8, ok);
      #pragma unroll
      for (int nt=0;nt<NT;nt++)
        acc[nt] = mfma16(a, bp4[(P*NT+nt)*64 + lane], acc[nt]);
    }
  }

  float av[NT][4];
  float s1[4] = {0.f,0.f,0.f,0.f}, s2[4] = {0.f,0.f,0.f,0.f};
  #pragma unroll
  for (int nt=0;nt<NT;nt++){
    float bv = bias[nt*16 + m];
    #pragma unroll
    for (int r=0;r<4;r++){
      float v = acc[nt][r] + bv;
      av[nt][r] = v;
      s1[r] += v; s2[r] += v*v;
    }
  }
  #pragma unroll
  for (int r=0;r<4;r++){
    #pragma unroll
    for (int off=1; off<16; off<<=1){
      s1[r] += __shfl_xor(s1[r], off, 64);
      s2[r] += __shfl_xor(s2[r], off, 64);
    }
  }
  #pragma unroll
  for (int r=0;r<4;r++){
    float mu  = s1[r]*(1.0f/COUT);
    float var = s2[r]*(1.0f/COUT) - mu*mu;
    float sc  = rsqrtf(var + 1e-6f);
    size_t px = ((size_t)(b*HO + oy))*WO + x0 + quad*4 + r;
    #pragma unroll
    for (int nt=0;nt<NT;nt++)
      out[px*COUT + nt*16 + m] = f2b(gelu_f((av[nt][r]-mu)*sc));
  }
}

// ---------------- merged weight repack (all 5 packs, one launch) ---------------
// segments: [0,36864) up | [36864,46080) mask | [46080,48640) c16<16> |
//           [48640,53760) c16<32> | [53760,72192) c32
__global__ void repack_all(const float* __restrict__ upw, const float* __restrict__ mw,
                           const float* __restrict__ w2, const float* __restrict__ w3,
                           const float* __restrict__ w4,
                           bf16* __restrict__ bpU, bf16* __restrict__ bpM,
                           bf16* __restrict__ bpT2, bf16* __restrict__ bpT3,
                           bf16* __restrict__ bpT4){
  int v = blockIdx.x*256 + threadIdx.x;
  if (v < 36864){
    int u = v;
    int j = u & 7; int lane = (u>>3)&63; int nt = (u>>9)&3; int c = (u>>11)&1; int tap = u>>12;
    int ci = c*32 + (lane>>4)*8 + j;
    int co = (lane&15)*4 + nt;
    bpU[u] = f2b(upw[(tap*64+ci)*64 + co]);
  } else if (v < 46080){
    int u = v - 36864;
    int j = u & 7; int lane = (u>>3)&63; int c = (u>>9)&1; int tap = u>>10;
    int ci = c*32 + (lane>>4)*8 + j;
    int n = lane & 15;
    bpM[u] = (n < 4) ? f2b(mw[(tap*64+ci)*4 + n]) : f2b(0.0f);
  } else if (v < 48640){
    int u = v - 46080;                 // c16<16>, NT=1
    int j = u & 7; int lane = (u>>3)&63; int P = u>>9;
    int m = lane & 15, quad = lane >> 4;
    int ci = (quad & 1)*8 + j;
    int tap = 2*P + (quad >> 1);
    bpT2[u] = (tap < 9) ? f2b(w2[((size_t)tap*16 + ci)*16 + m]) : f2b(0.0f);
  } else if (v < 53760){
    int u = v - 48640;                 // c16<32>, NT=2
    int j = u & 7; int lane = (u>>3)&63; int idx = u>>9;
    int nt = idx % 2; int P = idx / 2;
    int m = lane & 15, quad = lane >> 4;
    int ci = (quad & 1)*8 + j;
    int tap = 2*P + (quad >> 1);
    int co = nt*16 + m;
    bpT3[u] = (tap < 9) ? f2b(w3[((size_t)tap*16 + ci)*32 + co]) : f2b(0.0f);
  } else if (v < 72192){
    int u = v - 53760;                 // c32
    int j = u & 7; int lane = (u>>3)&63; int idx = u>>9;
    int nt = idx & 3; int tap = idx >> 2;
    int m = lane & 15, quad = lane >> 4;
    int ci = quad*8 + j;
    int co = nt*16 + m;
    bpT4[u] = f2b(w4[((size_t)tap*32 + ci)*64 + co]);
  }
}

// ------------- conv_transpose, stride-2 along y (DIM=0) — register form -------
template<int HI, int WI>
__global__ void upconv_dim0(const bf16* __restrict__ in, const bf16* __restrict__ bpack,
                            const float* __restrict__ upb, bf16* __restrict__ out){
  constexpr int HO = 2*HI, WO = WI, XT = WI/32;
  int lane = threadIdx.x & 63, wv = threadIdx.x >> 6;
  int wtile = swz8(blockIdx.x, gridDim.x)*4 + wv;
  int m = lane & 15, quad = lane >> 4;

  int x0 = (wtile % XT)*32;
  int o  = (wtile / XT) % HO;
  int b  = wtile / (XT*HO);

  int q = o >> 1;
  int stk[2], stq[2]; int nst;
  if (o & 1){ stk[0]=1; stq[0]=q; nst=1; }
  else {
    nst = 0;
    if (q >= 1){ stk[0]=0; stq[0]=q-1; nst=1; }
    stk[nst]=2; stq[nst]=q; nst++;
  }

  f32x4 acc[2][4];
  #pragma unroll
  for (int t=0;t<2;t++)
    #pragma unroll
    for (int nt=0;nt<4;nt++) acc[t][nt] = (f32x4){0.f,0.f,0.f,0.f};

  const uint4* bp4 = (const uint4*)bpack;

  #pragma unroll 1
  for (int s=0; s<nst; s++){
    int kyt = stk[s];
    const bf16* rowp = in + ((size_t)(b*HI+stq[s])*WI)*64 + quad*8;
    #pragma unroll
    for (int ut=0; ut<3; ut++){
      #pragma unroll
      for (int c=0;c<2;c++){
        int ix0 = x0 + m - 1 + ut;
        int ix1 = ix0 + 16;
        bf16x8 a0 = load_frag(rowp + (size_t)ix0*64 + c*32, ix0>=0 && ix0<WI);
        bf16x8 a1 = load_frag(rowp + (size_t)ix1*64 + c*32, ix1>=0 && ix1<WI);
        #pragma unroll
        for (int nt=0;nt<4;nt++){
          uint4 Bq = bp4[(((kyt*3+ut)*2+c)*4+nt)*64 + lane];
          acc[0][nt] = mfma16(a0, Bq, acc[0][nt]);
          acc[1][nt] = mfma16(a1, Bq, acc[1][nt]);
        }
      }
    }
  }

  float4 bv = *(const float4*)(upb + m*4);
  size_t rowbase = ((size_t)b*HO + o)*WO;
  #pragma unroll
  for (int t=0;t<2;t++){
    #pragma unroll
    for (int r=0;r<4;r++){
      int p = x0 + t*16 + quad*4 + r;
      float g0 = gelu_f(acc[t][0][r] + bv.x);
      float g1 = gelu_f(acc[t][1][r] + bv.y);
      float g2 = gelu_f(acc[t][2][r] + bv.z);
      float g3 = gelu_f(acc[t][3][r] + bv.w);
      unsigned int lo = (unsigned int)b2u(f2b(g0)) | ((unsigned int)b2u(f2b(g1))<<16);
      unsigned int hi = (unsigned int)b2u(f2b(g2)) | ((unsigned int)b2u(f2b(g3))<<16);
      *(uint2*)(out + (rowbase + p)*64 + m*4) = make_uint2(lo,hi);
    }
  }
}

// ------------- conv_transpose dim0 + B-pack in LDS, 256-thr (steps 2) ----------
template<int HI, int WI>
__global__ void __launch_bounds__(256,2)
upconv_dim0_bs(const bf16* __restrict__ in, const bf16* __restrict__ bpack,
               const float* __restrict__ upb, bf16* __restrict__ out){
  constexpr int HO = 2*HI, WO = WI, XT = WI/32;
  __shared__ __align__(16) uint4 Bsh[4608];          // 72 KB
  int tid = threadIdx.x, lane = tid & 63, wv = tid >> 6;
  int wtile = swz8(blockIdx.x, gridDim.x)*4 + wv;
  int m = lane & 15, quad = lane >> 4;

  int x0 = (wtile % XT)*32;
  int o  = (wtile / XT) % HO;
  int b  = wtile / (XT*HO);

  {
    const uint4* gp = (const uint4*)bpack;
    #pragma unroll
    for (int k=0;k<18;k++){
      int base = (wv*18 + k)*64;
      dma16(gp + base + lane, Bsh + base);
    }
  }

  int q = o >> 1;
  int stk[2], stq[2]; int nst;
  if (o & 1){ stk[0]=1; stq[0]=q; nst=1; }
  else {
    nst = 0;
    if (q >= 1){ stk[0]=0; stq[0]=q-1; nst=1; }
    stk[nst]=2; stq[nst]=q; nst++;
  }

  f32x4 acc[2][4];
  #pragma unroll
  for (int t=0;t<2;t++)
    #pragma unroll
    for (int nt=0;nt<4;nt++) acc[t][nt] = (f32x4){0.f,0.f,0.f,0.f};

  asm volatile("s_waitcnt vmcnt(0)" ::: "memory");
  __syncthreads();

  #pragma unroll 1
  for (int s=0; s<nst; s++){
    int kyt = stk[s];
    const bf16* rowp = in + ((size_t)(b*HI+stq[s])*WI)*64 + quad*8;
    #pragma unroll
    for (int ut=0; ut<3; ut++){
      #pragma unroll
      for (int c=0;c<2;c++){
        int ix0 = x0 + m - 1 + ut;
        int ix1 = ix0 + 16;
        bf16x8 a0 = load_frag(rowp + (size_t)ix0*64 + c*32, ix0>=0 && ix0<WI);
        bf16x8 a1 = load_frag(rowp + (size_t)ix1*64 + c*32, ix1>=0 && ix1<WI);
        #pragma unroll
        for (int nt=0;nt<4;nt++){
          uint4 Bq = Bsh[(((kyt*3+ut)*2+c)*4+nt)*64 + lane];
          acc[0][nt] = mfma16(a0, Bq, acc[0][nt]);
          acc[1][nt] = mfma16(a1, Bq, acc[1][nt]);
        }
      }
    }
  }

  float4 bv = *(const float4*)(upb + m*4);
  size_t rowbase = ((size_t)b*HO + o)*WO;
  #pragma unroll
  for (int t=0;t<2;t++){
    #pragma unroll
    for (int r=0;r<4;r++){
      int p = x0 + t*16 + quad*4 + r;
      float g0 = gelu_f(acc[t][0][r] + bv.x);
      float g1 = gelu_f(acc[t][1][r] + bv.y);
      float g2 = gelu_f(acc[t][2][r] + bv.z);
      float g3 = gelu_f(acc[t][3][r] + bv.w);
      unsigned int lo = (unsigned int)b2u(f2b(g0)) | ((unsigned int)b2u(f2b(g1))<<16);
      unsigned int hi = (unsigned int)b2u(f2b(g2)) | ((unsigned int)b2u(f2b(g3))<<16);
      *(uint2*)(out + (rowbase + p)*64 + m*4) = make_uint2(lo,hi);
    }
  }
}

// ------------- conv_transpose dim0 + B-pack in LDS, 512-thr (step 4) -----------
// 8 waves share one 72 KB B-pack stage: B-DMA bytes per output px HALVE and
// waves/CU double (8 -> 16 at the same 2-blocks/CU LDS limit).
template<int HI, int WI>
__global__ void __launch_bounds__(512,4)
upconv_dim0_bs8(const bf16* __restrict__ in, const bf16* __restrict__ bpack,
                const float* __restrict__ upb, bf16* __restrict__ out){
  constexpr int HO = 2*HI, WO = WI, XT = WI/32;
  __shared__ __align__(16) uint4 Bsh[4608];          // 72 KB
  int tid = threadIdx.x, lane = tid & 63, wv = tid >> 6;
  int wtile = swz8(blockIdx.x, gridDim.x)*8 + wv;
  int m = lane & 15, quad = lane >> 4;

  int x0 = (wtile % XT)*32;
  int o  = (wtile / XT) % HO;
  int b  = wtile / (XT*HO);

  {
    const uint4* gp = (const uint4*)bpack;
    #pragma unroll
    for (int k=0;k<9;k++){
      int base = (wv*9 + k)*64;
      dma16(gp + base + lane, Bsh + base);
    }
  }

  int q = o >> 1;
  int stk[2], stq[2]; int nst;
  if (o & 1){ stk[0]=1; stq[0]=q; nst=1; }
  else {
    nst = 0;
    if (q >= 1){ stk[0]=0; stq[0]=q-1; nst=1; }
    stk[nst]=2; stq[nst]=q; nst++;
  }

  f32x4 acc[2][4];
  #pragma unroll
  for (int t=0;t<2;t++)
    #pragma unroll
    for (int nt=0;nt<4;nt++) acc[t][nt] = (f32x4){0.f,0.f,0.f,0.f};

  asm volatile("s_waitcnt vmcnt(0)" ::: "memory");
  __syncthreads();

  #pragma unroll 1
  for (int s=0; s<nst; s++){
    int kyt = stk[s];
    const bf16* rowp = in + ((size_t)(b*HI+stq[s])*WI)*64 + quad*8;
    #pragma unroll
    for (int ut=0; ut<3; ut++){
      #pragma unroll
      for (int c=0;c<2;c++){
        int ix0 = x0 + m - 1 + ut;
        int ix1 = ix0 + 16;
        bf16x8 a0 = load_frag(rowp + (size_t)ix0*64 + c*32, ix0>=0 && ix0<WI);
        bf16x8 a1 = load_frag(rowp + (size_t)ix1*64 + c*32, ix1>=0 && ix1<WI);
        #pragma unroll
        for (int nt=0;nt<4;nt++){
          uint4 Bq = Bsh[(((kyt*3+ut)*2+c)*4+nt)*64 + lane];
          acc[0][nt] = mfma16(a0, Bq, acc[0][nt]);
          acc[1][nt] = mfma16(a1, Bq, acc[1][nt]);
        }
      }
    }
  }

  float4 bv = *(const float4*)(upb + m*4);
  size_t rowbase = ((size_t)b*HO + o)*WO;
  #pragma unroll
  for (int t=0;t<2;t++){
    #pragma unroll
    for (int r=0;r<4;r++){
      int p = x0 + t*16 + quad*4 + r;
      float g0 = gelu_f(acc[t][0][r] + bv.x);
      float g1 = gelu_f(acc[t][1][r] + bv.y);
      float g2 = gelu_f(acc[t][2][r] + bv.z);
      float g3 = gelu_f(acc[t][3][r] + bv.w);
      unsigned int lo = (unsigned int)b2u(f2b(g0)) | ((unsigned int)b2u(f2b(g1))<<16);
      unsigned int hi = (unsigned int)b2u(f2b(g2)) | ((unsigned int)b2u(f2b(g3))<<16);
      *(uint2*)(out + (rowbase + p)*64 + m*4) = make_uint2(lo,hi);
    }
  }
}

// ------------- conv_transpose dim1, register form — small grids (step 1) ------
template<int HI, int WI>
__global__ void upconv_dim1(const bf16* __restrict__ in, const bf16* __restrict__ bpack,
                            const float* __restrict__ upb, bf16* __restrict__ out){
  constexpr int HO = HI, WO = 2*WI, QT = WI/16;
  int lane = threadIdx.x & 63, wv = threadIdx.x >> 6;
  int wtile = swz8(blockIdx.x, gridDim.x)*4 + wv;
  int m = lane & 15, quad = lane >> 4;

  int q0 = (wtile % QT)*16;
  int y  = (wtile / QT) % HI;
  int b  = wtile / (QT*HI);

  f32x4 ae[4], ao[4];
  #pragma unroll
  for (int nt=0;nt<4;nt++){ ae[nt]=(f32x4){0.f,0.f,0.f,0.f}; ao[nt]=(f32x4){0.f,0.f,0.f,0.f}; }

  const uint4* bp4 = (const uint4*)bpack;

  #pragma unroll 1
  for (int ky=0; ky<3; ky++){
    int iy = y + ky - 1;
    if (iy < 0 || iy >= HI) continue;
    const bf16* rowp = in + ((size_t)(b*HI+iy)*WI)*64 + quad*8;
    #pragma unroll
    for (int c=0;c<2;c++){
      int qa = q0 + m;
      bf16x8 Au = load_frag(rowp + (size_t)qa*64 + c*32, true);
      bf16x8 As = load_frag(rowp + (size_t)(qa-1)*64 + c*32, qa >= 1);
      #pragma unroll
      for (int nt=0;nt<4;nt++){
        uint4 B0 = bp4[(((ky*3+0)*2+c)*4+nt)*64 + lane];
        uint4 B1 = bp4[(((ky*3+1)*2+c)*4+nt)*64 + lane];
        uint4 B2 = bp4[(((ky*3+2)*2+c)*4+nt)*64 + lane];
        ae[nt] = mfma16(As, B0, ae[nt]);
        ae[nt] = mfma16(Au, B2, ae[nt]);
        ao[nt] = mfma16(Au, B1, ao[nt]);
      }
    }
  }

  float4 bv = *(const float4*)(upb + m*4);
  size_t rowbase = ((size_t)b*HO + y)*WO;
  #pragma unroll
  for (int r=0;r<4;r++){
    int qq = q0 + quad*4 + r;
    {
      float g0 = gelu_f(ae[0][r] + bv.x);
      float g1 = gelu_f(ae[1][r] + bv.y);
      float g2 = gelu_f(ae[2][r] + bv.z);
      float g3 = gelu_f(ae[3][r] + bv.w);
      unsigned int lo = (unsigned int)b2u(f2b(g0)) | ((unsigned int)b2u(f2b(g1))<<16);
      unsigned int hi = (unsigned int)b2u(f2b(g2)) | ((unsigned int)b2u(f2b(g3))<<16);
      *(uint2*)(out + (rowbase + 2*qq)*64 + m*4) = make_uint2(lo,hi);
    }
    {
      float g0 = gelu_f(ao[0][r] + bv.x);
      float g1 = gelu_f(ao[1][r] + bv.y);
      float g2 = gelu_f(ao[2][r] + bv.z);
      float g3 = gelu_f(ao[3][r] + bv.w);
      unsigned int lo = (unsigned int)b2u(f2b(g0)) | ((unsigned int)b2u(f2b(g1))<<16);
      unsigned int hi = (unsigned int)b2u(f2b(g2)) | ((unsigned int)b2u(f2b(g3))<<16);
      *(uint2*)(out + (rowbase + 2*qq+1)*64 + m*4) = make_uint2(lo,hi);
    }
  }
}

// ------------- conv_transpose dim1, 2-row + B-pack in LDS, 256-thr (step 3) ----
template<int HI, int WI>
__global__ void __launch_bounds__(256,2)
upconv_dim1_bs(const bf16* __restrict__ in, const bf16* __restrict__ bpack,
               const float* __restrict__ upb, bf16* __restrict__ out){
  constexpr int HO = HI, WO = 2*WI, QT = WI/16;
  __shared__ __align__(16) uint4 Bsh[4608];          // 72 KB: full dim1 B-pack
  int tid = threadIdx.x, lane = tid & 63, wv = tid >> 6;
  int wtile = swz8(blockIdx.x, gridDim.x)*4 + wv;
  int m = lane & 15, quad = lane >> 4;

  int q0 = (wtile % QT)*16;
  int y  = ((wtile / QT) % (HI/2)) * 2;
  int b  = wtile / (QT*(HI/2));

  {
    const uint4* gp = (const uint4*)bpack;
    #pragma unroll
    for (int k=0;k<18;k++){
      int base = (wv*18 + k)*64;
      dma16(gp + base + lane, Bsh + base);
    }
  }

  int qa = q0 + m;

  bf16x8 Afr[4][2][2];              // [row4][c][{Au,As}]
  #pragma unroll
  for (int i4=0;i4<4;i4++){
    int iy = y + i4 - 1;
    bool ok = (iy>=0) && (iy<HI);
    const bf16* rowp = in + ((size_t)(b*HI+iy)*WI)*64 + quad*8;
    #pragma unroll
    for (int c=0;c<2;c++){
      Afr[i4][c][0] = load_frag(rowp + (size_t)qa*64 + c*32, ok);
      Afr[i4][c][1] = load_frag(rowp + (size_t)(qa-1)*64 + c*32, ok && qa >= 1);
    }
  }

  asm volatile("s_waitcnt vmcnt(0)" ::: "memory");
  __syncthreads();

  f32x4 ae[2][4], ao[2][4];
  #pragma unroll
  for (int r=0;r<2;r++)
    #pragma unroll
    for (int nt=0;nt<4;nt++){ ae[r][nt]=(f32x4){0.f,0.f,0.f,0.f}; ao[r][nt]=(f32x4){0.f,0.f,0.f,0.f}; }

  #pragma unroll
  for (int ky=0; ky<3; ky++){
    #pragma unroll
    for (int c=0;c<2;c++){
      #pragma unroll
      for (int nt=0;nt<4;nt++){
        uint4 B0 = Bsh[(((ky*3+0)*2+c)*4+nt)*64 + lane];
        uint4 B1 = Bsh[(((ky*3+1)*2+c)*4+nt)*64 + lane];
        uint4 B2 = Bsh[(((ky*3+2)*2+c)*4+nt)*64 + lane];
        #pragma unroll
        for (int r=0;r<2;r++){
          ae[r][nt] = mfma16(Afr[ky+r][c][1], B0, ae[r][nt]);
          ae[r][nt] = mfma16(Afr[ky+r][c][0], B2, ae[r][nt]);
          ao[r][nt] = mfma16(Afr[ky+r][c][0], B1, ao[r][nt]);
        }
      }
    }
  }

  float4 bv = *(const float4*)(upb + m*4);
  #pragma unroll
  for (int r2=0;r2<2;r2++){
    size_t rowbase = ((size_t)b*HO + y + r2)*WO;
    #pragma unroll
    for (int r=0;r<4;r++){
      int qq = q0 + quad*4 + r;
      {
        float g0 = gelu_f(ae[r2][0][r] + bv.x);
        float g1 = gelu_f(ae[r2][1][r] + bv.y);
        float g2 = gelu_f(ae[r2][2][r] + bv.z);
        float g3 = gelu_f(ae[r2][3][r] + bv.w);
        unsigned int lo = (unsigned int)b2u(f2b(g0)) | ((unsigned int)b2u(f2b(g1))<<16);
        unsigned int hi = (unsigned int)b2u(f2b(g2)) | ((unsigned int)b2u(f2b(g3))<<16);
        *(uint2*)(out + (rowbase + 2*qq)*64 + m*4) = make_uint2(lo,hi);
      }
      {
        float g0 = gelu_f(ao[r2][0][r] + bv.x);
        float g1 = gelu_f(ao[r2][1][r] + bv.y);
        float g2 = gelu_f(ao[r2][2][r] + bv.z);
        float g3 = gelu_f(ao[r2][3][r] + bv.w);
        unsigned int lo = (unsigned int)b2u(f2b(g0)) | ((unsigned int)b2u(f2b(g1))<<16);
        unsigned int hi = (unsigned int)b2u(f2b(g2)) | ((unsigned int)b2u(f2b(g3))<<16);
        *(uint2*)(out + (rowbase + 2*qq+1)*64 + m*4) = make_uint2(lo,hi);
      }
    }
  }
}

// ------------- conv_transpose dim1, 2-row + B-pack in LDS, 512-thr (step 5) ----
template<int HI, int WI>
__global__ void __launch_bounds__(512,4)
upconv_dim1_bs8(const bf16* __restrict__ in, const bf16* __restrict__ bpack,
                const float* __restrict__ upb, bf16* __restrict__ out){
  constexpr int HO = HI, WO = 2*WI, QT = WI/16;
  __shared__ __align__(16) uint4 Bsh[4608];          // 72 KB
  int tid = threadIdx.x, lane = tid & 63, wv = tid >> 6;
  int wtile = swz8(blockIdx.x, gridDim.x)*8 + wv;
  int m = lane & 15, quad = lane >> 4;

  int q0 = (wtile % QT)*16;
  int y  = ((wtile / QT) % (HI/2)) * 2;
  int b  = wtile / (QT*(HI/2));

  {
    const uint4* gp = (const uint4*)bpack;
    #pragma unroll
    for (int k=0;k<9;k++){
      int base = (wv*9 + k)*64;
      dma16(gp + base + lane, Bsh + base);
    }
  }

  int qa = q0 + m;

  bf16x8 Afr[4][2][2];              // [row4][c][{Au,As}]
  #pragma unroll
  for (int i4=0;i4<4;i4++){
    int iy = y + i4 - 1;
    bool ok = (iy>=0) && (iy<HI);
    const bf16* rowp = in + ((size_t)(b*HI+iy)*WI)*64 + quad*8;
    #pragma unroll
    for (int c=0;c<2;c++){
      Afr[i4][c][0] = load_frag(rowp + (size_t)qa*64 + c*32, ok);
      Afr[i4][c][1] = load_frag(rowp + (size_t)(qa-1)*64 + c*32, ok && qa >= 1);
    }
  }

  asm volatile("s_waitcnt vmcnt(0)" ::: "memory");
  __syncthreads();

  f32x4 ae[2][4], ao[2][4];
  #pragma unroll
  for (int r=0;r<2;r++)
    #pragma unroll
    for (int nt=0;nt<4;nt++){ ae[r][nt]=(f32x4){0.f,0.f,0.f,0.f}; ao[r][nt]=(f32x4){0.f,0.f,0.f,0.f}; }

  #pragma unroll
  for (int ky=0; ky<3; ky++){
    #pragma unroll
    for (int c=0;c<2;c++){
      #pragma unroll
      for (int nt=0;nt<4;nt++){
        uint4 B0 = Bsh[(((ky*3+0)*2+c)*4+nt)*64 + lane];
        uint4 B1 = Bsh[(((ky*3+1)*2+c)*4+nt)*64 + lane];
        uint4 B2 = Bsh[(((ky*3+2)*2+c)*4+nt)*64 + lane];
        #pragma unroll
        for (int r=0;r<2;r++){
          ae[r][nt] = mfma16(Afr[ky+r][c][1], B0, ae[r][nt]);
          ae[r][nt] = mfma16(Afr[ky+r][c][0], B2, ae[r][nt]);
          ao[r][nt] = mfma16(Afr[ky+r][c][0], B1, ao[r][nt]);
        }
      }
    }
  }

  float4 bv = *(const float4*)(upb + m*4);
  #pragma unroll
  for (int r2=0;r2<2;r2++){
    size_t rowbase = ((size_t)b*HO + y + r2)*WO;
    #pragma unroll
    for (int r=0;r<4;r++){
      int qq = q0 + quad*4 + r;
      {
        float g0 = gelu_f(ae[r2][0][r] + bv.x);
        float g1 = gelu_f(ae[r2][1][r] + bv.y);
        float g2 = gelu_f(ae[r2][2][r] + bv.z);
        float g3 = gelu_f(ae[r2][3][r] + bv.w);
        unsigned int lo = (unsigned int)b2u(f2b(g0)) | ((unsigned int)b2u(f2b(g1))<<16);
        unsigned int hi = (unsigned int)b2u(f2b(g2)) | ((unsigned int)b2u(f2b(g3))<<16);
        *(uint2*)(out + (rowbase + 2*qq)*64 + m*4) = make_uint2(lo,hi);
      }
      {
        float g0 = gelu_f(ao[r2][0][r] + bv.x);
        float g1 = gelu_f(ao[r2][1][r] + bv.y);
        float g2 = gelu_f(ao[r2][2][r] + bv.z);
        float g3 = gelu_f(ao[r2][3][r] + bv.w);
        unsigned int lo = (unsigned int)b2u(f2b(g0)) | ((unsigned int)b2u(f2b(g1))<<16);
        unsigned int hi = (unsigned int)b2u(f2b(g2)) | ((unsigned int)b2u(f2b(g3))<<16);
        *(uint2*)(out + (rowbase + 2*qq+1)*64 + m*4) = make_uint2(lo,hi);
      }
    }
  }
}

// ---------------- maskloss, register form — step 0 only ------------------------
template<int STEP, int DIM, int HH, int WW, int TILES>
__global__ void maskloss_mfma(const bf16* __restrict__ feat, const bf16* __restrict__ mpack,
                              const float* __restrict__ mb, const float* __restrict__ img,
                              const float* __restrict__ masks_in, float* __restrict__ masks_out,
                              float* __restrict__ accbuf){
  __shared__ float llog[4][64][4];
  __shared__ float red[4][2];
  int lane = threadIdx.x & 63;
  int wv   = threadIdx.x >> 6;
  int wtile = swz8(blockIdx.x, gridDim.x)*4 + wv;
  int m = lane & 15, quad = lane >> 4;

  constexpr int TPR = WW/(16*TILES);
  int x0 = (wtile % TPR)*(16*TILES);
  int y  = (wtile / TPR) % HH;
  int b  = wtile / (TPR*HH);

  const uint4* bp4 = (const uint4*)mpack;

  #pragma unroll 1
  for (int t=0; t<TILES; t++){
    f32x4 acc4 = (f32x4){0.f,0.f,0.f,0.f};
    #pragma unroll
    for (int c=0;c<2;c++){
      bf16x8 afr[9];
      #pragma unroll
      for (int ky=0; ky<3; ky++){
        int iy = y + ky - 1;
        bool rowok = (iy >= 0) && (iy < HH);
        const bf16* rowp = feat + ((size_t)(b*HH+iy)*WW)*64 + quad*8 + c*32;
        #pragma unroll
        for (int kx=0; kx<3; kx++){
          int ix = x0 + t*16 + m + kx - 1;
          bool ok = rowok && (ix >= 0) && (ix < WW);
          afr[ky*3+kx] = load_frag(rowp + (size_t)ix*64, ok);
        }
      }
      #pragma unroll
      for (int tap=0; tap<9; tap++){
        uint4 bb = bp4[(tap*2+c)*64 + lane];
        acc4 = mfma16(afr[tap], bb, acc4);
      }
    }
    if (m < 4){
      #pragma unroll
      for (int r=0;r<4;r++) llog[wv][t*16 + quad*4 + r][m] = acc4[r] + mb[m];
    }
  }
  __syncthreads();

  float ent = 0.f, mse = 0.f;
  if (lane < 16*TILES){
    int p = lane; int xx = x0 + p;
    float l0 = llog[wv][p][0], l1 = llog[wv][p][1];
    float l2 = llog[wv][p][2], l3 = llog[wv][p][3];
    float mx = fmaxf(fmaxf(l0,l1), fmaxf(l2,l3));
    float d0=l0-mx, d1=l1-mx, d2=l2-mx, d3=l3-mx;
    float e0=__expf(d0), e1=__expf(d1), e2=__expf(d2), e3=__expf(d3);
    float S = e0+e1+e2+e3;
    float inv = __builtin_amdgcn_rcpf(S);
    float sval = (e1 + 2.f*e2 + 3.f*e3)*inv;

    constexpr int HM = (DIM==0)? HH/2 : HH;
    constexpr int WM = (DIM==0)? WW : WW/2;
    int my = (DIM==0)? (y>>1) : y;
    int mxi = (DIM==1)? (xx>>1) : xx;
    float mv = masks_in[((size_t)b*HM + my)*WM + mxi];
    masks_out[((size_t)b*HH + y)*WW + xx] = mv + 0.25f*sval;

    ent = __logf(S) - (e0*d0 + e1*d1 + e2*d2 + e3*d3)*inv;

    constexpr int FH = 256/HH, FW = 256/WW;
    float isum = 0.f;
    const float* ib = img + ((size_t)b*256 + y*FH)*256 + xx*FW;
    #pragma unroll
    for (int dy=0; dy<FH; dy++)
      #pragma unroll
      for (int dx=0; dx<FW; dx++) isum += ib[dy*256+dx];
    float img_ds = isum * (1.0f/(FH*FW));
    float d = sval*(1.0f/3.0f) - img_ds;
    mse = d*d;
  }

  #pragma unroll
  for (int off=1; off<64; off<<=1){
    ent += __shfl_xor(ent, off, 64);
    mse += __shfl_xor(mse, off, 64);
  }
  if (lane == 0){ red[wv][0] = ent; red[wv][1] = mse; }
  __syncthreads();
  if (threadIdx.x == 0){
    float e  = red[0][0] + red[1][0] + red[2][0] + red[3][0];
    float ms = red[0][1] + red[1][1] + red[2][1] + red[3][1];
    int slot = blockIdx.x & (NSLOT-1);
    atomicAdd(accbuf + (2*STEP  )*NSLOT + slot, e);
    atomicAdd(accbuf + (2*STEP+1)*NSLOT + slot, ms);
  }
}

// ---------------- maskloss via async LDS staging, 256-thr (steps 1-3) ----------
template<int STEP, int DIM, int HH, int WW, int ROWS>
__global__ void maskloss_lds(const bf16* __restrict__ feat, const bf16* __restrict__ mpack,
                             const float* __restrict__ mb, const float* __restrict__ img,
                             const float* __restrict__ masks_in, float* __restrict__ masks_out,
                             float* __restrict__ accbuf){
  constexpr int NBrow = WW/64;
  constexpr int PITCH = 9216;                // 72 px * 128 B
  constexpr int NR = ROWS + 2;
  constexpr int WPR = 4/ROWS;                // waves per row
  __shared__ __align__(16) char smem[NR*PITCH];
  __shared__ float llog[4][ROWS][16][4];
  __shared__ float red[4][2];
  int tid = threadIdx.x;
  int lane = tid & 63, wv = tid >> 6;
  int bi = swz8(blockIdx.x, gridDim.x);
  int x0 = (bi % NBrow)*64;
  int y0 = ((bi / NBrow) % (HH/ROWS)) * ROWS;
  int b  = bi / (NBrow*(HH/ROWS));
  int m = lane & 15, quad = lane >> 4;
  int lanesw = ((lane ^ (lane>>3)) << 4);    // pre-swizzled lane*16

  int r_w   = wv / WPR;
  int xbase = (wv % WPR) * (16*ROWS);
  int yw    = y0 + r_w;

  for (int k = wv; k < NR*9; k += 4){
    int r = k/9, coff = (k%9)*1024;
    int iy = y0 + r - 1;
    if (iy < 0 || iy >= HH) continue;
    const char* g = (const char*)(feat + ((size_t)(b*HH+iy)*WW + x0 - 1)*64)
                    + coff + lanesw;
    dma16(g, smem + r*PITCH + coff);
  }
  asm volatile("s_waitcnt vmcnt(0)" ::: "memory");
  __syncthreads();
  if (x0 == 0 && tid < 32*NR)
    ((float*)(smem + (tid>>5)*PITCH))[tid & 31] = 0.f;
  if (x0 + 64 == WW && tid >= 128 && tid < 128 + 32*NR){
    int t = tid - 128;
    ((float*)(smem + (t>>5)*PITCH + 65*128))[t & 31] = 0.f;
  }
  __syncthreads();

  const uint4* bp4 = (const uint4*)mpack;
  #pragma unroll
  for (int t=0; t<ROWS; t++){
    f32x4 accA = (f32x4){0.f,0.f,0.f,0.f};
    f32x4 accB = (f32x4){0.f,0.f,0.f,0.f};
    #pragma unroll
    for (int ky=0; ky<3; ky++){
      int iyw = yw + ky - 1;
      if (iyw < 0 || iyw >= HH) continue;
      const char* rowl = smem + (size_t)(r_w + ky)*PITCH;
      #pragma unroll
      for (int kx=0; kx<3; kx++){
        int lp = xbase + t*16 + m + kx;
        const char* pl = rowl + (size_t)lp*128;
        int xw = (lp & 7) << 4;
        bf16x8 a0 = __builtin_bit_cast(bf16x8, *(const uint4*)(pl + ((quad*16     ) ^ xw)));
        bf16x8 a1 = __builtin_bit_cast(bf16x8, *(const uint4*)(pl + ((quad*16 + 64) ^ xw)));
        uint4 b0 = bp4[((ky*3+kx)*2+0)*64 + lane];
        uint4 b1 = bp4[((ky*3+kx)*2+1)*64 + lane];
        accA = mfma16(a0, b0, accA);
        accB = mfma16(a1, b1, accB);
      }
    }
    if (m < 4){
      #pragma unroll
      for (int r=0;r<4;r++) llog[wv][t][quad*4+r][m] = accA[r] + accB[r] + mb[m];
    }
  }
  __syncthreads();

  float ent = 0.f, mse = 0.f;
  if (lane < 16*ROWS){
    int t = lane >> 4;
    int p = lane & 15;
    int xx = x0 + xbase + t*16 + p;
    float l0 = llog[wv][t][p][0], l1 = llog[wv][t][p][1];
    float l2 = llog[wv][t][p][2], l3 = llog[wv][t][p][3];
    float mx = fmaxf(fmaxf(l0,l1), fmaxf(l2,l3));
    float d0=l0-mx, d1=l1-mx, d2=l2-mx, d3=l3-mx;
    float e0=__expf(d0), e1=__expf(d1), e2=__expf(d2), e3=__expf(d3);
    float S = e0+e1+e2+e3;
    float inv = __builtin_amdgcn_rcpf(S);
    float sval = (e1 + 2.f*e2 + 3.f*e3)*inv;

    constexpr int HM = (DIM==0)? HH/2 : HH;
    constexpr int WM = (DIM==0)? WW : WW/2;
    int my = (DIM==0)? (yw>>1) : yw;
    int mxi = (DIM==1)? (xx>>1) : xx;
    float mv = masks_in[((size_t)b*HM + my)*WM + mxi];
    masks_out[((size_t)b*HH + yw)*WW + xx] = mv + 0.25f*sval;

    ent = __logf(S) - (e0*d0 + e1*d1 + e2*d2 + e3*d3)*inv;

    constexpr int FH = 256/HH, FW = 256/WW;
    float isum = 0.f;
    const float* ib = img + ((size_t)b*256 + yw*FH)*256 + xx*FW;
    #pragma unroll
    for (int dy=0; dy<FH; dy++)
      #pragma unroll
      for (int dx=0; dx<FW; dx++) isum += ib[dy*256+dx];
    float img_ds = isum * (1.0f/(FH*FW));
    float d = sval*(1.0f/3.0f) - img_ds;
    mse = d*d;
  }

  #pragma unroll
  for (int off=1; off<64; off<<=1){
    ent += __shfl_xor(ent, off, 64);
    mse += __shfl_xor(mse, off, 64);
  }
  if (lane == 0){ red[wv][0] = ent; red[wv][1] = mse; }
  __syncthreads();
  if (threadIdx.x == 0){
    float e  = red[0][0] + red[1][0] + red[2][0] + red[3][0];
    float ms = red[0][1] + red[1][1] + red[2][1] + red[3][1];
    int slot = blockIdx.x & (NSLOT-1);
    atomicAdd(accbuf + (2*STEP  )*NSLOT + slot, e);
    atomicAdd(accbuf + (2*STEP+1)*NSLOT + slot, ms);
  }
}

// ---------------- maskloss, 512-thr 4-row blocks (steps 4,5) -------------------
// 8 waves, 4 output rows per block: stages 6 input rows for 4 out rows
// (1.5 rows/px vs 2.0 at ROWS=2), half the blocks -> half the per-block
// barrier/atomic overhead. LDS ~59.5 KB -> 2 blocks/CU = 16 waves.
template<int STEP, int DIM, int HH, int WW>
__global__ void __launch_bounds__(512,4)
maskloss_lds8(const bf16* __restrict__ feat, const bf16* __restrict__ mpack,
              const float* __restrict__ mb, const float* __restrict__ img,
              const float* __restrict__ masks_in, float* __restrict__ masks_out,
              float* __restrict__ accbuf){
  constexpr int NBrow = WW/64;
  constexpr int PITCH = 9216;                // 72 px * 128 B
  constexpr int NR = 6;                      // 4 out rows + 2 halo
  __shared__ __align__(16) char smem[NR*PITCH];
  __shared__ float llog[8][2][16][4];
  __shared__ float red[8][2];
  int tid = threadIdx.x;
  int lane = tid & 63, wv = tid >> 6;        // wv 0..7
  int bi = swz8(blockIdx.x, gridDim.x);
  int x0 = (bi % NBrow)*64;
  int y0 = ((bi / NBrow) % (HH/4)) * 4;
  int b  = bi / (NBrow*(HH/4));
  int m = lane & 15, quad = lane >> 4;
  int lanesw = ((lane ^ (lane>>3)) << 4);

  int r_w   = wv >> 1;                       // wave's row 0..3
  int xbase = (wv & 1) * 32;                 // wave covers 32 px via 2 tiles
  int yw    = y0 + r_w;

  for (int k = wv; k < NR*9; k += 8){
    int r = k/9, coff = (k%9)*1024;
    int iy = y0 + r - 1;
    if (iy < 0 || iy >= HH) continue;
    const char* g = (const char*)(feat + ((size_t)(b*HH+iy)*WW + x0 - 1)*64)
                    + coff + lanesw;
    dma16(g, smem + r*PITCH + coff);
  }
  asm volatile("s_waitcnt vmcnt(0)" ::: "memory");
  __syncthreads();
  if (x0 == 0 && tid < 32*NR)
    ((float*)(smem + (tid>>5)*PITCH))[tid & 31] = 0.f;
  if (x0 + 64 == WW && tid >= 256 && tid < 256 + 32*NR){
    int t = tid - 256;
    ((float*)(smem + (t>>5)*PITCH + 65*128))[t & 31] = 0.f;
  }
  __syncthreads();

  const uint4* bp4 = (const uint4*)mpack;
  #pragma unroll
  for (int t=0; t<2; t++){
    f32x4 accA = (f32x4){0.f,0.f,0.f,0.f};
    f32x4 accB = (f32x4){0.f,0.f,0.f,0.f};
    #pragma unroll
    for (int ky=0; ky<3; ky++){
      int iyw = yw + ky - 1;
      if (iyw < 0 || iyw >= HH) continue;
      const char* rowl = smem + (size_t)(r_w + ky)*PITCH;
      #pragma unroll
      for (int kx=0; kx<3; kx++){
        int lp = xbase + t*16 + m + kx;
        const char* pl = rowl + (size_t)lp*128;
        int xw = (lp & 7) << 4;
        bf16x8 a0 = __builtin_bit_cast(bf16x8, *(const uint4*)(pl + ((quad*16     ) ^ xw)));
        bf16x8 a1 = __builtin_bit_cast(bf16x8, *(const uint4*)(pl + ((quad*16 + 64) ^ xw)));
        uint4 b0 = bp4[((ky*3+kx)*2+0)*64 + lane];
        uint4 b1 = bp4[((ky*3+kx)*2+1)*64 + lane];
        accA = mfma16(a0, b0, accA);
        accB = mfma16(a1, b1, accB);
      }
    }
    if (m < 4){
      #pragma unroll
      for (int r=0;r<4;r++) llog[wv][t][quad*4+r][m] = accA[r] + accB[r] + mb[m];
    }
  }
  __syncthreads();

  float ent = 0.f, mse = 0.f;
  if (lane < 32){
    int t = lane >> 4;
    int p = lane & 15;
    int xx = x0 + xbase + t*16 + p;
    float l0 = llog[wv][t][p][0], l1 = llog[wv][t][p][1];
    float l2 = llog[wv][t][p][2], l3 = llog[wv][t][p][3];
    float mx = fmaxf(fmaxf(l0,l1), fmaxf(l2,l3));
    float d0=l0-mx, d1=l1-mx, d2=l2-mx, d3=l3-mx;
    float e0=__expf(d0), e1=__expf(d1), e2=__expf(d2), e3=__expf(d3);
    float S = e0+e1+e2+e3;
    float inv = __builtin_amdgcn_rcpf(S);
    float sval = (e1 + 2.f*e2 + 3.f*e3)*inv;

    constexpr int HM = (DIM==0)? HH/2 : HH;
    constexpr int WM = (DIM==0)? WW : WW/2;
    int my = (DIM==0)? (yw>>1) : yw;
    int mxi = (DIM==1)? (xx>>1) : xx;
    float mv = masks_in[((size_t)b*HM + my)*WM + mxi];
    masks_out[((size_t)b*HH + yw)*WW + xx] = mv + 0.25f*sval;

    ent = __logf(S) - (e0*d0 + e1*d1 + e2*d2 + e3*d3)*inv;

    constexpr int FH = 256/HH, FW = 256/WW;
    float isum = 0.f;
    const float* ib = img + ((size_t)b*256 + yw*FH)*256 + xx*FW;
    #pragma unroll
    for (int dy=0; dy<FH; dy++)
      #pragma unroll
      for (int dx=0; dx<FW; dx++) isum += ib[dy*256+dx];
    float img_ds = isum * (1.0f/(FH*FW));
    float d = sval*(1.0f/3.0f) - img_ds;
    mse = d*d;
  }

  #pragma unroll
  for (int off=1; off<64; off<<=1){
    ent += __shfl_xor(ent, off, 64);
    mse += __shfl_xor(mse, off, 64);
  }
  if (lane == 0){ red[wv][0] = ent; red[wv][1] = mse; }
  __syncthreads();
  if (threadIdx.x == 0){
    float e = 0.f, ms = 0.f;
    #pragma unroll
    for (int i=0;i<8;i++){ e += red[i][0]; ms += red[i][1]; }
    int slot = blockIdx.x & (NSLOT-1);
    atomicAdd(accbuf + (2*STEP  )*NSLOT + slot, e);
    atomicAdd(accbuf + (2*STEP+1)*NSLOT + slot, ms);
  }
}

__global__ void finalize_kernel(const float* __restrict__ acc, float* __restrict__ out){
  int lane = threadIdx.x & 63;
  float v[12];
  #pragma unroll
  for (int i=0;i<12;i++){
    float x = acc[i*NSLOT + lane];
    #pragma unroll
    for (int off=1; off<64; off<<=1) x += __shfl_xor(x, off, 64);
    v[i] = x;
  }
  if (lane == 0){
    const float lw[6] = {0.1f,0.1f,0.5f,0.5f,1.0f,1.0f};
    const float nn[6] = {16384.f,32768.f,65536.f,131072.f,262144.f,524288.f};
    float L=0.f;
    for (int i=0;i<6;i++) L += lw[i]*((v[2*i] + v[2*i+1])/nn[i]);
    out[0]=L;
  }
}

extern "C" void kernel_launch(void* const* d_in, const int* in_sizes, int n_in,
                              void* d_out, int out_size, void* d_ws, size_t ws_size,
                              hipStream_t stream){
  const float* image  = (const float*)d_in[0];
  const float* w1=(const float*)d_in[2];  const float* b1=(const float*)d_in[3];
  const float* w2=(const float*)d_in[4];  const float* b2=(const float*)d_in[5];
  const float* w3=(const float*)d_in[6];  const float* b3=(const float*)d_in[7];
  const float* w4=(const float*)d_in[8];  const float* b4=(const float*)d_in[9];
  const float* upw=(const float*)d_in[10];const float* upb=(const float*)d_in[11];
  const float* mw=(const float*)d_in[12]; const float* mb=(const float*)d_in[13];
  const float* masks0=(const float*)d_in[14];
  float* out = (float*)d_out;

  char* ws = (char*)d_ws;
  size_t off = 0;
  auto alloc = [&](size_t bytes)->char*{
    char* p = ws + off; off += (bytes + 255) & ~(size_t)255; return p;
  };
  bf16* enc1  = (bf16*)alloc((size_t)8*256*256*16*2);
  bf16* enc2  = (bf16*)alloc((size_t)8*128*128*16*2);
  bf16* enc3  = (bf16*)alloc((size_t)8*64*64*32*2);
  bf16* featA = (bf16*)alloc((size_t)8*256*256*64*2);
  bf16* featB = (bf16*)alloc((size_t)8*256*128*64*2);
  float* mbA  = (float*)alloc((size_t)8*256*128*4);
  float* mbB  = (float*)alloc((size_t)8*128*128*4);
  bf16* packU = (bf16*)alloc((size_t)9*2*4*64*8*2);
  bf16* packM = (bf16*)alloc((size_t)9*2*64*8*2);
  bf16* packT2= (bf16*)alloc((size_t)5*1*64*8*2);
  bf16* packT3= (bf16*)alloc((size_t)5*2*64*8*2);
  bf16* packT4= (bf16*)alloc((size_t)9*4*64*8*2);
  float* acc  = (float*)alloc(12*NSLOT*sizeof(float));

  hipMemsetAsync(acc, 0, 12*NSLOT*sizeof(float), stream);

  repack_all<<<282,256,0,stream>>>(upw, mw, w2, w3, w4,
                                   packU, packM, packT2, packT3, packT4);

  // encoder
  trio_kernel<float,1,16,1,1,256,256><<<8*256*256/256,256,0,stream>>>(image,w1,b1,enc1);
  trio_mfma<16,16,256,256><<<8*128*128/16/4,256,0,stream>>>(enc1,packT2,b2,enc2);
  trio_mfma<16,32,128,128><<<8*64*64/16/4,256,0,stream>>>(enc2,packT3,b3,enc3);
  trio_mfma<32,64,64,64><<<8*32*32/16/4,256,0,stream>>>(enc3,packT4,b4,featA);

  // step 0: (32,32) -> (64,32)
  upconv_dim0<32,32><<<128,256,0,stream>>>(featA,packU,upb,featB);
  maskloss_mfma<0,0,64,32,2><<<128,256,0,stream>>>(featB,packM,mb,image,masks0,mbA,acc);
  // step 1: (64,32) -> (64,64)
  upconv_dim1<64,32><<<256,256,0,stream>>>(featB,packU,upb,featA);
  maskloss_lds<1,1,64,64,1><<<512,256,0,stream>>>(featA,packM,mb,image,mbA,mbB,acc);
  // step 2: (64,64) -> (128,64)
  upconv_dim0_bs<64,64><<<512,256,0,stream>>>(featA,packU,upb,featB);
  maskloss_lds<2,0,128,64,1><<<1024,256,0,stream>>>(featB,packM,mb,image,mbB,mbA,acc);
  // step 3: (128,64) -> (128,128)
  upconv_dim1_bs<128,64><<<512,256,0,stream>>>(featB,packU,upb,featA);
  maskloss_lds<3,1,128,128,2><<<1024,256,0,stream>>>(featA,packM,mb,image,mbA,mbB,acc);
  // step 4: (128,128) -> (256,128)  [512-thr blocks]
  upconv_dim0_bs8<128,128><<<1024,512,0,stream>>>(featA,packU,upb,featB);
  maskloss_lds8<4,0,256,128><<<1024,512,0,stream>>>(featB,packM,mb,image,mbB,mbA,acc);
  // step 5: (256,128) -> (256,256)  [512-thr blocks]
  upconv_dim1_bs8<256,128><<<1024,512,0,stream>>>(featB,packU,upb,featA);
  maskloss_lds8<5,1,256,256><<<2048,512,0,stream>>>(featA,packM,mb,image,mbA,out+1,acc);

  finalize_kernel<<<1,64,0,stream>>>(acc,out);
}